// Round 1
// baseline (3416.375 us; speedup 1.0000x reference)
//
#include <hip/hip_runtime.h>
#include <hip/hip_bf16.h>
#include <cstdint>

#define SEQ  4096
#define DIM  768
#define NH   12
#define HDIM 64
#define NLAYER 2
#define CHK  256
#define WINR 256
#define NCLS 64
#define NCHK 16
#define FFD  3072
#define NEGV (-1000000000.0f)
#define QSCALE 0.125f
#define SD ((size_t)SEQ * DIM)

// ---------------- reductions ----------------
__device__ __forceinline__ float block_reduce_sum(float v, float* red) {
    int t = threadIdx.x;
    red[t] = v; __syncthreads();
    #pragma unroll
    for (int st = 128; st > 0; st >>= 1) {
        if (t < st) red[t] += red[t + st];
        __syncthreads();
    }
    float r = red[0]; __syncthreads();
    return r;
}
__device__ __forceinline__ float block_reduce_max(float v, float* red) {
    int t = threadIdx.x;
    red[t] = v; __syncthreads();
    #pragma unroll
    for (int st = 128; st > 0; st >>= 1) {
        if (t < st) red[t] = fmaxf(red[t], red[t + st]);
        __syncthreads();
    }
    float r = red[0]; __syncthreads();
    return r;
}

__device__ __forceinline__ float gelu_f(float x) {
    float x3 = x * x * x;
    return 0.5f * x * (1.0f + tanhf(0.7978845608028654f * (x + 0.044715f * x3)));
}

// ---------------- embedding + LN ----------------
__global__ __launch_bounds__(256) void embed_ln_kernel(
    const int* __restrict__ x, const int* __restrict__ segs,
    const float* __restrict__ word_emb, const float* __restrict__ pos_emb,
    const float* __restrict__ type_emb, const float* __restrict__ gs,
    const float* __restrict__ gb, float* __restrict__ h)
{
    __shared__ float red[256];
    int s = blockIdx.x, t = threadIdx.x;
    int w = x[s], sg = segs[s];
    float v0[3]; float lsum = 0.f;
    #pragma unroll
    for (int i = 0; i < 3; i++) {
        int d = t + i * 256;
        float val = word_emb[(size_t)w * DIM + d] + pos_emb[(size_t)s * DIM + d]
                  + type_emb[(size_t)sg * DIM + d];
        v0[i] = val; lsum += val;
    }
    float mean = block_reduce_sum(lsum, red) * (1.0f / DIM);
    float lv = 0.f;
    #pragma unroll
    for (int i = 0; i < 3; i++) { float dv = v0[i] - mean; lv += dv * dv; }
    float var = block_reduce_sum(lv, red) * (1.0f / DIM);
    float rstd = rsqrtf(var + 1e-5f);
    #pragma unroll
    for (int i = 0; i < 3; i++) {
        int d = t + i * 256;
        h[(size_t)s * DIM + d] = (v0[i] - mean) * rstd * gs[d] + gb[d];
    }
}

// ---------------- residual add + LN (in-place on h) ----------------
__global__ __launch_bounds__(256) void add_ln_kernel(
    float* __restrict__ h, const float* __restrict__ r,
    const float* __restrict__ gs, const float* __restrict__ gb)
{
    __shared__ float red[256];
    int s = blockIdx.x, t = threadIdx.x;
    float v0[3]; float lsum = 0.f;
    #pragma unroll
    for (int i = 0; i < 3; i++) {
        int d = t + i * 256;
        float val = h[(size_t)s * DIM + d] + r[(size_t)s * DIM + d];
        v0[i] = val; lsum += val;
    }
    float mean = block_reduce_sum(lsum, red) * (1.0f / DIM);
    float lv = 0.f;
    #pragma unroll
    for (int i = 0; i < 3; i++) { float dv = v0[i] - mean; lv += dv * dv; }
    float var = block_reduce_sum(lv, red) * (1.0f / DIM);
    float rstd = rsqrtf(var + 1e-5f);
    #pragma unroll
    for (int i = 0; i < 3; i++) {
        int d = t + i * 256;
        h[(size_t)s * DIM + d] = (v0[i] - mean) * rstd * gs[d] + gb[d];
    }
}

// ---------------- f32 tiled GEMM: C = f((A@W + bias) * scale) ----------------
#define BM 64
#define BN 64
#define BK 16
#define LDA (BM + 4)
#define LDB (BN + 4)
__global__ __launch_bounds__(256) void gemm_kernel(
    const float* __restrict__ A, const float* __restrict__ W,
    const float* __restrict__ bias, float* __restrict__ Cmat,
    int M, int N, int K, float scale, int act)
{
    __shared__ float As[BK * LDA];
    __shared__ float Bs[BK * LDB];
    int bm = blockIdx.x * BM, bn = blockIdx.y * BN;
    int t = threadIdx.x;
    int tx = t & 15, ty = t >> 4;
    float acc[4][4];
    #pragma unroll
    for (int i = 0; i < 4; i++)
        #pragma unroll
        for (int j = 0; j < 4; j++) acc[i][j] = 0.f;

    int ar = t >> 2, ac = (t & 3) * 4;       // A: 64 rows x 16 k
    int brk = t >> 4, bcn = (t & 15) * 4;    // B: 16 k x 64 cols

    for (int k0 = 0; k0 < K; k0 += BK) {
        float4 a4 = *(const float4*)(A + (size_t)(bm + ar) * K + k0 + ac);
        float4 b4 = *(const float4*)(W + (size_t)(k0 + brk) * N + bn + bcn);
        __syncthreads();
        As[(ac + 0) * LDA + ar] = a4.x;
        As[(ac + 1) * LDA + ar] = a4.y;
        As[(ac + 2) * LDA + ar] = a4.z;
        As[(ac + 3) * LDA + ar] = a4.w;
        *(float4*)&Bs[brk * LDB + bcn] = b4;
        __syncthreads();
        #pragma unroll
        for (int kk = 0; kk < BK; kk++) {
            float4 av = *(const float4*)&As[kk * LDA + ty * 4];
            float4 bv = *(const float4*)&Bs[kk * LDB + tx * 4];
            acc[0][0] += av.x * bv.x; acc[0][1] += av.x * bv.y;
            acc[0][2] += av.x * bv.z; acc[0][3] += av.x * bv.w;
            acc[1][0] += av.y * bv.x; acc[1][1] += av.y * bv.y;
            acc[1][2] += av.y * bv.z; acc[1][3] += av.y * bv.w;
            acc[2][0] += av.z * bv.x; acc[2][1] += av.z * bv.y;
            acc[2][2] += av.z * bv.z; acc[2][3] += av.z * bv.w;
            acc[3][0] += av.w * bv.x; acc[3][1] += av.w * bv.y;
            acc[3][2] += av.w * bv.z; acc[3][3] += av.w * bv.w;
        }
    }
    float bias4[4];
    #pragma unroll
    for (int j = 0; j < 4; j++) bias4[j] = bias[bn + tx * 4 + j];
    #pragma unroll
    for (int i = 0; i < 4; i++) {
        float4 o;
        o.x = (acc[i][0] + bias4[0]) * scale;
        o.y = (acc[i][1] + bias4[1]) * scale;
        o.z = (acc[i][2] + bias4[2]) * scale;
        o.w = (acc[i][3] + bias4[3]) * scale;
        if (act) { o.x = gelu_f(o.x); o.y = gelu_f(o.y); o.z = gelu_f(o.z); o.w = gelu_f(o.w); }
        *(float4*)(Cmat + (size_t)(bm + ty * 4 + i) * N + bn + tx * 4) = o;
    }
}

// ---------------- fused band + global-key attention (flash-style) ----------------
// grid (NCHK, NH, 4); block 256. Thread t: query ql = t>>2 (within 64-query group),
// lane-part = t&3 owns 16 dims. Online softmax over [64 global keys | 9 band tiles of 64].
__global__ __launch_bounds__(256) void band_attn_kernel(
    const float* __restrict__ q, const float* __restrict__ k, const float* __restrict__ v,
    const int* __restrict__ clss, const int* __restrict__ mask_src,
    const int* __restrict__ is_glb, float* __restrict__ outb)
{
    __shared__ float kt[64 * 64];
    __shared__ float vt[64 * 64];
    __shared__ int kvalid[64];
    __shared__ int gpos[64];
    int n = blockIdx.x, hh = blockIdx.y, qgi = blockIdx.z;
    int t = threadIdx.x;
    int ql = t >> 2, part = t & 3, d0 = part * 16;
    int i = qgi * 64 + ql;           // query index within chunk (0..255)
    int sq = n * CHK + i;            // global sequence position
    float qreg[16];
    const float* qp = q + (size_t)sq * DIM + hh * HDIM + d0;
    #pragma unroll
    for (int dd = 0; dd < 16; dd++) qreg[dd] = qp[dd];
    float acc[16];
    #pragma unroll
    for (int dd = 0; dd < 16; dd++) acc[dd] = 0.f;
    float m = -1e30f, l = 0.f;

    if (t < 64) gpos[t] = clss[t];

    int jt_lo = qgi;
    int jt_hi = (qgi + 8 < 11) ? (qgi + 8) : 11;  // band slots j in [i, i+512]
    int ntiles = 2 + jt_hi - jt_lo;               // 1 global tile + band tiles
    int r = t >> 2, c0 = (t & 3) * 16;

    for (int tt = 0; tt < ntiles; tt++) {
        __syncthreads();   // previous tile fully consumed (also covers gpos store)
        int pos, valid, jbase = 0;
        if (tt == 0) {
            pos = gpos[r];
            valid = (mask_src[pos] > 0) ? 1 : 0;
        } else {
            int jt = jt_lo + tt - 1;
            jbase = jt * 64;
            int j = jbase + r;
            pos = n * CHK + j - CHK;
            valid = (pos >= 0 && pos < SEQ && mask_src[pos] > 0 && is_glb[pos] == 0) ? 1 : 0;
        }
        if ((t & 3) == 0) kvalid[r] = valid;
        if (valid) {
            const float* kp = k + (size_t)pos * DIM + hh * HDIM + c0;
            const float* vp = v + (size_t)pos * DIM + hh * HDIM + c0;
            #pragma unroll
            for (int ii = 0; ii < 4; ii++) {
                *(float4*)&kt[r * 64 + c0 + 4 * ii] = *(const float4*)(kp + 4 * ii);
                *(float4*)&vt[r * 64 + c0 + 4 * ii] = *(const float4*)(vp + 4 * ii);
            }
        } else {
            float4 z = make_float4(0.f, 0.f, 0.f, 0.f);
            #pragma unroll
            for (int ii = 0; ii < 4; ii++) {
                *(float4*)&kt[r * 64 + c0 + 4 * ii] = z;
                *(float4*)&vt[r * 64 + c0 + 4 * ii] = z;
            }
        }
        __syncthreads();
        int isband = (tt != 0);
        for (int jj = 0; jj < 64; jj++) {
            int use = kvalid[jj];
            if (isband) {
                int rel = jbase + jj - i;     // 0 <= j-i <= 512  <=>  |j-(i+C)| <= WIN
                use = use && (rel >= 0) && (rel <= 2 * WINR);
            }
            if (!use) continue;               // identical to -1e9 fill + softmax
            const float4* kt4 = (const float4*)&kt[jj * 64 + d0];
            float partial = 0.f;
            #pragma unroll
            for (int ii = 0; ii < 4; ii++) {
                float4 kk4 = kt4[ii];
                partial += qreg[4 * ii + 0] * kk4.x + qreg[4 * ii + 1] * kk4.y
                         + qreg[4 * ii + 2] * kk4.z + qreg[4 * ii + 3] * kk4.w;
            }
            partial += __shfl_xor(partial, 1);
            partial += __shfl_xor(partial, 2);   // 4 lanes/query -> full 64-dim dot
            float sc = partial;
            float mn = fmaxf(m, sc);
            float al = __expf(m - mn);
            float p  = __expf(sc - mn);
            l = l * al + p;
            const float4* vt4 = (const float4*)&vt[jj * 64 + d0];
            #pragma unroll
            for (int ii = 0; ii < 4; ii++) {
                float4 vv = vt4[ii];
                acc[4 * ii + 0] = acc[4 * ii + 0] * al + p * vv.x;
                acc[4 * ii + 1] = acc[4 * ii + 1] * al + p * vv.y;
                acc[4 * ii + 2] = acc[4 * ii + 2] * al + p * vv.z;
                acc[4 * ii + 3] = acc[4 * ii + 3] * al + p * vv.w;
            }
            m = mn;
        }
    }
    float inv = 1.0f / l;
    float* op = outb + (size_t)sq * DIM + hh * HDIM + d0;
    #pragma unroll
    for (int dd = 0; dd < 16; dd++) op[dd] = acc[dd] * inv;
}

// ---------------- global-query full attention: scores ----------------
// grid (NH, SEQ/256); scores[hh][gq][j] = qg[gq,hh,:] . kgf[j,hh,:]  (masked)
__global__ __launch_bounds__(256) void gq_scores_kernel(
    const float* __restrict__ qgb, const float* __restrict__ kgf,
    const int* __restrict__ mask_src, float* __restrict__ scores)
{
    __shared__ float qs[64 * 64];
    int hh = blockIdx.x, t = threadIdx.x;
    int j = blockIdx.y * 256 + t;
    #pragma unroll
    for (int c0 = 0; c0 < 16; c0++) {
        int li = t + c0 * 256;
        int gq = li >> 6, d = li & 63;
        qs[li] = qgb[(size_t)gq * DIM + hh * HDIM + d];
    }
    __syncthreads();
    float accv[64];
    #pragma unroll
    for (int gq = 0; gq < 64; gq++) accv[gq] = 0.f;
    const float* kp = kgf + (size_t)j * DIM + hh * HDIM;
    for (int d4 = 0; d4 < 16; d4++) {
        float4 kk = *(const float4*)(kp + 4 * d4);
        #pragma unroll
        for (int gq = 0; gq < 64; gq++) {
            float4 qq = *(const float4*)&qs[gq * 64 + 4 * d4];
            accv[gq] += qq.x * kk.x + qq.y * kk.y + qq.z * kk.z + qq.w * kk.w;
        }
    }
    int ok = mask_src[j] > 0;
    float* srow = scores + (size_t)hh * 64 * SEQ + j;
    #pragma unroll
    for (int gq = 0; gq < 64; gq++)
        srow[(size_t)gq * SEQ] = ok ? accv[gq] : NEGV;
}

// ---------------- row softmax over SEQ ----------------
__global__ __launch_bounds__(256) void softmax_kernel(float* __restrict__ scores)
{
    __shared__ float red[256];
    int row = blockIdx.x, t = threadIdx.x;
    float* p = scores + (size_t)row * SEQ;
    float lm = -1e30f;
    for (int jj = t; jj < SEQ; jj += 256) lm = fmaxf(lm, p[jj]);
    float mx = block_reduce_max(lm, red);
    float ls = 0.f;
    for (int jj = t; jj < SEQ; jj += 256) { float e = __expf(p[jj] - mx); p[jj] = e; ls += e; }
    float sum = block_reduce_sum(ls, red);
    float inv = 1.0f / sum;
    for (int jj = t; jj < SEQ; jj += 256) p[jj] *= inv;
}

// ---------------- global-query PV ----------------
// grid (NH, NCLS), 64 threads (thread = dim)
__global__ __launch_bounds__(64) void gq_out_kernel(
    const float* __restrict__ scores, const float* __restrict__ vgf,
    float* __restrict__ ogb)
{
    __shared__ float ps[64];
    int hh = blockIdx.x, gq = blockIdx.y;
    int d = threadIdx.x;
    const float* srow = scores + ((size_t)hh * 64 + gq) * SEQ;
    float acc = 0.f;
    for (int j0 = 0; j0 < SEQ; j0 += 64) {
        __syncthreads();
        ps[d] = srow[j0 + d];
        __syncthreads();
        const float* vp = vgf + (size_t)j0 * DIM + hh * HDIM + d;
        #pragma unroll 8
        for (int jj = 0; jj < 64; jj++) acc += ps[jj] * vp[(size_t)jj * DIM];
    }
    ogb[(size_t)gq * DIM + hh * HDIM + d] = acc;
}

// ---------------- gather / scatter rows ----------------
__global__ __launch_bounds__(256) void gather_rows_kernel(
    const float* __restrict__ src, const int* __restrict__ idx, float* __restrict__ dst)
{
    int i = blockIdx.x, t = threadIdx.x;
    int p = idx[i];
    #pragma unroll
    for (int c = 0; c < 3; c++)
        dst[(size_t)i * DIM + t + c * 256] = src[(size_t)p * DIM + t + c * 256];
}
__global__ __launch_bounds__(256) void scatter_rows_kernel(
    const float* __restrict__ src, const int* __restrict__ idx, float* __restrict__ dst)
{
    int i = blockIdx.x, t = threadIdx.x;
    int p = idx[i];
    #pragma unroll
    for (int c = 0; c < 3; c++)
        dst[(size_t)p * DIM + t + c * 256] = src[(size_t)i * DIM + t + c * 256];
}

// ---------------- is_glb build (single block) ----------------
__global__ __launch_bounds__(256) void build_glb_kernel(
    const int* __restrict__ clss, int* __restrict__ is_glb)
{
    int t = threadIdx.x;
    for (int s0 = t; s0 < SEQ; s0 += 256) is_glb[s0] = 0;
    __syncthreads();
    if (t < NCLS) is_glb[clss[t]] = 1;
}

// ---------------- host launcher ----------------
extern "C" void kernel_launch(void* const* d_in, const int* in_sizes, int n_in,
                              void* d_out, int out_size, void* d_ws, size_t ws_size,
                              hipStream_t stream)
{
    const int* x        = (const int*)d_in[0];
    const int* mask_src = (const int*)d_in[1];
    const int* clss     = (const int*)d_in[2];
    const int* segs     = (const int*)d_in[3];
    const float* word_emb = (const float*)d_in[4];
    const float* pos_emb  = (const float*)d_in[5];
    const float* type_emb = (const float*)d_in[6];
    const float* ln_e_s   = (const float*)d_in[7];
    const float* ln_e_b   = (const float*)d_in[8];
    const float* Wq  = (const float*)d_in[9];
    const float* bq  = (const float*)d_in[10];
    const float* Wk  = (const float*)d_in[11];
    const float* bk  = (const float*)d_in[12];
    const float* Wv  = (const float*)d_in[13];
    const float* bv  = (const float*)d_in[14];
    const float* Wqg = (const float*)d_in[15];
    const float* bqg = (const float*)d_in[16];
    const float* Wkg = (const float*)d_in[17];
    const float* bkg = (const float*)d_in[18];
    const float* Wvg = (const float*)d_in[19];
    const float* bvg = (const float*)d_in[20];
    const float* Wo  = (const float*)d_in[21];
    const float* bo  = (const float*)d_in[22];
    const float* ln1_s = (const float*)d_in[23];
    const float* ln1_b = (const float*)d_in[24];
    const float* Wf1 = (const float*)d_in[25];
    const float* bf1 = (const float*)d_in[26];
    const float* Wf2 = (const float*)d_in[27];
    const float* bf2 = (const float*)d_in[28];
    const float* ln2_s = (const float*)d_in[29];
    const float* ln2_b = (const float*)d_in[30];

    float* ws = (float*)d_ws;
    float* h   = ws;
    float* b1  = ws + 1 * SD;
    float* b2  = ws + 2 * SD;
    float* b3  = ws + 3 * SD;
    float* b4  = ws + 4 * SD;
    float* b5  = ws + 5 * SD;
    float* b6  = ws + 6 * SD;
    float* qgb = ws + 7 * SD;
    float* ogb = qgb + (size_t)NCLS * DIM;
    float* hgb = ogb + (size_t)NCLS * DIM;
    int*   isglb = (int*)(hgb + (size_t)NCLS * DIM);

    build_glb_kernel<<<1, 256, 0, stream>>>(clss, isglb);
    embed_ln_kernel<<<SEQ, 256, 0, stream>>>(x, segs, word_emb, pos_emb, type_emb,
                                             ln_e_s, ln_e_b, h);

    for (int l = 0; l < NLAYER; l++) {
        const float* Wq_l  = Wq  + (size_t)l * DIM * DIM;
        const float* Wk_l  = Wk  + (size_t)l * DIM * DIM;
        const float* Wv_l  = Wv  + (size_t)l * DIM * DIM;
        const float* Wqg_l = Wqg + (size_t)l * DIM * DIM;
        const float* Wkg_l = Wkg + (size_t)l * DIM * DIM;
        const float* Wvg_l = Wvg + (size_t)l * DIM * DIM;
        const float* Wo_l  = Wo  + (size_t)l * DIM * DIM;
        const float* Wf1_l = Wf1 + (size_t)l * DIM * FFD;
        const float* Wf2_l = Wf2 + (size_t)l * FFD * DIM;
        const float* bq_l  = bq  + (size_t)l * DIM;
        const float* bk_l  = bk  + (size_t)l * DIM;
        const float* bv_l  = bv  + (size_t)l * DIM;
        const float* bqg_l = bqg + (size_t)l * DIM;
        const float* bkg_l = bkg + (size_t)l * DIM;
        const float* bvg_l = bvg + (size_t)l * DIM;
        const float* bo_l  = bo  + (size_t)l * DIM;
        const float* bf1_l = bf1 + (size_t)l * FFD;
        const float* bf2_l = bf2 + (size_t)l * DIM;
        const float* ln1_s_l = ln1_s + (size_t)l * DIM;
        const float* ln1_b_l = ln1_b + (size_t)l * DIM;
        const float* ln2_s_l = ln2_s + (size_t)l * DIM;
        const float* ln2_b_l = ln2_b + (size_t)l * DIM;

        dim3 gD(SEQ / BM, DIM / BN);
        // q,k,v (q pre-scaled)
        gemm_kernel<<<gD, 256, 0, stream>>>(h, Wq_l, bq_l, b1, SEQ, DIM, DIM, QSCALE, 0);
        gemm_kernel<<<gD, 256, 0, stream>>>(h, Wk_l, bk_l, b2, SEQ, DIM, DIM, 1.0f, 0);
        gemm_kernel<<<gD, 256, 0, stream>>>(h, Wv_l, bv_l, b3, SEQ, DIM, DIM, 1.0f, 0);
        // band + global-key attention -> b6
        band_attn_kernel<<<dim3(NCHK, NH, 4), 256, 0, stream>>>(b1, b2, b3, clss,
                                                                mask_src, isglb, b6);
        // global-query path
        gemm_kernel<<<gD, 256, 0, stream>>>(h, Wkg_l, bkg_l, b4, SEQ, DIM, DIM, 1.0f, 0);
        gemm_kernel<<<gD, 256, 0, stream>>>(h, Wvg_l, bvg_l, b5, SEQ, DIM, DIM, 1.0f, 0);
        gather_rows_kernel<<<NCLS, 256, 0, stream>>>(h, clss, hgb);
        gemm_kernel<<<dim3(NCLS / BM, DIM / BN), 256, 0, stream>>>(hgb, Wqg_l, bqg_l, qgb,
                                                                   NCLS, DIM, DIM, QSCALE, 0);
        gq_scores_kernel<<<dim3(NH, SEQ / 256), 256, 0, stream>>>(qgb, b4, mask_src, b2);
        softmax_kernel<<<NH * NCLS, 256, 0, stream>>>(b2);
        gq_out_kernel<<<dim3(NH, NCLS), 64, 0, stream>>>(b2, b5, ogb);
        scatter_rows_kernel<<<NCLS, 256, 0, stream>>>(ogb, clss, b6);
        // output projection + LN1
        gemm_kernel<<<gD, 256, 0, stream>>>(b6, Wo_l, bo_l, b1, SEQ, DIM, DIM, 1.0f, 0);
        add_ln_kernel<<<SEQ, 256, 0, stream>>>(h, b1, ln1_s_l, ln1_b_l);
        // FFN (gelu fused; S x FF buffer overlays b1..b4) + LN2
        gemm_kernel<<<dim3(SEQ / BM, FFD / BN), 256, 0, stream>>>(h, Wf1_l, bf1_l, b1,
                                                                  SEQ, FFD, DIM, 1.0f, 1);
        gemm_kernel<<<gD, 256, 0, stream>>>(b1, Wf2_l, bf2_l, b5, SEQ, DIM, FFD, 1.0f, 0);
        add_ln_kernel<<<SEQ, 256, 0, stream>>>(h, b5, ln2_s_l, ln2_b_l);
    }

    hipMemcpyAsync(d_out, h, SD * sizeof(float), hipMemcpyDeviceToDevice, stream);
}

// Round 2
// 2115.343 us; speedup vs baseline: 1.6150x; 1.6150x over previous
//
#include <hip/hip_runtime.h>
#include <hip/hip_bf16.h>
#include <cstdint>

#define SEQ  4096
#define DIM  768
#define NH   12
#define HDIM 64
#define NLAYER 2
#define CHK  256
#define WINR 256
#define NCLS 64
#define NCHK 16
#define FFD  3072
#define NEGV (-1000000000.0f)
#define QSCALE 0.125f
#define SD ((size_t)SEQ * DIM)

typedef __attribute__((__vector_size__(16))) float floatx4;
typedef __attribute__((ext_vector_type(8))) __bf16 bf16x8;

// ---------------- async global->LDS (16B per lane, wave-uniform LDS base) --------
__device__ __forceinline__ void async16(const void* g, void* l) {
    __builtin_amdgcn_global_load_lds(
        (const __attribute__((address_space(1))) uint32_t*)g,
        (__attribute__((address_space(3))) uint32_t*)l, 16, 0, 0);
}

// ---------------- reductions ----------------
__device__ __forceinline__ float block_reduce_sum(float v, float* red) {
    int t = threadIdx.x;
    red[t] = v; __syncthreads();
    #pragma unroll
    for (int st = 128; st > 0; st >>= 1) {
        if (t < st) red[t] += red[t + st];
        __syncthreads();
    }
    float r = red[0]; __syncthreads();
    return r;
}
__device__ __forceinline__ float block_reduce_max(float v, float* red) {
    int t = threadIdx.x;
    red[t] = v; __syncthreads();
    #pragma unroll
    for (int st = 128; st > 0; st >>= 1) {
        if (t < st) red[t] = fmaxf(red[t], red[t + st]);
        __syncthreads();
    }
    float r = red[0]; __syncthreads();
    return r;
}

__device__ __forceinline__ float gelu_f(float x) {
    float x3 = x * x * x;
    return 0.5f * x * (1.0f + tanhf(0.7978845608028654f * (x + 0.044715f * x3)));
}

// ---------------- embedding + LN (writes f32 + bf16) ----------------
__global__ __launch_bounds__(256) void embed_ln_kernel(
    const int* __restrict__ x, const int* __restrict__ segs,
    const float* __restrict__ word_emb, const float* __restrict__ pos_emb,
    const float* __restrict__ type_emb, const float* __restrict__ gs,
    const float* __restrict__ gb, float* __restrict__ h, __bf16* __restrict__ hb)
{
    __shared__ float red[256];
    int s = blockIdx.x, t = threadIdx.x;
    int w = x[s], sg = segs[s];
    float v0[3]; float lsum = 0.f;
    #pragma unroll
    for (int i = 0; i < 3; i++) {
        int d = t + i * 256;
        float val = word_emb[(size_t)w * DIM + d] + pos_emb[(size_t)s * DIM + d]
                  + type_emb[(size_t)sg * DIM + d];
        v0[i] = val; lsum += val;
    }
    float mean = block_reduce_sum(lsum, red) * (1.0f / DIM);
    float lv = 0.f;
    #pragma unroll
    for (int i = 0; i < 3; i++) { float dv = v0[i] - mean; lv += dv * dv; }
    float var = block_reduce_sum(lv, red) * (1.0f / DIM);
    float rstd = rsqrtf(var + 1e-5f);
    #pragma unroll
    for (int i = 0; i < 3; i++) {
        int d = t + i * 256;
        float o = (v0[i] - mean) * rstd * gs[d] + gb[d];
        h[(size_t)s * DIM + d] = o;
        hb[(size_t)s * DIM + d] = (__bf16)o;
    }
}

// ---------------- residual add + LN (in-place on h; writes f32 + bf16) ----------
__global__ __launch_bounds__(256) void add_ln_kernel(
    float* __restrict__ h, const float* __restrict__ r,
    const float* __restrict__ gs, const float* __restrict__ gb,
    __bf16* __restrict__ hb)
{
    __shared__ float red[256];
    int s = blockIdx.x, t = threadIdx.x;
    float v0[3]; float lsum = 0.f;
    #pragma unroll
    for (int i = 0; i < 3; i++) {
        int d = t + i * 256;
        float val = h[(size_t)s * DIM + d] + r[(size_t)s * DIM + d];
        v0[i] = val; lsum += val;
    }
    float mean = block_reduce_sum(lsum, red) * (1.0f / DIM);
    float lv = 0.f;
    #pragma unroll
    for (int i = 0; i < 3; i++) { float dv = v0[i] - mean; lv += dv * dv; }
    float var = block_reduce_sum(lv, red) * (1.0f / DIM);
    float rstd = rsqrtf(var + 1e-5f);
    #pragma unroll
    for (int i = 0; i < 3; i++) {
        int d = t + i * 256;
        float o = (v0[i] - mean) * rstd * gs[d] + gb[d];
        h[(size_t)s * DIM + d] = o;
        hb[(size_t)s * DIM + d] = (__bf16)o;
    }
}

// ---------------- weight transpose-convert: f32 [K][N] -> bf16 [N][K] ----------
struct Ptr7 { const float* p[7]; };
__global__ __launch_bounds__(256) void transpose_w_kernel(
    Ptr7 in, __bf16* __restrict__ out, int K, int N)
{
    __shared__ float tile[32][33];
    const float* src = in.p[blockIdx.z];
    __bf16* dst = out + (size_t)blockIdx.z * K * N;
    int bx = blockIdx.x * 32;   // N offset
    int by = blockIdx.y * 32;   // K offset
    int tx = threadIdx.x & 31, ty = threadIdx.x >> 5;
    #pragma unroll
    for (int i = 0; i < 32; i += 8)
        tile[ty + i][tx] = src[(size_t)(by + ty + i) * N + bx + tx];
    __syncthreads();
    #pragma unroll
    for (int i = 0; i < 32; i += 8)
        dst[(size_t)(bx + ty + i) * K + by + tx] = (__bf16)tile[tx][ty + i];
}

// ---------------- bf16 MFMA GEMM: C = f((A @ Bt^T + bias) * scale) -------------
// A: [M][K] bf16 row-major; Bt: [N][K] bf16 (pre-transposed weights).
// 128x128 tile, BK=32, 4 waves each 64x64 via 4x4 mfma_f32_16x16x32_bf16.
#define TM 128
#define TN 128
#define TK 32
__global__ __launch_bounds__(256) void mfma_gemm(
    const __bf16* __restrict__ A, const __bf16* __restrict__ Bt,
    const float* __restrict__ bias, float* __restrict__ Cf,
    __bf16* __restrict__ Cb, int M, int N, int K, float scale, int act)
{
    __shared__ __align__(16) __bf16 As[TM * TK];
    __shared__ __align__(16) __bf16 Bs[TN * TK];
    int t = threadIdx.x;
    int wave = t >> 6, lane = t & 63;
    int bm = blockIdx.x * TM, bn = blockIdx.y * TN;
    int wm = (wave & 1) * 64, wn = (wave >> 1) * 64;

    floatx4 acc[4][4];
    #pragma unroll
    for (int i = 0; i < 4; i++)
        #pragma unroll
        for (int j = 0; j < 4; j++) { floatx4 z = {0.f, 0.f, 0.f, 0.f}; acc[i][j] = z; }

    // staging: chunk c = wave*128 + p*64 + lane; 16B chunk -> row c>>2, kchunk c&3
    const int c0 = wave * 128 + lane;
    const int c1 = c0 + 64;
    const int r0 = c0 >> 2, kc0 = (c0 & 3) * 8;
    const int r1 = c1 >> 2, kc1 = (c1 & 3) * 8;
    __bf16* lA0 = &As[(size_t)(wave * 128) * 8];
    __bf16* lA1 = &As[(size_t)(wave * 128 + 64) * 8];
    __bf16* lB0 = &Bs[(size_t)(wave * 128) * 8];
    __bf16* lB1 = &Bs[(size_t)(wave * 128 + 64) * 8];

    const int mrow = lane & 15, kq = (lane >> 4) * 8;

    for (int k0 = 0; k0 < K; k0 += TK) {
        __syncthreads();   // previous iteration's LDS reads complete
        async16(A  + (size_t)(bm + r0) * K + k0 + kc0, lA0);
        async16(A  + (size_t)(bm + r1) * K + k0 + kc1, lA1);
        async16(Bt + (size_t)(bn + r0) * K + k0 + kc0, lB0);
        async16(Bt + (size_t)(bn + r1) * K + k0 + kc1, lB1);
        __builtin_amdgcn_s_waitcnt(0x0f70);   // vmcnt(0)
        __syncthreads();
        bf16x8 af[4], bfr[4];
        #pragma unroll
        for (int mt = 0; mt < 4; mt++)
            af[mt] = *(const bf16x8*)&As[(wm + mt * 16 + mrow) * TK + kq];
        #pragma unroll
        for (int nt = 0; nt < 4; nt++)
            bfr[nt] = *(const bf16x8*)&Bs[(wn + nt * 16 + mrow) * TK + kq];
        #pragma unroll
        for (int mt = 0; mt < 4; mt++)
            #pragma unroll
            for (int nt = 0; nt < 4; nt++)
                acc[mt][nt] = __builtin_amdgcn_mfma_f32_16x16x32_bf16(
                    af[mt], bfr[nt], acc[mt][nt], 0, 0, 0);
    }

    // C/D layout: col = lane&15, row = (lane>>4)*4 + reg
    int col_l = lane & 15, row_l = (lane >> 4) * 4;
    #pragma unroll
    for (int nt = 0; nt < 4; nt++) {
        int col = bn + wn + nt * 16 + col_l;
        float bs = bias[col];
        #pragma unroll
        for (int mt = 0; mt < 4; mt++) {
            floatx4 v = acc[mt][nt];
            #pragma unroll
            for (int rr = 0; rr < 4; rr++) {
                int row = bm + wm + mt * 16 + row_l + rr;
                float o = (v[rr] + bs) * scale;
                if (act) o = gelu_f(o);
                if (Cb) Cb[(size_t)row * N + col] = (__bf16)o;
                else    Cf[(size_t)row * N + col] = o;
            }
        }
    }
}

// ---------------- f32 tiled GEMM (kept for tiny qg projection) ----------------
#define BM 64
#define BN 64
#define BK 16
#define LDA (BM + 4)
#define LDB (BN + 4)
__global__ __launch_bounds__(256) void gemm_kernel(
    const float* __restrict__ A, const float* __restrict__ W,
    const float* __restrict__ bias, float* __restrict__ Cmat,
    int M, int N, int K, float scale, int act)
{
    __shared__ float As[BK * LDA];
    __shared__ float Bs[BK * LDB];
    int bm = blockIdx.x * BM, bn = blockIdx.y * BN;
    int t = threadIdx.x;
    int tx = t & 15, ty = t >> 4;
    float acc[4][4];
    #pragma unroll
    for (int i = 0; i < 4; i++)
        #pragma unroll
        for (int j = 0; j < 4; j++) acc[i][j] = 0.f;

    int ar = t >> 2, ac = (t & 3) * 4;
    int brk = t >> 4, bcn = (t & 15) * 4;

    for (int k0 = 0; k0 < K; k0 += BK) {
        float4 a4 = *(const float4*)(A + (size_t)(bm + ar) * K + k0 + ac);
        float4 b4 = *(const float4*)(W + (size_t)(k0 + brk) * N + bn + bcn);
        __syncthreads();
        As[(ac + 0) * LDA + ar] = a4.x;
        As[(ac + 1) * LDA + ar] = a4.y;
        As[(ac + 2) * LDA + ar] = a4.z;
        As[(ac + 3) * LDA + ar] = a4.w;
        *(float4*)&Bs[brk * LDB + bcn] = b4;
        __syncthreads();
        #pragma unroll
        for (int kk = 0; kk < BK; kk++) {
            float4 av = *(const float4*)&As[kk * LDA + ty * 4];
            float4 bv = *(const float4*)&Bs[kk * LDB + tx * 4];
            acc[0][0] += av.x * bv.x; acc[0][1] += av.x * bv.y;
            acc[0][2] += av.x * bv.z; acc[0][3] += av.x * bv.w;
            acc[1][0] += av.y * bv.x; acc[1][1] += av.y * bv.y;
            acc[1][2] += av.y * bv.z; acc[1][3] += av.y * bv.w;
            acc[2][0] += av.z * bv.x; acc[2][1] += av.z * bv.y;
            acc[2][2] += av.z * bv.z; acc[2][3] += av.z * bv.w;
            acc[3][0] += av.w * bv.x; acc[3][1] += av.w * bv.y;
            acc[3][2] += av.w * bv.z; acc[3][3] += av.w * bv.w;
        }
    }
    float bias4[4];
    #pragma unroll
    for (int j = 0; j < 4; j++) bias4[j] = bias[bn + tx * 4 + j];
    #pragma unroll
    for (int i = 0; i < 4; i++) {
        float4 o;
        o.x = (acc[i][0] + bias4[0]) * scale;
        o.y = (acc[i][1] + bias4[1]) * scale;
        o.z = (acc[i][2] + bias4[2]) * scale;
        o.w = (acc[i][3] + bias4[3]) * scale;
        if (act) { o.x = gelu_f(o.x); o.y = gelu_f(o.y); o.z = gelu_f(o.z); o.w = gelu_f(o.w); }
        *(float4*)(Cmat + (size_t)(bm + ty * 4 + i) * N + bn + tx * 4) = o;
    }
}

// ---------------- fused band + global-key attention (flash-style, f32) ---------
__global__ __launch_bounds__(256) void band_attn_kernel(
    const float* __restrict__ q, const float* __restrict__ k, const float* __restrict__ v,
    const int* __restrict__ clss, const int* __restrict__ mask_src,
    const int* __restrict__ is_glb, __bf16* __restrict__ outb)
{
    __shared__ float kt[64 * 64];
    __shared__ float vt[64 * 64];
    __shared__ int kvalid[64];
    __shared__ int gpos[64];
    int n = blockIdx.x, hh = blockIdx.y, qgi = blockIdx.z;
    int t = threadIdx.x;
    int ql = t >> 2, part = t & 3, d0 = part * 16;
    int i = qgi * 64 + ql;
    int sq = n * CHK + i;
    float qreg[16];
    const float* qp = q + (size_t)sq * DIM + hh * HDIM + d0;
    #pragma unroll
    for (int dd = 0; dd < 16; dd++) qreg[dd] = qp[dd];
    float acc[16];
    #pragma unroll
    for (int dd = 0; dd < 16; dd++) acc[dd] = 0.f;
    float m = -1e30f, l = 0.f;

    if (t < 64) gpos[t] = clss[t];

    int jt_lo = qgi;
    int jt_hi = (qgi + 8 < 11) ? (qgi + 8) : 11;
    int ntiles = 2 + jt_hi - jt_lo;
    int r = t >> 2, c0 = (t & 3) * 16;

    for (int tt = 0; tt < ntiles; tt++) {
        __syncthreads();
        int pos, valid, jbase = 0;
        if (tt == 0) {
            pos = gpos[r];
            valid = (mask_src[pos] > 0) ? 1 : 0;
        } else {
            int jt = jt_lo + tt - 1;
            jbase = jt * 64;
            int j = jbase + r;
            pos = n * CHK + j - CHK;
            valid = (pos >= 0 && pos < SEQ && mask_src[pos] > 0 && is_glb[pos] == 0) ? 1 : 0;
        }
        if ((t & 3) == 0) kvalid[r] = valid;
        if (valid) {
            const float* kp = k + (size_t)pos * DIM + hh * HDIM + c0;
            const float* vp = v + (size_t)pos * DIM + hh * HDIM + c0;
            #pragma unroll
            for (int ii = 0; ii < 4; ii++) {
                *(float4*)&kt[r * 64 + c0 + 4 * ii] = *(const float4*)(kp + 4 * ii);
                *(float4*)&vt[r * 64 + c0 + 4 * ii] = *(const float4*)(vp + 4 * ii);
            }
        } else {
            float4 z = make_float4(0.f, 0.f, 0.f, 0.f);
            #pragma unroll
            for (int ii = 0; ii < 4; ii++) {
                *(float4*)&kt[r * 64 + c0 + 4 * ii] = z;
                *(float4*)&vt[r * 64 + c0 + 4 * ii] = z;
            }
        }
        __syncthreads();
        int isband = (tt != 0);
        for (int jj = 0; jj < 64; jj++) {
            int use = kvalid[jj];
            if (isband) {
                int rel = jbase + jj - i;
                use = use && (rel >= 0) && (rel <= 2 * WINR);
            }
            if (!use) continue;
            const float4* kt4 = (const float4*)&kt[jj * 64 + d0];
            float partial = 0.f;
            #pragma unroll
            for (int ii = 0; ii < 4; ii++) {
                float4 kk4 = kt4[ii];
                partial += qreg[4 * ii + 0] * kk4.x + qreg[4 * ii + 1] * kk4.y
                         + qreg[4 * ii + 2] * kk4.z + qreg[4 * ii + 3] * kk4.w;
            }
            partial += __shfl_xor(partial, 1);
            partial += __shfl_xor(partial, 2);
            float sc = partial;
            float mn = fmaxf(m, sc);
            float al = __expf(m - mn);
            float p  = __expf(sc - mn);
            l = l * al + p;
            const float4* vt4 = (const float4*)&vt[jj * 64 + d0];
            #pragma unroll
            for (int ii = 0; ii < 4; ii++) {
                float4 vv = vt4[ii];
                acc[4 * ii + 0] = acc[4 * ii + 0] * al + p * vv.x;
                acc[4 * ii + 1] = acc[4 * ii + 1] * al + p * vv.y;
                acc[4 * ii + 2] = acc[4 * ii + 2] * al + p * vv.z;
                acc[4 * ii + 3] = acc[4 * ii + 3] * al + p * vv.w;
            }
            m = mn;
        }
    }
    float inv = 1.0f / l;
    __bf16* op = outb + (size_t)sq * DIM + hh * HDIM + d0;
    #pragma unroll
    for (int dd = 0; dd < 16; dd++) op[dd] = (__bf16)(acc[dd] * inv);
}

// ---------------- global-query full attention: scores ----------------
__global__ __launch_bounds__(256) void gq_scores_kernel(
    const float* __restrict__ qgb, const float* __restrict__ kgf,
    const int* __restrict__ mask_src, float* __restrict__ scores)
{
    __shared__ float qs[64 * 64];
    int hh = blockIdx.x, t = threadIdx.x;
    int j = blockIdx.y * 256 + t;
    #pragma unroll
    for (int c0 = 0; c0 < 16; c0++) {
        int li = t + c0 * 256;
        int gq = li >> 6, d = li & 63;
        qs[li] = qgb[(size_t)gq * DIM + hh * HDIM + d];
    }
    __syncthreads();
    float accv[64];
    #pragma unroll
    for (int gq = 0; gq < 64; gq++) accv[gq] = 0.f;
    const float* kp = kgf + (size_t)j * DIM + hh * HDIM;
    for (int d4 = 0; d4 < 16; d4++) {
        float4 kk = *(const float4*)(kp + 4 * d4);
        #pragma unroll
        for (int gq = 0; gq < 64; gq++) {
            float4 qq = *(const float4*)&qs[gq * 64 + 4 * d4];
            accv[gq] += qq.x * kk.x + qq.y * kk.y + qq.z * kk.z + qq.w * kk.w;
        }
    }
    int ok = mask_src[j] > 0;
    float* srow = scores + (size_t)hh * 64 * SEQ + j;
    #pragma unroll
    for (int gq = 0; gq < 64; gq++)
        srow[(size_t)gq * SEQ] = ok ? accv[gq] : NEGV;
}

// ---------------- row softmax over SEQ ----------------
__global__ __launch_bounds__(256) void softmax_kernel(float* __restrict__ scores)
{
    __shared__ float red[256];
    int row = blockIdx.x, t = threadIdx.x;
    float* p = scores + (size_t)row * SEQ;
    float lm = -1e30f;
    for (int jj = t; jj < SEQ; jj += 256) lm = fmaxf(lm, p[jj]);
    float mx = block_reduce_max(lm, red);
    float ls = 0.f;
    for (int jj = t; jj < SEQ; jj += 256) { float e = __expf(p[jj] - mx); p[jj] = e; ls += e; }
    float sum = block_reduce_sum(ls, red);
    float inv = 1.0f / sum;
    for (int jj = t; jj < SEQ; jj += 256) p[jj] *= inv;
}

// ---------------- global-query PV ----------------
__global__ __launch_bounds__(64) void gq_out_kernel(
    const float* __restrict__ scores, const float* __restrict__ vgf,
    float* __restrict__ ogb)
{
    __shared__ float ps[64];
    int hh = blockIdx.x, gq = blockIdx.y;
    int d = threadIdx.x;
    const float* srow = scores + ((size_t)hh * 64 + gq) * SEQ;
    float acc = 0.f;
    for (int j0 = 0; j0 < SEQ; j0 += 64) {
        __syncthreads();
        ps[d] = srow[j0 + d];
        __syncthreads();
        const float* vp = vgf + (size_t)j0 * DIM + hh * HDIM + d;
        #pragma unroll 8
        for (int jj = 0; jj < 64; jj++) acc += ps[jj] * vp[(size_t)jj * DIM];
    }
    ogb[(size_t)gq * DIM + hh * HDIM + d] = acc;
}

// ---------------- gather / scatter rows ----------------
__global__ __launch_bounds__(256) void gather_rows_kernel(
    const float* __restrict__ src, const int* __restrict__ idx, float* __restrict__ dst)
{
    int i = blockIdx.x, t = threadIdx.x;
    int p = idx[i];
    #pragma unroll
    for (int c = 0; c < 3; c++)
        dst[(size_t)i * DIM + t + c * 256] = src[(size_t)p * DIM + t + c * 256];
}
__global__ __launch_bounds__(256) void scatter_rows_bf16_kernel(
    const float* __restrict__ src, const int* __restrict__ idx, __bf16* __restrict__ dst)
{
    int i = blockIdx.x, t = threadIdx.x;
    int p = idx[i];
    #pragma unroll
    for (int c = 0; c < 3; c++)
        dst[(size_t)p * DIM + t + c * 256] = (__bf16)src[(size_t)i * DIM + t + c * 256];
}

// ---------------- is_glb build ----------------
__global__ __launch_bounds__(256) void build_glb_kernel(
    const int* __restrict__ clss, int* __restrict__ is_glb)
{
    int t = threadIdx.x;
    for (int s0 = t; s0 < SEQ; s0 += 256) is_glb[s0] = 0;
    __syncthreads();
    if (t < NCLS) is_glb[clss[t]] = 1;
}

// ---------------- host launcher ----------------
extern "C" void kernel_launch(void* const* d_in, const int* in_sizes, int n_in,
                              void* d_out, int out_size, void* d_ws, size_t ws_size,
                              hipStream_t stream)
{
    const int* x        = (const int*)d_in[0];
    const int* mask_src = (const int*)d_in[1];
    const int* clss     = (const int*)d_in[2];
    const int* segs     = (const int*)d_in[3];
    const float* word_emb = (const float*)d_in[4];
    const float* pos_emb  = (const float*)d_in[5];
    const float* type_emb = (const float*)d_in[6];
    const float* ln_e_s   = (const float*)d_in[7];
    const float* ln_e_b   = (const float*)d_in[8];
    const float* Wq  = (const float*)d_in[9];
    const float* bq  = (const float*)d_in[10];
    const float* Wk  = (const float*)d_in[11];
    const float* bk  = (const float*)d_in[12];
    const float* Wv  = (const float*)d_in[13];
    const float* bv  = (const float*)d_in[14];
    const float* Wqg = (const float*)d_in[15];
    const float* bqg = (const float*)d_in[16];
    const float* Wkg = (const float*)d_in[17];
    const float* bkg = (const float*)d_in[18];
    const float* Wvg = (const float*)d_in[19];
    const float* bvg = (const float*)d_in[20];
    const float* Wo  = (const float*)d_in[21];
    const float* bo  = (const float*)d_in[22];
    const float* ln1_s = (const float*)d_in[23];
    const float* ln1_b = (const float*)d_in[24];
    const float* Wf1 = (const float*)d_in[25];
    const float* bf1 = (const float*)d_in[26];
    const float* Wf2 = (const float*)d_in[27];
    const float* bf2 = (const float*)d_in[28];
    const float* ln2_s = (const float*)d_in[29];
    const float* ln2_b = (const float*)d_in[30];

    float* ws = (float*)d_ws;
    float* h     = ws;                 // slot0: h f32
    float* s1    = ws + 1 * SD;        // slot1: q f32 -> scores -> gelu(lo)
    float* s2    = ws + 2 * SD;        // slot2: k f32 -> kg f32 -> gelu(hi)
    float* s3    = ws + 3 * SD;        // slot3: v f32 -> vg f32 -> ffn2 out
    float* s4    = ws + 4 * SD;        // slot4: attn proj out f32
    __bf16* hb   = (__bf16*)(ws + 5 * SD);            // slot5 lo: h bf16
    __bf16* b6b  = (__bf16*)(ws + 5 * SD) + SD;       // slot5 hi: attn out bf16
    __bf16* Wbf  = (__bf16*)(ws + 6 * SD);            // slot6: per-layer bf16 weights
    float* smalls = ws + 7 * SD;
    float* hgb = smalls;
    float* qgb = smalls + (size_t)NCLS * DIM;
    float* ogb = smalls + 2 * (size_t)NCLS * DIM;
    int*   isglb = (int*)(smalls + 3 * (size_t)NCLS * DIM);
    __bf16* gelu_b = (__bf16*)s1;      // spans slots 1-2 (S x FF bf16)

    build_glb_kernel<<<1, 256, 0, stream>>>(clss, isglb);
    embed_ln_kernel<<<SEQ, 256, 0, stream>>>(x, segs, word_emb, pos_emb, type_emb,
                                             ln_e_s, ln_e_b, h, hb);

    const size_t DD = (size_t)DIM * DIM;
    for (int l = 0; l < NLAYER; l++) {
        const float* bq_l  = bq  + (size_t)l * DIM;
        const float* bk_l  = bk  + (size_t)l * DIM;
        const float* bv_l  = bv  + (size_t)l * DIM;
        const float* bqg_l = bqg + (size_t)l * DIM;
        const float* bkg_l = bkg + (size_t)l * DIM;
        const float* bvg_l = bvg + (size_t)l * DIM;
        const float* bo_l  = bo  + (size_t)l * DIM;
        const float* bf1_l = bf1 + (size_t)l * FFD;
        const float* bf2_l = bf2 + (size_t)l * DIM;

        // 0: convert+transpose the 6 MFMA-consumed DxD weights -> Wbf
        Ptr7 wp;
        wp.p[0] = Wq  + l * DD; wp.p[1] = Wk  + l * DD; wp.p[2] = Wv  + l * DD;
        wp.p[3] = Wkg + l * DD; wp.p[4] = Wvg + l * DD; wp.p[5] = Wo  + l * DD;
        wp.p[6] = nullptr;
        transpose_w_kernel<<<dim3(DIM / 32, DIM / 32, 6), 256, 0, stream>>>(wp, Wbf, DIM, DIM);

        dim3 gDD(SEQ / TM, DIM / TN);
        // q,k,v
        mfma_gemm<<<gDD, 256, 0, stream>>>(hb, Wbf + 0 * DD, bq_l, s1, nullptr,
                                           SEQ, DIM, DIM, QSCALE, 0);
        mfma_gemm<<<gDD, 256, 0, stream>>>(hb, Wbf + 1 * DD, bk_l, s2, nullptr,
                                           SEQ, DIM, DIM, 1.0f, 0);
        mfma_gemm<<<gDD, 256, 0, stream>>>(hb, Wbf + 2 * DD, bv_l, s3, nullptr,
                                           SEQ, DIM, DIM, 1.0f, 0);
        // band + global-key attention -> b6b (bf16)
        band_attn_kernel<<<dim3(NCHK, NH, 4), 256, 0, stream>>>(s1, s2, s3, clss,
                                                                mask_src, isglb, b6b);
        // global-query path: kg -> s2, vg -> s3 (k,v dead after band_attn)
        mfma_gemm<<<gDD, 256, 0, stream>>>(hb, Wbf + 3 * DD, bkg_l, s2, nullptr,
                                           SEQ, DIM, DIM, 1.0f, 0);
        mfma_gemm<<<gDD, 256, 0, stream>>>(hb, Wbf + 4 * DD, bvg_l, s3, nullptr,
                                           SEQ, DIM, DIM, 1.0f, 0);
        gather_rows_kernel<<<NCLS, 256, 0, stream>>>(h, clss, hgb);
        gemm_kernel<<<dim3(NCLS / BM, DIM / BN), 256, 0, stream>>>(hgb, Wqg + l * DD, bqg_l,
                                                                   qgb, NCLS, DIM, DIM, QSCALE, 0);
        gq_scores_kernel<<<dim3(NH, SEQ / 256), 256, 0, stream>>>(qgb, s2, mask_src, s1);
        softmax_kernel<<<NH * NCLS, 256, 0, stream>>>(s1);
        gq_out_kernel<<<dim3(NH, NCLS), 64, 0, stream>>>(s1, s3, ogb);
        scatter_rows_bf16_kernel<<<NCLS, 256, 0, stream>>>(ogb, clss, b6b);
        // output projection + LN1
        mfma_gemm<<<gDD, 256, 0, stream>>>(b6b, Wbf + 5 * DD, bo_l, s4, nullptr,
                                           SEQ, DIM, DIM, 1.0f, 0);
        add_ln_kernel<<<SEQ, 256, 0, stream>>>(h, s4, ln1_s + (size_t)l * DIM,
                                               ln1_b + (size_t)l * DIM, hb);
        // FFN
        Ptr7 wf1; wf1.p[0] = Wf1 + (size_t)l * DIM * FFD;
        transpose_w_kernel<<<dim3(FFD / 32, DIM / 32, 1), 256, 0, stream>>>(wf1, Wbf, DIM, FFD);
        mfma_gemm<<<dim3(SEQ / TM, FFD / TN), 256, 0, stream>>>(hb, Wbf, bf1_l, nullptr,
                                                                gelu_b, SEQ, FFD, DIM, 1.0f, 1);
        Ptr7 wf2; wf2.p[0] = Wf2 + (size_t)l * FFD * DIM;
        transpose_w_kernel<<<dim3(DIM / 32, FFD / 32, 1), 256, 0, stream>>>(wf2, Wbf, FFD, DIM);
        mfma_gemm<<<dim3(SEQ / TM, DIM / TN), 256, 0, stream>>>(gelu_b, Wbf, bf2_l, s3,
                                                                nullptr, SEQ, DIM, FFD, 1.0f, 0);
        add_ln_kernel<<<SEQ, 256, 0, stream>>>(h, s3, ln2_s + (size_t)l * DIM,
                                               ln2_b + (size_t)l * DIM, hb);
    }

    hipMemcpyAsync(d_out, h, SD * sizeof(float), hipMemcpyDeviceToDevice, stream);
}

// Round 3
// 1125.198 us; speedup vs baseline: 3.0362x; 1.8800x over previous
//
#include <hip/hip_runtime.h>
#include <hip/hip_bf16.h>
#include <cstdint>

#define SEQ  4096
#define DIM  768
#define NH   12
#define HDIM 64
#define NLAYER 2
#define CHK  256
#define WINR 256
#define NCLS 64
#define NCHK 16
#define FFD  3072
#define QSCALE 0.125f
#define SD ((size_t)SEQ * DIM)
#define PS_LD 72   // padded P-tile row stride (elems): breaks 16-way bank aliasing

typedef __attribute__((__vector_size__(16))) float floatx4;
typedef __attribute__((ext_vector_type(8))) __bf16 bf16x8;

// ---------------- async global->LDS (16B per lane, wave-uniform LDS base) --------
__device__ __forceinline__ void async16(const void* g, void* l) {
    __builtin_amdgcn_global_load_lds(
        (const __attribute__((address_space(1))) uint32_t*)g,
        (__attribute__((address_space(3))) uint32_t*)l, 16, 0, 0);
}

// ---------------- reductions ----------------
__device__ __forceinline__ float block_reduce_sum(float v, float* red) {
    int t = threadIdx.x;
    red[t] = v; __syncthreads();
    #pragma unroll
    for (int st = 128; st > 0; st >>= 1) {
        if (t < st) red[t] += red[t + st];
        __syncthreads();
    }
    float r = red[0]; __syncthreads();
    return r;
}

__device__ __forceinline__ float gelu_f(float x) {
    float x3 = x * x * x;
    return 0.5f * x * (1.0f + tanhf(0.7978845608028654f * (x + 0.044715f * x3)));
}

// ---------------- embedding + LN (writes f32 + bf16) ----------------
__global__ __launch_bounds__(256) void embed_ln_kernel(
    const int* __restrict__ x, const int* __restrict__ segs,
    const float* __restrict__ word_emb, const float* __restrict__ pos_emb,
    const float* __restrict__ type_emb, const float* __restrict__ gs,
    const float* __restrict__ gb, float* __restrict__ h, __bf16* __restrict__ hb)
{
    __shared__ float red[256];
    int s = blockIdx.x, t = threadIdx.x;
    int w = x[s], sg = segs[s];
    float v0[3]; float lsum = 0.f;
    #pragma unroll
    for (int i = 0; i < 3; i++) {
        int d = t + i * 256;
        float val = word_emb[(size_t)w * DIM + d] + pos_emb[(size_t)s * DIM + d]
                  + type_emb[(size_t)sg * DIM + d];
        v0[i] = val; lsum += val;
    }
    float mean = block_reduce_sum(lsum, red) * (1.0f / DIM);
    float lv = 0.f;
    #pragma unroll
    for (int i = 0; i < 3; i++) { float dv = v0[i] - mean; lv += dv * dv; }
    float var = block_reduce_sum(lv, red) * (1.0f / DIM);
    float rstd = rsqrtf(var + 1e-5f);
    #pragma unroll
    for (int i = 0; i < 3; i++) {
        int d = t + i * 256;
        float o = (v0[i] - mean) * rstd * gs[d] + gb[d];
        h[(size_t)s * DIM + d] = o;
        hb[(size_t)s * DIM + d] = (__bf16)o;
    }
}

// ---------------- residual add + LN (in-place on h; writes f32 + bf16) ----------
__global__ __launch_bounds__(256) void add_ln_kernel(
    float* __restrict__ h, const float* __restrict__ r,
    const float* __restrict__ gs, const float* __restrict__ gb,
    __bf16* __restrict__ hb)
{
    __shared__ float red[256];
    int s = blockIdx.x, t = threadIdx.x;
    float v0[3]; float lsum = 0.f;
    #pragma unroll
    for (int i = 0; i < 3; i++) {
        int d = t + i * 256;
        float val = h[(size_t)s * DIM + d] + r[(size_t)s * DIM + d];
        v0[i] = val; lsum += val;
    }
    float mean = block_reduce_sum(lsum, red) * (1.0f / DIM);
    float lv = 0.f;
    #pragma unroll
    for (int i = 0; i < 3; i++) { float dv = v0[i] - mean; lv += dv * dv; }
    float var = block_reduce_sum(lv, red) * (1.0f / DIM);
    float rstd = rsqrtf(var + 1e-5f);
    #pragma unroll
    for (int i = 0; i < 3; i++) {
        int d = t + i * 256;
        float o = (v0[i] - mean) * rstd * gs[d] + gb[d];
        h[(size_t)s * DIM + d] = o;
        hb[(size_t)s * DIM + d] = (__bf16)o;
    }
}

// ---------------- weight transpose-convert: f32 [K][N] -> bf16 [N][K] ----------
struct Ptr7 { const float* p[7]; };
__global__ __launch_bounds__(256) void transpose_w_kernel(
    Ptr7 in, __bf16* __restrict__ out, int K, int N)
{
    __shared__ float tile[32][33];
    const float* src = in.p[blockIdx.z];
    __bf16* dst = out + (size_t)blockIdx.z * K * N;
    int bx = blockIdx.x * 32;   // N offset
    int by = blockIdx.y * 32;   // K offset
    int tx = threadIdx.x & 31, ty = threadIdx.x >> 5;
    #pragma unroll
    for (int i = 0; i < 32; i += 8)
        tile[ty + i][tx] = src[(size_t)(by + ty + i) * N + bx + tx];
    __syncthreads();
    #pragma unroll
    for (int i = 0; i < 32; i += 8)
        dst[(size_t)(bx + ty + i) * K + by + tx] = (__bf16)tile[tx][ty + i];
}

// ---------------- bf16 MFMA GEMM: out = f((A @ Bt^T + bias) * scale) -----------
// A: [M][K] bf16; Bt: [N][K] bf16. Outputs: Cf (f32 [M][N]), Cb (bf16 [M][N]),
// Ct (bf16 [N][M] column-major, i.e. transposed-by-head when N=DIM).
#define TM 128
#define TN 128
#define TK 32
__global__ __launch_bounds__(256) void mfma_gemm(
    const __bf16* __restrict__ A, const __bf16* __restrict__ Bt,
    const float* __restrict__ bias, float* __restrict__ Cf,
    __bf16* __restrict__ Cb, __bf16* __restrict__ Ct,
    int M, int N, int K, float scale, int act)
{
    __shared__ __align__(16) __bf16 As[TM * TK];
    __shared__ __align__(16) __bf16 Bs[TN * TK];
    int t = threadIdx.x;
    int wave = t >> 6, lane = t & 63;
    int bm = blockIdx.x * TM, bn = blockIdx.y * TN;
    int wm = (wave & 1) * 64, wn = (wave >> 1) * 64;

    floatx4 acc[4][4];
    #pragma unroll
    for (int i = 0; i < 4; i++)
        #pragma unroll
        for (int j = 0; j < 4; j++) { floatx4 z = {0.f, 0.f, 0.f, 0.f}; acc[i][j] = z; }

    const int c0 = wave * 128 + lane;
    const int c1 = c0 + 64;
    const int r0 = c0 >> 2, kc0 = (c0 & 3) * 8;
    const int r1 = c1 >> 2, kc1 = (c1 & 3) * 8;
    __bf16* lA0 = &As[(size_t)(wave * 128) * 8];
    __bf16* lA1 = &As[(size_t)(wave * 128 + 64) * 8];
    __bf16* lB0 = &Bs[(size_t)(wave * 128) * 8];
    __bf16* lB1 = &Bs[(size_t)(wave * 128 + 64) * 8];

    const int mrow = lane & 15, kq = (lane >> 4) * 8;

    for (int k0 = 0; k0 < K; k0 += TK) {
        __syncthreads();
        async16(A  + (size_t)(bm + r0) * K + k0 + kc0, lA0);
        async16(A  + (size_t)(bm + r1) * K + k0 + kc1, lA1);
        async16(Bt + (size_t)(bn + r0) * K + k0 + kc0, lB0);
        async16(Bt + (size_t)(bn + r1) * K + k0 + kc1, lB1);
        __builtin_amdgcn_s_waitcnt(0x0f70);   // vmcnt(0)
        __syncthreads();
        bf16x8 af[4], bfr[4];
        #pragma unroll
        for (int mt = 0; mt < 4; mt++)
            af[mt] = *(const bf16x8*)&As[(wm + mt * 16 + mrow) * TK + kq];
        #pragma unroll
        for (int nt = 0; nt < 4; nt++)
            bfr[nt] = *(const bf16x8*)&Bs[(wn + nt * 16 + mrow) * TK + kq];
        #pragma unroll
        for (int mt = 0; mt < 4; mt++)
            #pragma unroll
            for (int nt = 0; nt < 4; nt++)
                acc[mt][nt] = __builtin_amdgcn_mfma_f32_16x16x32_bf16(
                    af[mt], bfr[nt], acc[mt][nt], 0, 0, 0);
    }

    int col_l = lane & 15, row_l = (lane >> 4) * 4;
    #pragma unroll
    for (int nt = 0; nt < 4; nt++) {
        int col = bn + wn + nt * 16 + col_l;
        float bs = bias[col];
        #pragma unroll
        for (int mt = 0; mt < 4; mt++) {
            floatx4 v = acc[mt][nt];
            int row0 = bm + wm + mt * 16 + row_l;
            float o4[4];
            #pragma unroll
            for (int rr = 0; rr < 4; rr++) {
                float o = (v[rr] + bs) * scale;
                if (act) o = gelu_f(o);
                o4[rr] = o;
            }
            if (Cf) {
                #pragma unroll
                for (int rr = 0; rr < 4; rr++)
                    Cf[(size_t)(row0 + rr) * N + col] = o4[rr];
            }
            if (Cb) {
                #pragma unroll
                for (int rr = 0; rr < 4; rr++)
                    Cb[(size_t)(row0 + rr) * N + col] = (__bf16)o4[rr];
            }
            if (Ct) {
                __bf16 t4[4];
                #pragma unroll
                for (int rr = 0; rr < 4; rr++) t4[rr] = (__bf16)o4[rr];
                *(uint2*)&Ct[(size_t)col * M + row0] = *(uint2*)t4;
            }
        }
    }
}

// ---------------- f32 tiled GEMM (tiny qg projection; adds bf16 out) -----------
#define BM 64
#define BN 64
#define BK 16
#define LDA (BM + 4)
#define LDB (BN + 4)
__global__ __launch_bounds__(256) void gemm_kernel(
    const float* __restrict__ A, const float* __restrict__ W,
    const float* __restrict__ bias, float* __restrict__ Cmat,
    __bf16* __restrict__ Cbf, int M, int N, int K, float scale, int act)
{
    __shared__ float As[BK * LDA];
    __shared__ float Bs[BK * LDB];
    int bm = blockIdx.x * BM, bn = blockIdx.y * BN;
    int t = threadIdx.x;
    int tx = t & 15, ty = t >> 4;
    float acc[4][4];
    #pragma unroll
    for (int i = 0; i < 4; i++)
        #pragma unroll
        for (int j = 0; j < 4; j++) acc[i][j] = 0.f;

    int ar = t >> 2, ac = (t & 3) * 4;
    int brk = t >> 4, bcn = (t & 15) * 4;

    for (int k0 = 0; k0 < K; k0 += BK) {
        float4 a4 = *(const float4*)(A + (size_t)(bm + ar) * K + k0 + ac);
        float4 b4 = *(const float4*)(W + (size_t)(k0 + brk) * N + bn + bcn);
        __syncthreads();
        As[(ac + 0) * LDA + ar] = a4.x;
        As[(ac + 1) * LDA + ar] = a4.y;
        As[(ac + 2) * LDA + ar] = a4.z;
        As[(ac + 3) * LDA + ar] = a4.w;
        *(float4*)&Bs[brk * LDB + bcn] = b4;
        __syncthreads();
        #pragma unroll
        for (int kk = 0; kk < BK; kk++) {
            float4 av = *(const float4*)&As[kk * LDA + ty * 4];
            float4 bv = *(const float4*)&Bs[kk * LDB + tx * 4];
            acc[0][0] += av.x * bv.x; acc[0][1] += av.x * bv.y;
            acc[0][2] += av.x * bv.z; acc[0][3] += av.x * bv.w;
            acc[1][0] += av.y * bv.x; acc[1][1] += av.y * bv.y;
            acc[1][2] += av.y * bv.z; acc[1][3] += av.y * bv.w;
            acc[2][0] += av.z * bv.x; acc[2][1] += av.z * bv.y;
            acc[2][2] += av.z * bv.z; acc[2][3] += av.z * bv.w;
            acc[3][0] += av.w * bv.x; acc[3][1] += av.w * bv.y;
            acc[3][2] += av.w * bv.z; acc[3][3] += av.w * bv.w;
        }
    }
    float bias4[4];
    #pragma unroll
    for (int j = 0; j < 4; j++) bias4[j] = bias[bn + tx * 4 + j];
    #pragma unroll
    for (int i = 0; i < 4; i++) {
        float4 o;
        o.x = (acc[i][0] + bias4[0]) * scale;
        o.y = (acc[i][1] + bias4[1]) * scale;
        o.z = (acc[i][2] + bias4[2]) * scale;
        o.w = (acc[i][3] + bias4[3]) * scale;
        if (act) { o.x = gelu_f(o.x); o.y = gelu_f(o.y); o.z = gelu_f(o.z); o.w = gelu_f(o.w); }
        *(float4*)(Cmat + (size_t)(bm + ty * 4 + i) * N + bn + tx * 4) = o;
        if (Cbf) {
            __bf16* cb = Cbf + (size_t)(bm + ty * 4 + i) * N + bn + tx * 4;
            cb[0] = (__bf16)o.x; cb[1] = (__bf16)o.y; cb[2] = (__bf16)o.z; cb[3] = (__bf16)o.w;
        }
    }
}

// ---------------- MFMA band + global-key attention (flash) ----------------
// grid (NCHK, NH, 2); block 128 (2 waves). Wave handles 64 queries.
// Tiles: tt=0 global keys (gathered), tt=1..10 band tiles jt = bz*2 + tt-1.
__global__ __launch_bounds__(128) void band_attn_mfma(
    const __bf16* __restrict__ qb, const __bf16* __restrict__ kb,
    const __bf16* __restrict__ vb, const __bf16* __restrict__ vtg,
    const int* __restrict__ clss, const int* __restrict__ mask_src,
    const int* __restrict__ is_glb, __bf16* __restrict__ outb)
{
    __shared__ __align__(16) __bf16 Kt[4096];           // panels [p][key(64)][d(32)]
    __shared__ __align__(16) __bf16 Vt[4096];           // panels [p][d(64)][key(32)]
    __shared__ __align__(16) __bf16 Ps[2][64 * PS_LD];  // per-wave P tile (padded)
    __shared__ int kvalid[64];
    __shared__ int gpos[64];

    const int n = blockIdx.x, hh = blockIdx.y, bz = blockIdx.z;
    const int t = threadIdx.x, wave = t >> 6, lane = t & 63;
    const int quad = lane >> 4, col_l = lane & 15, row_l = quad * 4;
    const int qw = bz * 128 + wave * 64;
    const int l3 = lane & 3, l2h = lane >> 2, l7 = lane & 7, l3h = lane >> 3;

    if (t < 64) gpos[t] = clss[t];

    // Q fragments (A-operand) from global
    bf16x8 aq[4][2];
    #pragma unroll
    for (int mt = 0; mt < 4; mt++) {
        const __bf16* qp = qb + (size_t)(n * CHK + qw + mt * 16 + col_l) * DIM + hh * HDIM;
        aq[mt][0] = *(const bf16x8*)(qp + quad * 8);
        aq[mt][1] = *(const bf16x8*)(qp + 32 + quad * 8);
    }

    floatx4 oacc[4][4];
    #pragma unroll
    for (int i = 0; i < 4; i++)
        #pragma unroll
        for (int j = 0; j < 4; j++) { floatx4 z = {0.f,0.f,0.f,0.f}; oacc[i][j] = z; }
    float mrow[16], lrow[16];
    #pragma unroll
    for (int r = 0; r < 16; r++) { mrow[r] = -1e30f; lrow[r] = 0.f; }

    __bf16* PsW = Ps[wave];

    for (int tt = 0; tt < 11; tt++) {
        __syncthreads();   // prev tile fully consumed; gpos visible at tt=0
        int jbase = -1;
        if (tt == 0) {
            if (t < 64) kvalid[t] = (mask_src[gpos[t]] > 0) ? 1 : 0;
            // K panels (gathered rows)
            #pragma unroll
            for (int ii = 0; ii < 4; ii++) {
                int p = ii >> 1;
                int kbase = wave * 32 + (ii & 1) * 16;
                int key = kbase + l2h;
                int pos = gpos[key];
                const __bf16* g = kb + (size_t)pos * DIM + hh * HDIM + p * 32 + l3 * 8;
                async16(g, &Kt[p * 2048 + kbase * 32]);
            }
            // V rows (gathered) -> scratch (Ps[0] region), transposed later
            __bf16* Vrow = &Ps[0][0];
            #pragma unroll
            for (int ii = 0; ii < 4; ii++) {
                int kbase = wave * 32 + ii * 8;
                int key = kbase + l3h;
                int pos = gpos[key];
                const __bf16* g = vb + (size_t)pos * DIM + hh * HDIM + l7 * 8;
                async16(g, &Vrow[kbase * 64]);
            }
        } else {
            jbase = (bz * 2 + tt - 1) * 64;
            if (t < 64) {
                int pos = n * CHK + jbase + t - CHK;
                kvalid[t] = (pos >= 0 && pos < SEQ && mask_src[pos] > 0
                             && is_glb[pos] == 0) ? 1 : 0;
            }
            int s0 = n * CHK + jbase - CHK;
            #pragma unroll
            for (int ii = 0; ii < 4; ii++) {
                int p = ii >> 1;
                int kbase = wave * 32 + (ii & 1) * 16;
                int key = kbase + l2h;
                int pos = s0 + key; pos = min(max(pos, 0), SEQ - 1);
                const __bf16* g = kb + (size_t)pos * DIM + hh * HDIM + p * 32 + l3 * 8;
                async16(g, &Kt[p * 2048 + kbase * 32]);
            }
            #pragma unroll
            for (int ii = 0; ii < 4; ii++) {
                int p = ii >> 1;
                int dbase = wave * 32 + (ii & 1) * 16;
                int d = dbase + l2h;
                int s = s0 + p * 32 + l3 * 8; s = min(max(s, 0), SEQ - 8);
                const __bf16* g = vtg + (size_t)(hh * HDIM + d) * SEQ + s;
                async16(g, &Vt[p * 2048 + dbase * 32]);
            }
        }
        __builtin_amdgcn_s_waitcnt(0x0f70);
        __syncthreads();
        if (tt == 0) {
            // transpose gathered V rows -> Vt panels
            const __bf16* Vrow = &Ps[0][0];
            for (int idx = t; idx < 4096; idx += 128) {
                int key = idx >> 6, d = idx & 63;
                Vt[(key >> 5) * 2048 + d * 32 + (key & 31)] = Vrow[idx];
            }
            __syncthreads();
        } else {
            // wave-level relevance (uniform): skip compute, keep barriers aligned
            if (jbase + 63 < qw || jbase > qw + 575) continue;
        }

        bf16x8 bk[4][2];
        #pragma unroll
        for (int nt = 0; nt < 4; nt++) {
            bk[nt][0] = *(const bf16x8*)&Kt[(nt * 16 + col_l) * 32 + quad * 8];
            bk[nt][1] = *(const bf16x8*)&Kt[2048 + (nt * 16 + col_l) * 32 + quad * 8];
        }
        int kv[4];
        #pragma unroll
        for (int nt = 0; nt < 4; nt++) kv[nt] = kvalid[nt * 16 + col_l];

        #pragma unroll
        for (int mt = 0; mt < 4; mt++) {
            floatx4 s[4];
            #pragma unroll
            for (int nt = 0; nt < 4; nt++) {
                floatx4 z = {0.f,0.f,0.f,0.f};
                z = __builtin_amdgcn_mfma_f32_16x16x32_bf16(aq[mt][0], bk[nt][0], z, 0,0,0);
                z = __builtin_amdgcn_mfma_f32_16x16x32_bf16(aq[mt][1], bk[nt][1], z, 0,0,0);
                s[nt] = z;
            }
            #pragma unroll
            for (int nt = 0; nt < 4; nt++)
                #pragma unroll
                for (int rr = 0; rr < 4; rr++) {
                    int ok = kv[nt];
                    if (tt != 0) {
                        int i = qw + mt * 16 + row_l + rr;
                        int rel = jbase + nt * 16 + col_l - i;
                        ok = ok && (rel >= 0) && (rel <= 2 * WINR);
                    }
                    if (!ok) s[nt][rr] = -1e30f;
                }
            #pragma unroll
            for (int rr = 0; rr < 4; rr++) {
                float rm = fmaxf(fmaxf(s[0][rr], s[1][rr]), fmaxf(s[2][rr], s[3][rr]));
                rm = fmaxf(rm, __shfl_xor(rm, 1));
                rm = fmaxf(rm, __shfl_xor(rm, 2));
                rm = fmaxf(rm, __shfl_xor(rm, 4));
                rm = fmaxf(rm, __shfl_xor(rm, 8));
                int ri = mt * 4 + rr;
                float mo = mrow[ri];
                float mn = fmaxf(mo, rm);
                float alpha = __expf(mo - mn);
                float rsum = 0.f;
                #pragma unroll
                for (int nt = 0; nt < 4; nt++) {
                    float sv = s[nt][rr];
                    float p = __expf(sv - mn);
                    p = (sv > -1e29f) ? p : 0.f;
                    rsum += p;
                    PsW[(mt * 16 + row_l + rr) * PS_LD + nt * 16 + col_l] = (__bf16)p;
                }
                rsum += __shfl_xor(rsum, 1);
                rsum += __shfl_xor(rsum, 2);
                rsum += __shfl_xor(rsum, 4);
                rsum += __shfl_xor(rsum, 8);
                lrow[ri] = lrow[ri] * alpha + rsum;
                mrow[ri] = mn;
                #pragma unroll
                for (int nt = 0; nt < 4; nt++) oacc[mt][nt][rr] *= alpha;
            }
        }
        // PV
        bf16x8 bv[4][2], ap[4][2];
        #pragma unroll
        for (int nt = 0; nt < 4; nt++) {
            bv[nt][0] = *(const bf16x8*)&Vt[(nt * 16 + col_l) * 32 + quad * 8];
            bv[nt][1] = *(const bf16x8*)&Vt[2048 + (nt * 16 + col_l) * 32 + quad * 8];
        }
        #pragma unroll
        for (int mt = 0; mt < 4; mt++) {
            ap[mt][0] = *(const bf16x8*)&PsW[(mt * 16 + col_l) * PS_LD + quad * 8];
            ap[mt][1] = *(const bf16x8*)&PsW[(mt * 16 + col_l) * PS_LD + 32 + quad * 8];
        }
        #pragma unroll
        for (int mt = 0; mt < 4; mt++)
            #pragma unroll
            for (int nt = 0; nt < 4; nt++) {
                oacc[mt][nt] = __builtin_amdgcn_mfma_f32_16x16x32_bf16(
                    ap[mt][0], bv[nt][0], oacc[mt][nt], 0,0,0);
                oacc[mt][nt] = __builtin_amdgcn_mfma_f32_16x16x32_bf16(
                    ap[mt][1], bv[nt][1], oacc[mt][nt], 0,0,0);
            }
    }

    #pragma unroll
    for (int mt = 0; mt < 4; mt++)
        #pragma unroll
        for (int nt = 0; nt < 4; nt++)
            #pragma unroll
            for (int rr = 0; rr < 4; rr++) {
                int ri = mt * 4 + rr;
                float o = oacc[mt][nt][rr] / lrow[ri];
                int srow = n * CHK + qw + mt * 16 + row_l + rr;
                outb[(size_t)srow * DIM + hh * HDIM + nt * 16 + col_l] = (__bf16)o;
            }
}

// ---------------- global-query flash attention, split-K partials ----------------
// grid (NH, 16 splits); block 256 (4 waves, each 16 queries). 256 keys/split.
__global__ __launch_bounds__(256) void gq_flash(
    const __bf16* __restrict__ qgbb, const __bf16* __restrict__ kgb,
    const __bf16* __restrict__ vgt, const int* __restrict__ mask_src,
    float* __restrict__ Opart, float* __restrict__ mlpart)
{
    __shared__ __align__(16) __bf16 Kg[4096];
    __shared__ __align__(16) __bf16 Vg[4096];
    __shared__ __align__(16) __bf16 Psg[4][16 * PS_LD];
    __shared__ int kvalid[64];
    const int hh = blockIdx.x, sp = blockIdx.y;
    const int t = threadIdx.x, wave = t >> 6, lane = t & 63;
    const int quad = lane >> 4, col_l = lane & 15, row_l = quad * 4;
    const int l3 = lane & 3, l2h = lane >> 2;

    bf16x8 aq[2];
    {
        const __bf16* qp = qgbb + (size_t)(wave * 16 + col_l) * DIM + hh * HDIM;
        aq[0] = *(const bf16x8*)(qp + quad * 8);
        aq[1] = *(const bf16x8*)(qp + 32 + quad * 8);
    }
    floatx4 oacc[4];
    #pragma unroll
    for (int i = 0; i < 4; i++) { floatx4 z = {0.f,0.f,0.f,0.f}; oacc[i] = z; }
    float m4[4], l4[4];
    #pragma unroll
    for (int r = 0; r < 4; r++) { m4[r] = -1e30f; l4[r] = 0.f; }
    __bf16* PsW = Psg[wave];

    for (int tt = 0; tt < 4; tt++) {
        int pos0 = sp * 256 + tt * 64;
        __syncthreads();
        if (t < 64) kvalid[t] = (mask_src[pos0 + t] > 0) ? 1 : 0;
        #pragma unroll
        for (int ii = 0; ii < 2; ii++) {
            int gid = wave * 2 + ii;
            int p = gid >> 2, kbase = (gid & 3) * 16;
            int key = kbase + l2h;
            const __bf16* g = kgb + (size_t)(pos0 + key) * DIM + hh * HDIM + p * 32 + l3 * 8;
            async16(g, &Kg[p * 2048 + kbase * 32]);
        }
        #pragma unroll
        for (int ii = 0; ii < 2; ii++) {
            int gid = wave * 2 + ii;
            int p = gid >> 2, dbase = (gid & 3) * 16;
            int d = dbase + l2h;
            const __bf16* g = vgt + (size_t)(hh * HDIM + d) * SEQ + pos0 + p * 32 + l3 * 8;
            async16(g, &Vg[p * 2048 + dbase * 32]);
        }
        __builtin_amdgcn_s_waitcnt(0x0f70);
        __syncthreads();

        floatx4 s[4];
        #pragma unroll
        for (int nt = 0; nt < 4; nt++) {
            bf16x8 b0 = *(const bf16x8*)&Kg[(nt * 16 + col_l) * 32 + quad * 8];
            bf16x8 b1 = *(const bf16x8*)&Kg[2048 + (nt * 16 + col_l) * 32 + quad * 8];
            floatx4 z = {0.f,0.f,0.f,0.f};
            z = __builtin_amdgcn_mfma_f32_16x16x32_bf16(aq[0], b0, z, 0,0,0);
            z = __builtin_amdgcn_mfma_f32_16x16x32_bf16(aq[1], b1, z, 0,0,0);
            s[nt] = z;
        }
        int kv[4];
        #pragma unroll
        for (int nt = 0; nt < 4; nt++) kv[nt] = kvalid[nt * 16 + col_l];
        #pragma unroll
        for (int nt = 0; nt < 4; nt++)
            #pragma unroll
            for (int rr = 0; rr < 4; rr++)
                if (!kv[nt]) s[nt][rr] = -1e30f;
        #pragma unroll
        for (int rr = 0; rr < 4; rr++) {
            float rm = fmaxf(fmaxf(s[0][rr], s[1][rr]), fmaxf(s[2][rr], s[3][rr]));
            rm = fmaxf(rm, __shfl_xor(rm, 1));
            rm = fmaxf(rm, __shfl_xor(rm, 2));
            rm = fmaxf(rm, __shfl_xor(rm, 4));
            rm = fmaxf(rm, __shfl_xor(rm, 8));
            float mo = m4[rr];
            float mn = fmaxf(mo, rm);
            float alpha = __expf(mo - mn);
            float rsum = 0.f;
            #pragma unroll
            for (int nt = 0; nt < 4; nt++) {
                float sv = s[nt][rr];
                float p = __expf(sv - mn);
                p = (sv > -1e29f) ? p : 0.f;
                rsum += p;
                PsW[(row_l + rr) * PS_LD + nt * 16 + col_l] = (__bf16)p;
            }
            rsum += __shfl_xor(rsum, 1);
            rsum += __shfl_xor(rsum, 2);
            rsum += __shfl_xor(rsum, 4);
            rsum += __shfl_xor(rsum, 8);
            l4[rr] = l4[rr] * alpha + rsum;
            m4[rr] = mn;
            #pragma unroll
            for (int nt = 0; nt < 4; nt++) oacc[nt][rr] *= alpha;
        }
        bf16x8 ap0 = *(const bf16x8*)&PsW[col_l * PS_LD + quad * 8];
        bf16x8 ap1 = *(const bf16x8*)&PsW[col_l * PS_LD + 32 + quad * 8];
        #pragma unroll
        for (int nt = 0; nt < 4; nt++) {
            bf16x8 b0 = *(const bf16x8*)&Vg[(nt * 16 + col_l) * 32 + quad * 8];
            bf16x8 b1 = *(const bf16x8*)&Vg[2048 + (nt * 16 + col_l) * 32 + quad * 8];
            oacc[nt] = __builtin_amdgcn_mfma_f32_16x16x32_bf16(ap0, b0, oacc[nt], 0,0,0);
            oacc[nt] = __builtin_amdgcn_mfma_f32_16x16x32_bf16(ap1, b1, oacc[nt], 0,0,0);
        }
    }
    size_t base = (size_t)(hh * 16 + sp) * 64;
    #pragma unroll
    for (int nt = 0; nt < 4; nt++)
        #pragma unroll
        for (int rr = 0; rr < 4; rr++)
            Opart[(base + wave * 16 + row_l + rr) * 64 + nt * 16 + col_l] = oacc[nt][rr];
    if (col_l == 0) {
        #pragma unroll
        for (int rr = 0; rr < 4; rr++) {
            mlpart[(base + wave * 16 + row_l + rr) * 2]     = m4[rr];
            mlpart[(base + wave * 16 + row_l + rr) * 2 + 1] = l4[rr];
        }
    }
}

// ---------------- merge split-K partials ----------------
__global__ __launch_bounds__(64) void gq_merge(
    const float* __restrict__ Opart, const float* __restrict__ mlpart,
    float* __restrict__ ogb)
{
    int hh = blockIdx.x, q = blockIdx.y, d = threadIdx.x;
    float M = -1e30f;
    for (int s = 0; s < 16; s++)
        M = fmaxf(M, mlpart[(((size_t)hh * 16 + s) * 64 + q) * 2]);
    float L = 0.f, acc = 0.f;
    for (int s = 0; s < 16; s++) {
        size_t b = ((size_t)hh * 16 + s) * 64 + q;
        float w = __expf(mlpart[b * 2] - M);
        L += mlpart[b * 2 + 1] * w;
        acc += w * Opart[b * 64 + d];
    }
    ogb[(size_t)q * DIM + hh * HDIM + d] = acc / L;
}

// ---------------- gather / scatter rows ----------------
__global__ __launch_bounds__(256) void gather_rows_kernel(
    const float* __restrict__ src, const int* __restrict__ idx, float* __restrict__ dst)
{
    int i = blockIdx.x, t = threadIdx.x;
    int p = idx[i];
    #pragma unroll
    for (int c = 0; c < 3; c++)
        dst[(size_t)i * DIM + t + c * 256] = src[(size_t)p * DIM + t + c * 256];
}
__global__ __launch_bounds__(256) void scatter_rows_bf16_kernel(
    const float* __restrict__ src, const int* __restrict__ idx, __bf16* __restrict__ dst)
{
    int i = blockIdx.x, t = threadIdx.x;
    int p = idx[i];
    #pragma unroll
    for (int c = 0; c < 3; c++)
        dst[(size_t)p * DIM + t + c * 256] = (__bf16)src[(size_t)i * DIM + t + c * 256];
}

// ---------------- is_glb build ----------------
__global__ __launch_bounds__(256) void build_glb_kernel(
    const int* __restrict__ clss, int* __restrict__ is_glb)
{
    int t = threadIdx.x;
    for (int s0 = t; s0 < SEQ; s0 += 256) is_glb[s0] = 0;
    __syncthreads();
    if (t < NCLS) is_glb[clss[t]] = 1;
}

// ---------------- host launcher ----------------
extern "C" void kernel_launch(void* const* d_in, const int* in_sizes, int n_in,
                              void* d_out, int out_size, void* d_ws, size_t ws_size,
                              hipStream_t stream)
{
    const int* x        = (const int*)d_in[0];
    const int* mask_src = (const int*)d_in[1];
    const int* clss     = (const int*)d_in[2];
    const int* segs     = (const int*)d_in[3];
    const float* word_emb = (const float*)d_in[4];
    const float* pos_emb  = (const float*)d_in[5];
    const float* type_emb = (const float*)d_in[6];
    const float* ln_e_s   = (const float*)d_in[7];
    const float* ln_e_b   = (const float*)d_in[8];
    const float* Wq  = (const float*)d_in[9];
    const float* bq  = (const float*)d_in[10];
    const float* Wk  = (const float*)d_in[11];
    const float* bk  = (const float*)d_in[12];
    const float* Wv  = (const float*)d_in[13];
    const float* bv  = (const float*)d_in[14];
    const float* Wqg = (const float*)d_in[15];
    const float* bqg = (const float*)d_in[16];
    const float* Wkg = (const float*)d_in[17];
    const float* bkg = (const float*)d_in[18];
    const float* Wvg = (const float*)d_in[19];
    const float* bvg = (const float*)d_in[20];
    const float* Wo  = (const float*)d_in[21];
    const float* bo  = (const float*)d_in[22];
    const float* ln1_s = (const float*)d_in[23];
    const float* ln1_b = (const float*)d_in[24];
    const float* Wf1 = (const float*)d_in[25];
    const float* bf1 = (const float*)d_in[26];
    const float* Wf2 = (const float*)d_in[27];
    const float* bf2 = (const float*)d_in[28];
    const float* ln2_s = (const float*)d_in[29];
    const float* ln2_b = (const float*)d_in[30];

    float* ws = (float*)d_ws;
    float*  h    = ws;                                  // slot0
    float*  s4   = ws + SD;                             // slot1 (proj / ffn2 out)
    __bf16* hb   = (__bf16*)(ws + 2 * SD);              // slot2 lo
    __bf16* b6b  = (__bf16*)(ws + 2 * SD) + SD;         // slot2 hi (attn out bf16)
    __bf16* qb   = (__bf16*)(ws + 3 * SD);              // slot3 lo
    __bf16* kb   = (__bf16*)(ws + 3 * SD) + SD;         // slot3 hi
    __bf16* vb   = (__bf16*)(ws + 4 * SD);              // slot4 lo
    __bf16* vtg  = (__bf16*)(ws + 4 * SD) + SD;         // slot4 hi (v transposed)
    __bf16* kgb  = (__bf16*)(ws + 5 * SD);              // slot5 lo
    __bf16* vgt  = (__bf16*)(ws + 5 * SD) + SD;         // slot5 hi (vg transposed)
    __bf16* gelu_b = qb;                                // FFN phase overlays slots 3-4
    float* extra = ws + 6 * SD;                         // slot6
    __bf16* Wbf   = (__bf16*)extra;                     // <= 6*DD bf16 = 1,769,472 f32
    float* Opart  = extra + 1769472;                    // 786,432 f32
    float* mlpart = Opart + 786432;                     // 24,576 f32
    float* hgb    = mlpart + 24576;                     // 49,152
    float* qgb    = hgb + 49152;                        // 49,152
    __bf16* qgbb  = (__bf16*)(qgb + 49152);             // 24,576 f32 worth
    float* ogb    = qgb + 49152 + 24576;                // 49,152
    int*   isglb  = (int*)(ogb + 49152);

    build_glb_kernel<<<1, 256, 0, stream>>>(clss, isglb);
    embed_ln_kernel<<<SEQ, 256, 0, stream>>>(x, segs, word_emb, pos_emb, type_emb,
                                             ln_e_s, ln_e_b, h, hb);

    const size_t DD = (size_t)DIM * DIM;
    for (int l = 0; l < NLAYER; l++) {
        const float* bq_l  = bq  + (size_t)l * DIM;
        const float* bk_l  = bk  + (size_t)l * DIM;
        const float* bv_l  = bv  + (size_t)l * DIM;
        const float* bqg_l = bqg + (size_t)l * DIM;
        const float* bkg_l = bkg + (size_t)l * DIM;
        const float* bvg_l = bvg + (size_t)l * DIM;
        const float* bo_l  = bo  + (size_t)l * DIM;
        const float* bf1_l = bf1 + (size_t)l * FFD;
        const float* bf2_l = bf2 + (size_t)l * DIM;

        Ptr7 wp;
        wp.p[0] = Wq  + l * DD; wp.p[1] = Wk  + l * DD; wp.p[2] = Wv  + l * DD;
        wp.p[3] = Wkg + l * DD; wp.p[4] = Wvg + l * DD; wp.p[5] = Wo  + l * DD;
        wp.p[6] = nullptr;
        transpose_w_kernel<<<dim3(DIM / 32, DIM / 32, 6), 256, 0, stream>>>(wp, Wbf, DIM, DIM);

        dim3 gDD(SEQ / TM, DIM / TN);
        mfma_gemm<<<gDD, 256, 0, stream>>>(hb, Wbf + 0 * DD, bq_l, nullptr, qb, nullptr,
                                           SEQ, DIM, DIM, QSCALE, 0);
        mfma_gemm<<<gDD, 256, 0, stream>>>(hb, Wbf + 1 * DD, bk_l, nullptr, kb, nullptr,
                                           SEQ, DIM, DIM, 1.0f, 0);
        mfma_gemm<<<gDD, 256, 0, stream>>>(hb, Wbf + 2 * DD, bv_l, nullptr, vb, vtg,
                                           SEQ, DIM, DIM, 1.0f, 0);
        band_attn_mfma<<<dim3(NCHK, NH, 2), 128, 0, stream>>>(qb, kb, vb, vtg, clss,
                                                              mask_src, isglb, b6b);
        // global-query path
        mfma_gemm<<<gDD, 256, 0, stream>>>(hb, Wbf + 3 * DD, bkg_l, nullptr, kgb, nullptr,
                                           SEQ, DIM, DIM, 1.0f, 0);
        mfma_gemm<<<gDD, 256, 0, stream>>>(hb, Wbf + 4 * DD, bvg_l, nullptr, nullptr, vgt,
                                           SEQ, DIM, DIM, 1.0f, 0);
        gather_rows_kernel<<<NCLS, 256, 0, stream>>>(h, clss, hgb);
        gemm_kernel<<<dim3(NCLS / BM, DIM / BN), 256, 0, stream>>>(
            hgb, Wqg + l * DD, bqg_l, qgb, qgbb, NCLS, DIM, DIM, QSCALE, 0);
        gq_flash<<<dim3(NH, 16), 256, 0, stream>>>(qgbb, kgb, vgt, mask_src, Opart, mlpart);
        gq_merge<<<dim3(NH, NCLS), 64, 0, stream>>>(Opart, mlpart, ogb);
        scatter_rows_bf16_kernel<<<NCLS, 256, 0, stream>>>(ogb, clss, b6b);
        // output projection + LN1
        mfma_gemm<<<gDD, 256, 0, stream>>>(b6b, Wbf + 5 * DD, bo_l, s4, nullptr, nullptr,
                                           SEQ, DIM, DIM, 1.0f, 0);
        add_ln_kernel<<<SEQ, 256, 0, stream>>>(h, s4, ln1_s + (size_t)l * DIM,
                                               ln1_b + (size_t)l * DIM, hb);
        // FFN
        Ptr7 wf1; wf1.p[0] = Wf1 + (size_t)l * DIM * FFD;
        transpose_w_kernel<<<dim3(FFD / 32, DIM / 32, 1), 256, 0, stream>>>(wf1, Wbf, DIM, FFD);
        mfma_gemm<<<dim3(SEQ / TM, FFD / TN), 256, 0, stream>>>(
            hb, Wbf, bf1_l, nullptr, gelu_b, nullptr, SEQ, FFD, DIM, 1.0f, 1);
        Ptr7 wf2; wf2.p[0] = Wf2 + (size_t)l * FFD * DIM;
        transpose_w_kernel<<<dim3(DIM / 32, FFD / 32, 1), 256, 0, stream>>>(wf2, Wbf, FFD, DIM);
        mfma_gemm<<<dim3(SEQ / TM, DIM / TN), 256, 0, stream>>>(
            gelu_b, Wbf, bf2_l, s4, nullptr, nullptr, SEQ, DIM, FFD, 1.0f, 0);
        add_ln_kernel<<<SEQ, 256, 0, stream>>>(h, s4, ln2_s + (size_t)l * DIM,
                                               ln2_b + (size_t)l * DIM, hb);
    }

    hipMemcpyAsync(d_out, h, SD * sizeof(float), hipMemcpyDeviceToDevice, stream);
}

// Round 4
// 947.412 us; speedup vs baseline: 3.6060x; 1.1877x over previous
//
#include <hip/hip_runtime.h>
#include <hip/hip_bf16.h>
#include <cstdint>

#define SEQ  4096
#define DIM  768
#define NH   12
#define HDIM 64
#define NLAYER 2
#define CHK  256
#define WINR 256
#define NCLS 64
#define NCHK 16
#define FFD  3072
#define QSCALE 0.125f
#define LOG2E 1.44269504f
#define QSC2 (QSCALE * LOG2E)
#define SD ((size_t)SEQ * DIM)
#define PS_LD 72
#define TK 32

typedef __attribute__((__vector_size__(16))) float floatx4;
typedef __attribute__((ext_vector_type(8))) __bf16 bf16x8;

__device__ __forceinline__ void async16(const void* g, void* l) {
    __builtin_amdgcn_global_load_lds(
        (const __attribute__((address_space(1))) uint32_t*)g,
        (__attribute__((address_space(3))) uint32_t*)l, 16, 0, 0);
}

__device__ __forceinline__ float block_reduce_sum(float v, float* red) {
    int t = threadIdx.x;
    red[t] = v; __syncthreads();
    #pragma unroll
    for (int st = 128; st > 0; st >>= 1) {
        if (t < st) red[t] += red[t + st];
        __syncthreads();
    }
    float r = red[0]; __syncthreads();
    return r;
}

__device__ __forceinline__ float gelu_f(float x) {
    float x3 = x * x * x;
    return 0.5f * x * (1.0f + tanhf(0.7978845608028654f * (x + 0.044715f * x3)));
}

// ---------------- embedding + LN ----------------
__global__ __launch_bounds__(256) void embed_ln_kernel(
    const int* __restrict__ x, const int* __restrict__ segs,
    const float* __restrict__ word_emb, const float* __restrict__ pos_emb,
    const float* __restrict__ type_emb, const float* __restrict__ gs,
    const float* __restrict__ gb, float* __restrict__ h, __bf16* __restrict__ hb)
{
    __shared__ float red[256];
    int s = blockIdx.x, t = threadIdx.x;
    int w = x[s], sg = segs[s];
    float v0[3]; float lsum = 0.f;
    #pragma unroll
    for (int i = 0; i < 3; i++) {
        int d = t + i * 256;
        float val = word_emb[(size_t)w * DIM + d] + pos_emb[(size_t)s * DIM + d]
                  + type_emb[(size_t)sg * DIM + d];
        v0[i] = val; lsum += val;
    }
    float mean = block_reduce_sum(lsum, red) * (1.0f / DIM);
    float lv = 0.f;
    #pragma unroll
    for (int i = 0; i < 3; i++) { float dv = v0[i] - mean; lv += dv * dv; }
    float var = block_reduce_sum(lv, red) * (1.0f / DIM);
    float rstd = rsqrtf(var + 1e-5f);
    #pragma unroll
    for (int i = 0; i < 3; i++) {
        int d = t + i * 256;
        float o = (v0[i] - mean) * rstd * gs[d] + gb[d];
        h[(size_t)s * DIM + d] = o;
        hb[(size_t)s * DIM + d] = (__bf16)o;
    }
}

// ---------------- residual add + LN ----------------
__global__ __launch_bounds__(256) void add_ln_kernel(
    float* __restrict__ h, const float* __restrict__ r,
    const float* __restrict__ gs, const float* __restrict__ gb,
    __bf16* __restrict__ hb)
{
    __shared__ float red[256];
    int s = blockIdx.x, t = threadIdx.x;
    float v0[3]; float lsum = 0.f;
    #pragma unroll
    for (int i = 0; i < 3; i++) {
        int d = t + i * 256;
        float val = h[(size_t)s * DIM + d] + r[(size_t)s * DIM + d];
        v0[i] = val; lsum += val;
    }
    float mean = block_reduce_sum(lsum, red) * (1.0f / DIM);
    float lv = 0.f;
    #pragma unroll
    for (int i = 0; i < 3; i++) { float dv = v0[i] - mean; lv += dv * dv; }
    float var = block_reduce_sum(lv, red) * (1.0f / DIM);
    float rstd = rsqrtf(var + 1e-5f);
    #pragma unroll
    for (int i = 0; i < 3; i++) {
        int d = t + i * 256;
        float o = (v0[i] - mean) * rstd * gs[d] + gb[d];
        h[(size_t)s * DIM + d] = o;
        hb[(size_t)s * DIM + d] = (__bf16)o;
    }
}

// ---------------- weight transpose-convert: f32 [K][N] -> bf16 [N][K] ----------
struct Ptr16 { const float* p[16]; };
__global__ __launch_bounds__(256) void transpose_w_kernel(
    Ptr16 in, __bf16* __restrict__ out, int K, int N)
{
    __shared__ float tile[32][33];
    const float* src = in.p[blockIdx.z];
    __bf16* dst = out + (size_t)blockIdx.z * K * N;
    int bx = blockIdx.x * 32;
    int by = blockIdx.y * 32;
    int tx = threadIdx.x & 31, ty = threadIdx.x >> 5;
    #pragma unroll
    for (int i = 0; i < 32; i += 8)
        tile[ty + i][tx] = src[(size_t)(by + ty + i) * N + bx + tx];
    __syncthreads();
    #pragma unroll
    for (int i = 0; i < 32; i += 8)
        dst[(size_t)(bx + ty + i) * K + by + tx] = (__bf16)tile[tx][ty + i];
}

// ---------------- bias concat ----------------
__global__ __launch_bounds__(256) void concat_bias_kernel(
    const float* __restrict__ bq, const float* __restrict__ bk, const float* __restrict__ bv,
    const float* __restrict__ bkg, const float* __restrict__ bvg,
    float* __restrict__ bqkv, float* __restrict__ bkgvg)
{
    int idx = blockIdx.x * 256 + threadIdx.x;
    if (idx < 2 * 2304) {
        int l = idx / 2304, c = idx % 2304, j = c / 768, d = c % 768;
        const float* s = (j == 0) ? bq : (j == 1) ? bk : bv;
        bqkv[idx] = s[l * 768 + d];
    }
    if (idx < 2 * 1536) {
        int l = idx / 1536, c = idx % 1536, j = c / 768, d = c % 768;
        const float* s = j ? bvg : bkg;
        bkgvg[idx] = s[l * 768 + d];
    }
}

// ================= generic templated MFMA GEMM =================
// A [M][K] bf16, Bt [N][K] bf16. 4 waves in 2x2; wave tile (TMv/2)x(TNv/2).
template<int TMv, int TNv>
__global__ __launch_bounds__(256) void mfma_gemm_t(
    const __bf16* __restrict__ A, const __bf16* __restrict__ Bt,
    const float* __restrict__ bias, float* __restrict__ Cf,
    __bf16* __restrict__ Cb, int M, int N, int K, float scale, int act)
{
    constexpr int AM = TMv / 32, AN = TNv / 32;
    constexpr int CA = TMv / 64, CB = TNv / 64;
    __shared__ __align__(16) __bf16 As[TMv * TK];
    __shared__ __align__(16) __bf16 Bs[TNv * TK];
    int t = threadIdx.x;
    int wave = t >> 6, lane = t & 63;
    int bm = blockIdx.x * TMv, bn = blockIdx.y * TNv;
    int wm = (wave & 1) * (TMv / 2), wn = (wave >> 1) * (TNv / 2);

    floatx4 acc[AM][AN];
    #pragma unroll
    for (int i = 0; i < AM; i++)
        #pragma unroll
        for (int j = 0; j < AN; j++) { floatx4 z = {0.f,0.f,0.f,0.f}; acc[i][j] = z; }

    const int mrow = lane & 15, kq = (lane >> 4) * 8;

    for (int k0 = 0; k0 < K; k0 += TK) {
        __syncthreads();
        #pragma unroll
        for (int i = 0; i < CA; i++) {
            int c = i * 256 + wave * 64 + lane;
            async16(A + (size_t)(bm + (c >> 2)) * K + k0 + (c & 3) * 8,
                    &As[(size_t)(i * 256 + wave * 64) * 8]);
        }
        #pragma unroll
        for (int i = 0; i < CB; i++) {
            int c = i * 256 + wave * 64 + lane;
            async16(Bt + (size_t)(bn + (c >> 2)) * K + k0 + (c & 3) * 8,
                    &Bs[(size_t)(i * 256 + wave * 64) * 8]);
        }
        __builtin_amdgcn_s_waitcnt(0x0f70);
        __syncthreads();
        bf16x8 af[AM], bfr[AN];
        #pragma unroll
        for (int mt = 0; mt < AM; mt++)
            af[mt] = *(const bf16x8*)&As[(wm + mt * 16 + mrow) * TK + kq];
        #pragma unroll
        for (int nt = 0; nt < AN; nt++)
            bfr[nt] = *(const bf16x8*)&Bs[(wn + nt * 16 + mrow) * TK + kq];
        #pragma unroll
        for (int mt = 0; mt < AM; mt++)
            #pragma unroll
            for (int nt = 0; nt < AN; nt++)
                acc[mt][nt] = __builtin_amdgcn_mfma_f32_16x16x32_bf16(
                    af[mt], bfr[nt], acc[mt][nt], 0, 0, 0);
    }

    int col_l = lane & 15, row_l = (lane >> 4) * 4;
    #pragma unroll
    for (int nt = 0; nt < AN; nt++) {
        int col = bn + wn + nt * 16 + col_l;
        float bs = bias[col];
        #pragma unroll
        for (int mt = 0; mt < AM; mt++) {
            floatx4 v = acc[mt][nt];
            int row0 = bm + wm + mt * 16 + row_l;
            #pragma unroll
            for (int rr = 0; rr < 4; rr++) {
                float o = (v[rr] + bs) * scale;
                if (act) o = gelu_f(o);
                if (Cf) Cf[(size_t)(row0 + rr) * N + col] = o;
                if (Cb) Cb[(size_t)(row0 + rr) * N + col] = (__bf16)o;
            }
        }
    }
}

// ================= fused QKV / KGVG GEMM (128x128 tile) =================
// N = nseg*768. mode 0 (QKV): seg0->qdst (scaled), seg1->kdst, seg2->vdst+vt.
// mode 1 (KGVG): seg0->kdst rows, seg1->vt only.
__global__ __launch_bounds__(256) void mfma_gemm_qkv(
    const __bf16* __restrict__ A, const __bf16* __restrict__ Bt,
    const float* __restrict__ bias,
    __bf16* __restrict__ qdst, __bf16* __restrict__ kdst,
    __bf16* __restrict__ vdst, __bf16* __restrict__ vt,
    int N, int K, float qscale, int mode)
{
    __shared__ __align__(16) __bf16 As[128 * TK];
    __shared__ __align__(16) __bf16 Bs[128 * TK];
    int t = threadIdx.x;
    int wave = t >> 6, lane = t & 63;
    int bm = blockIdx.x * 128, bn = blockIdx.y * 128;
    int wm = (wave & 1) * 64, wn = (wave >> 1) * 64;

    floatx4 acc[4][4];
    #pragma unroll
    for (int i = 0; i < 4; i++)
        #pragma unroll
        for (int j = 0; j < 4; j++) { floatx4 z = {0.f,0.f,0.f,0.f}; acc[i][j] = z; }

    const int mrow = lane & 15, kq = (lane >> 4) * 8;

    for (int k0 = 0; k0 < K; k0 += TK) {
        __syncthreads();
        #pragma unroll
        for (int i = 0; i < 2; i++) {
            int c = i * 256 + wave * 64 + lane;
            async16(A + (size_t)(bm + (c >> 2)) * K + k0 + (c & 3) * 8,
                    &As[(size_t)(i * 256 + wave * 64) * 8]);
            async16(Bt + (size_t)(bn + (c >> 2)) * K + k0 + (c & 3) * 8,
                    &Bs[(size_t)(i * 256 + wave * 64) * 8]);
        }
        __builtin_amdgcn_s_waitcnt(0x0f70);
        __syncthreads();
        bf16x8 af[4], bfr[4];
        #pragma unroll
        for (int mt = 0; mt < 4; mt++)
            af[mt] = *(const bf16x8*)&As[(wm + mt * 16 + mrow) * TK + kq];
        #pragma unroll
        for (int nt = 0; nt < 4; nt++)
            bfr[nt] = *(const bf16x8*)&Bs[(wn + nt * 16 + mrow) * TK + kq];
        #pragma unroll
        for (int mt = 0; mt < 4; mt++)
            #pragma unroll
            for (int nt = 0; nt < 4; nt++)
                acc[mt][nt] = __builtin_amdgcn_mfma_f32_16x16x32_bf16(
                    af[mt], bfr[nt], acc[mt][nt], 0, 0, 0);
    }

    int col_l = lane & 15, row_l = (lane >> 4) * 4;
    int seg = bn / 768;                 // block-uniform
    int colw_base = bn - seg * 768 + wn;
    float scl = (mode == 0 && seg == 0) ? qscale : 1.0f;
    #pragma unroll
    for (int nt = 0; nt < 4; nt++) {
        int col = bn + wn + nt * 16 + col_l;
        int colw = colw_base + nt * 16 + col_l;
        float bs = bias[col];
        #pragma unroll
        for (int mt = 0; mt < 4; mt++) {
            floatx4 v = acc[mt][nt];
            int row0 = bm + wm + mt * 16 + row_l;
            __bf16 t4[4];
            #pragma unroll
            for (int rr = 0; rr < 4; rr++) t4[rr] = (__bf16)((v[rr] + bs) * scl);
            if (mode == 0) {
                __bf16* dst = (seg == 0) ? qdst : (seg == 1) ? kdst : vdst;
                #pragma unroll
                for (int rr = 0; rr < 4; rr++)
                    dst[(size_t)(row0 + rr) * 768 + colw] = t4[rr];
                if (seg == 2)
                    *(uint2*)&vt[(size_t)colw * SEQ + row0] = *(uint2*)t4;
            } else {
                if (seg == 0) {
                    #pragma unroll
                    for (int rr = 0; rr < 4; rr++)
                        kdst[(size_t)(row0 + rr) * 768 + colw] = t4[rr];
                } else {
                    *(uint2*)&vt[(size_t)colw * SEQ + row0] = *(uint2*)t4;
                }
            }
        }
    }
}

// ---------------- MFMA band + global-key attention (flash, base-2 softmax) ------
__global__ __launch_bounds__(128) void band_attn_mfma(
    const __bf16* __restrict__ qb, const __bf16* __restrict__ kb,
    const __bf16* __restrict__ vb, const __bf16* __restrict__ vtg,
    const int* __restrict__ clss, const int* __restrict__ mask_src,
    const int* __restrict__ is_glb, __bf16* __restrict__ outb)
{
    __shared__ __align__(16) __bf16 Kt[4096];
    __shared__ __align__(16) __bf16 Vt[4096];
    __shared__ __align__(16) __bf16 Ps[2][64 * PS_LD];
    __shared__ int kvalid[64];
    __shared__ int gpos[64];

    const int n = blockIdx.x, hh = blockIdx.y, bz = blockIdx.z;
    const int t = threadIdx.x, wave = t >> 6, lane = t & 63;
    const int quad = lane >> 4, col_l = lane & 15, row_l = quad * 4;
    const int qw = bz * 128 + wave * 64;
    const int l3 = lane & 3, l2h = lane >> 2, l7 = lane & 7, l3h = lane >> 3;

    if (t < 64) gpos[t] = clss[t];

    bf16x8 aq[4][2];
    #pragma unroll
    for (int mt = 0; mt < 4; mt++) {
        const __bf16* qp = qb + (size_t)(n * CHK + qw + mt * 16 + col_l) * DIM + hh * HDIM;
        aq[mt][0] = *(const bf16x8*)(qp + quad * 8);
        aq[mt][1] = *(const bf16x8*)(qp + 32 + quad * 8);
    }

    floatx4 oacc[4][4];
    #pragma unroll
    for (int i = 0; i < 4; i++)
        #pragma unroll
        for (int j = 0; j < 4; j++) { floatx4 z = {0.f,0.f,0.f,0.f}; oacc[i][j] = z; }
    float mrow[16], lrow[16];
    #pragma unroll
    for (int r = 0; r < 16; r++) { mrow[r] = -1e30f; lrow[r] = 0.f; }

    __bf16* PsW = Ps[wave];

    for (int tt = 0; tt < 11; tt++) {
        __syncthreads();
        int jbase = -1;
        if (tt == 0) {
            if (t < 64) kvalid[t] = (mask_src[gpos[t]] > 0) ? 1 : 0;
            #pragma unroll
            for (int ii = 0; ii < 4; ii++) {
                int p = ii >> 1;
                int kbase = wave * 32 + (ii & 1) * 16;
                int key = kbase + l2h;
                int pos = gpos[key];
                const __bf16* g = kb + (size_t)pos * DIM + hh * HDIM + p * 32 + l3 * 8;
                async16(g, &Kt[p * 2048 + kbase * 32]);
            }
            __bf16* Vrow = &Ps[0][0];
            #pragma unroll
            for (int ii = 0; ii < 4; ii++) {
                int kbase = wave * 32 + ii * 8;
                int key = kbase + l3h;
                int pos = gpos[key];
                const __bf16* g = vb + (size_t)pos * DIM + hh * HDIM + l7 * 8;
                async16(g, &Vrow[kbase * 64]);
            }
        } else {
            jbase = (bz * 2 + tt - 1) * 64;
            if (t < 64) {
                int pos = n * CHK + jbase + t - CHK;
                kvalid[t] = (pos >= 0 && pos < SEQ && mask_src[pos] > 0
                             && is_glb[pos] == 0) ? 1 : 0;
            }
            int s0 = n * CHK + jbase - CHK;
            #pragma unroll
            for (int ii = 0; ii < 4; ii++) {
                int p = ii >> 1;
                int kbase = wave * 32 + (ii & 1) * 16;
                int key = kbase + l2h;
                int pos = s0 + key; pos = min(max(pos, 0), SEQ - 1);
                const __bf16* g = kb + (size_t)pos * DIM + hh * HDIM + p * 32 + l3 * 8;
                async16(g, &Kt[p * 2048 + kbase * 32]);
            }
            #pragma unroll
            for (int ii = 0; ii < 4; ii++) {
                int p = ii >> 1;
                int dbase = wave * 32 + (ii & 1) * 16;
                int d = dbase + l2h;
                int s = s0 + p * 32 + l3 * 8; s = min(max(s, 0), SEQ - 8);
                const __bf16* g = vtg + (size_t)(hh * HDIM + d) * SEQ + s;
                async16(g, &Vt[p * 2048 + dbase * 32]);
            }
        }
        __builtin_amdgcn_s_waitcnt(0x0f70);
        __syncthreads();
        if (tt == 0) {
            const __bf16* Vrow = &Ps[0][0];
            for (int idx = t; idx < 4096; idx += 128) {
                int key = idx >> 6, d = idx & 63;
                Vt[(key >> 5) * 2048 + d * 32 + (key & 31)] = Vrow[idx];
            }
            __syncthreads();
        } else {
            if (jbase + 63 < qw || jbase > qw + 575) continue;
        }

        bf16x8 bk[4][2];
        #pragma unroll
        for (int nt = 0; nt < 4; nt++) {
            bk[nt][0] = *(const bf16x8*)&Kt[(nt * 16 + col_l) * 32 + quad * 8];
            bk[nt][1] = *(const bf16x8*)&Kt[2048 + (nt * 16 + col_l) * 32 + quad * 8];
        }
        int kv[4];
        #pragma unroll
        for (int nt = 0; nt < 4; nt++) kv[nt] = kvalid[nt * 16 + col_l];

        #pragma unroll
        for (int mt = 0; mt < 4; mt++) {
            floatx4 s[4];
            #pragma unroll
            for (int nt = 0; nt < 4; nt++) {
                floatx4 z = {0.f,0.f,0.f,0.f};
                z = __builtin_amdgcn_mfma_f32_16x16x32_bf16(aq[mt][0], bk[nt][0], z, 0,0,0);
                z = __builtin_amdgcn_mfma_f32_16x16x32_bf16(aq[mt][1], bk[nt][1], z, 0,0,0);
                s[nt] = z;
            }
            #pragma unroll
            for (int nt = 0; nt < 4; nt++)
                #pragma unroll
                for (int rr = 0; rr < 4; rr++) {
                    int ok = kv[nt];
                    if (tt != 0) {
                        int i = qw + mt * 16 + row_l + rr;
                        int rel = jbase + nt * 16 + col_l - i;
                        ok = ok && (rel >= 0) && (rel <= 2 * WINR);
                    }
                    if (!ok) s[nt][rr] = -1e30f;
                }
            #pragma unroll
            for (int rr = 0; rr < 4; rr++) {
                float rm = fmaxf(fmaxf(s[0][rr], s[1][rr]), fmaxf(s[2][rr], s[3][rr]));
                rm = fmaxf(rm, __shfl_xor(rm, 1));
                rm = fmaxf(rm, __shfl_xor(rm, 2));
                rm = fmaxf(rm, __shfl_xor(rm, 4));
                rm = fmaxf(rm, __shfl_xor(rm, 8));
                int ri = mt * 4 + rr;
                float mo = mrow[ri];
                float mn = fmaxf(mo, rm);
                float alpha = exp2f(mo - mn);
                float rsum = 0.f;
                #pragma unroll
                for (int nt = 0; nt < 4; nt++) {
                    float sv = s[nt][rr];
                    float p = exp2f(sv - mn);
                    p = (sv > -1e29f) ? p : 0.f;
                    rsum += p;
                    PsW[(mt * 16 + row_l + rr) * PS_LD + nt * 16 + col_l] = (__bf16)p;
                }
                rsum += __shfl_xor(rsum, 1);
                rsum += __shfl_xor(rsum, 2);
                rsum += __shfl_xor(rsum, 4);
                rsum += __shfl_xor(rsum, 8);
                lrow[ri] = lrow[ri] * alpha + rsum;
                mrow[ri] = mn;
                #pragma unroll
                for (int nt = 0; nt < 4; nt++) oacc[mt][nt][rr] *= alpha;
            }
        }
        bf16x8 bv[4][2], ap[4][2];
        #pragma unroll
        for (int nt = 0; nt < 4; nt++) {
            bv[nt][0] = *(const bf16x8*)&Vt[(nt * 16 + col_l) * 32 + quad * 8];
            bv[nt][1] = *(const bf16x8*)&Vt[2048 + (nt * 16 + col_l) * 32 + quad * 8];
        }
        #pragma unroll
        for (int mt = 0; mt < 4; mt++) {
            ap[mt][0] = *(const bf16x8*)&PsW[(mt * 16 + col_l) * PS_LD + quad * 8];
            ap[mt][1] = *(const bf16x8*)&PsW[(mt * 16 + col_l) * PS_LD + 32 + quad * 8];
        }
        #pragma unroll
        for (int mt = 0; mt < 4; mt++)
            #pragma unroll
            for (int nt = 0; nt < 4; nt++) {
                oacc[mt][nt] = __builtin_amdgcn_mfma_f32_16x16x32_bf16(
                    ap[mt][0], bv[nt][0], oacc[mt][nt], 0,0,0);
                oacc[mt][nt] = __builtin_amdgcn_mfma_f32_16x16x32_bf16(
                    ap[mt][1], bv[nt][1], oacc[mt][nt], 0,0,0);
            }
    }

    #pragma unroll
    for (int mt = 0; mt < 4; mt++)
        #pragma unroll
        for (int nt = 0; nt < 4; nt++)
            #pragma unroll
            for (int rr = 0; rr < 4; rr++) {
                int ri = mt * 4 + rr;
                float o = oacc[mt][nt][rr] / lrow[ri];
                int srow = n * CHK + qw + mt * 16 + row_l + rr;
                outb[(size_t)srow * DIM + hh * HDIM + nt * 16 + col_l] = (__bf16)o;
            }
}

// ---------------- global-query flash, split-K partials (base-2) ----------------
__global__ __launch_bounds__(256) void gq_flash(
    const __bf16* __restrict__ qgbb, const __bf16* __restrict__ kgb,
    const __bf16* __restrict__ vgt, const int* __restrict__ mask_src,
    float* __restrict__ Opart, float* __restrict__ mlpart)
{
    __shared__ __align__(16) __bf16 Kg[4096];
    __shared__ __align__(16) __bf16 Vg[4096];
    __shared__ __align__(16) __bf16 Psg[4][16 * PS_LD];
    __shared__ int kvalid[64];
    const int hh = blockIdx.x, sp = blockIdx.y;
    const int t = threadIdx.x, wave = t >> 6, lane = t & 63;
    const int quad = lane >> 4, col_l = lane & 15, row_l = quad * 4;
    const int l3 = lane & 3, l2h = lane >> 2;

    bf16x8 aq[2];
    {
        const __bf16* qp = qgbb + (size_t)(wave * 16 + col_l) * DIM + hh * HDIM;
        aq[0] = *(const bf16x8*)(qp + quad * 8);
        aq[1] = *(const bf16x8*)(qp + 32 + quad * 8);
    }
    floatx4 oacc[4];
    #pragma unroll
    for (int i = 0; i < 4; i++) { floatx4 z = {0.f,0.f,0.f,0.f}; oacc[i] = z; }
    float m4[4], l4[4];
    #pragma unroll
    for (int r = 0; r < 4; r++) { m4[r] = -1e30f; l4[r] = 0.f; }
    __bf16* PsW = Psg[wave];

    for (int tt = 0; tt < 4; tt++) {
        int pos0 = sp * 256 + tt * 64;
        __syncthreads();
        if (t < 64) kvalid[t] = (mask_src[pos0 + t] > 0) ? 1 : 0;
        #pragma unroll
        for (int ii = 0; ii < 2; ii++) {
            int gid = wave * 2 + ii;
            int p = gid >> 2, kbase = (gid & 3) * 16;
            int key = kbase + l2h;
            const __bf16* g = kgb + (size_t)(pos0 + key) * DIM + hh * HDIM + p * 32 + l3 * 8;
            async16(g, &Kg[p * 2048 + kbase * 32]);
        }
        #pragma unroll
        for (int ii = 0; ii < 2; ii++) {
            int gid = wave * 2 + ii;
            int p = gid >> 2, dbase = (gid & 3) * 16;
            int d = dbase + l2h;
            const __bf16* g = vgt + (size_t)(hh * HDIM + d) * SEQ + pos0 + p * 32 + l3 * 8;
            async16(g, &Vg[p * 2048 + dbase * 32]);
        }
        __builtin_amdgcn_s_waitcnt(0x0f70);
        __syncthreads();

        floatx4 s[4];
        #pragma unroll
        for (int nt = 0; nt < 4; nt++) {
            bf16x8 b0 = *(const bf16x8*)&Kg[(nt * 16 + col_l) * 32 + quad * 8];
            bf16x8 b1 = *(const bf16x8*)&Kg[2048 + (nt * 16 + col_l) * 32 + quad * 8];
            floatx4 z = {0.f,0.f,0.f,0.f};
            z = __builtin_amdgcn_mfma_f32_16x16x32_bf16(aq[0], b0, z, 0,0,0);
            z = __builtin_amdgcn_mfma_f32_16x16x32_bf16(aq[1], b1, z, 0,0,0);
            s[nt] = z;
        }
        int kv[4];
        #pragma unroll
        for (int nt = 0; nt < 4; nt++) kv[nt] = kvalid[nt * 16 + col_l];
        #pragma unroll
        for (int nt = 0; nt < 4; nt++)
            #pragma unroll
            for (int rr = 0; rr < 4; rr++)
                if (!kv[nt]) s[nt][rr] = -1e30f;
        #pragma unroll
        for (int rr = 0; rr < 4; rr++) {
            float rm = fmaxf(fmaxf(s[0][rr], s[1][rr]), fmaxf(s[2][rr], s[3][rr]));
            rm = fmaxf(rm, __shfl_xor(rm, 1));
            rm = fmaxf(rm, __shfl_xor(rm, 2));
            rm = fmaxf(rm, __shfl_xor(rm, 4));
            rm = fmaxf(rm, __shfl_xor(rm, 8));
            float mo = m4[rr];
            float mn = fmaxf(mo, rm);
            float alpha = exp2f(mo - mn);
            float rsum = 0.f;
            #pragma unroll
            for (int nt = 0; nt < 4; nt++) {
                float sv = s[nt][rr];
                float p = exp2f(sv - mn);
                p = (sv > -1e29f) ? p : 0.f;
                rsum += p;
                PsW[(row_l + rr) * PS_LD + nt * 16 + col_l] = (__bf16)p;
            }
            rsum += __shfl_xor(rsum, 1);
            rsum += __shfl_xor(rsum, 2);
            rsum += __shfl_xor(rsum, 4);
            rsum += __shfl_xor(rsum, 8);
            l4[rr] = l4[rr] * alpha + rsum;
            m4[rr] = mn;
            #pragma unroll
            for (int nt = 0; nt < 4; nt++) oacc[nt][rr] *= alpha;
        }
        bf16x8 ap0 = *(const bf16x8*)&PsW[col_l * PS_LD + quad * 8];
        bf16x8 ap1 = *(const bf16x8*)&PsW[col_l * PS_LD + 32 + quad * 8];
        #pragma unroll
        for (int nt = 0; nt < 4; nt++) {
            bf16x8 b0 = *(const bf16x8*)&Vg[(nt * 16 + col_l) * 32 + quad * 8];
            bf16x8 b1 = *(const bf16x8*)&Vg[2048 + (nt * 16 + col_l) * 32 + quad * 8];
            oacc[nt] = __builtin_amdgcn_mfma_f32_16x16x32_bf16(ap0, b0, oacc[nt], 0,0,0);
            oacc[nt] = __builtin_amdgcn_mfma_f32_16x16x32_bf16(ap1, b1, oacc[nt], 0,0,0);
        }
    }
    size_t base = (size_t)(hh * 16 + sp) * 64;
    #pragma unroll
    for (int nt = 0; nt < 4; nt++)
        #pragma unroll
        for (int rr = 0; rr < 4; rr++)
            Opart[(base + wave * 16 + row_l + rr) * 64 + nt * 16 + col_l] = oacc[nt][rr];
    if (col_l == 0) {
        #pragma unroll
        for (int rr = 0; rr < 4; rr++) {
            mlpart[(base + wave * 16 + row_l + rr) * 2]     = m4[rr];
            mlpart[(base + wave * 16 + row_l + rr) * 2 + 1] = l4[rr];
        }
    }
}

// ---------------- merge split-K partials + scatter into attention out ----------
__global__ __launch_bounds__(64) void gq_merge_scatter(
    const float* __restrict__ Opart, const float* __restrict__ mlpart,
    const int* __restrict__ clss, __bf16* __restrict__ b6b)
{
    int hh = blockIdx.x, q = blockIdx.y, d = threadIdx.x;
    float M = -1e30f;
    for (int s = 0; s < 16; s++)
        M = fmaxf(M, mlpart[(((size_t)hh * 16 + s) * 64 + q) * 2]);
    float L = 0.f, acc = 0.f;
    for (int s = 0; s < 16; s++) {
        size_t b = ((size_t)hh * 16 + s) * 64 + q;
        float w = exp2f(mlpart[b * 2] - M);
        L += mlpart[b * 2 + 1] * w;
        acc += w * Opart[b * 64 + d];
    }
    b6b[(size_t)clss[q] * DIM + hh * HDIM + d] = (__bf16)(acc / L);
}

// ---------------- gather rows -> bf16 ----------------
__global__ __launch_bounds__(256) void gather_rows_bf16(
    const float* __restrict__ src, const int* __restrict__ idx, __bf16* __restrict__ dst)
{
    int i = blockIdx.x, t = threadIdx.x;
    int p = idx[i];
    #pragma unroll
    for (int c = 0; c < 3; c++)
        dst[(size_t)i * DIM + t + c * 256] = (__bf16)src[(size_t)p * DIM + t + c * 256];
}

// ---------------- is_glb build ----------------
__global__ __launch_bounds__(256) void build_glb_kernel(
    const int* __restrict__ clss, int* __restrict__ is_glb)
{
    int t = threadIdx.x;
    for (int s0 = t; s0 < SEQ; s0 += 256) is_glb[s0] = 0;
    __syncthreads();
    if (t < NCLS) is_glb[clss[t]] = 1;
}

// ---------------- host launcher ----------------
extern "C" void kernel_launch(void* const* d_in, const int* in_sizes, int n_in,
                              void* d_out, int out_size, void* d_ws, size_t ws_size,
                              hipStream_t stream)
{
    const int* x        = (const int*)d_in[0];
    const int* mask_src = (const int*)d_in[1];
    const int* clss     = (const int*)d_in[2];
    const int* segs     = (const int*)d_in[3];
    const float* word_emb = (const float*)d_in[4];
    const float* pos_emb  = (const float*)d_in[5];
    const float* type_emb = (const float*)d_in[6];
    const float* ln_e_s   = (const float*)d_in[7];
    const float* ln_e_b   = (const float*)d_in[8];
    const float* Wq  = (const float*)d_in[9];
    const float* bq  = (const float*)d_in[10];
    const float* Wk  = (const float*)d_in[11];
    const float* bk  = (const float*)d_in[12];
    const float* Wv  = (const float*)d_in[13];
    const float* bv  = (const float*)d_in[14];
    const float* Wqg = (const float*)d_in[15];
    const float* bqg = (const float*)d_in[16];
    const float* Wkg = (const float*)d_in[17];
    const float* bkg = (const float*)d_in[18];
    const float* Wvg = (const float*)d_in[19];
    const float* bvg = (const float*)d_in[20];
    const float* Wo  = (const float*)d_in[21];
    const float* bo  = (const float*)d_in[22];
    const float* ln1_s = (const float*)d_in[23];
    const float* ln1_b = (const float*)d_in[24];
    const float* Wf1 = (const float*)d_in[25];
    const float* bf1 = (const float*)d_in[26];
    const float* Wf2 = (const float*)d_in[27];
    const float* bf2 = (const float*)d_in[28];
    const float* ln2_s = (const float*)d_in[29];
    const float* ln2_b = (const float*)d_in[30];

    const size_t DD = (size_t)DIM * DIM;       // 589824
    float* ws = (float*)d_ws;
    float*  h    = ws;                                  // slot0
    float*  s4   = ws + SD;                             // slot1
    __bf16* hb   = (__bf16*)(ws + 2 * SD);              // slot2 lo
    __bf16* b6b  = (__bf16*)(ws + 2 * SD) + SD;         // slot2 hi
    __bf16* qb   = (__bf16*)(ws + 3 * SD);              // slot3 lo
    __bf16* kb   = (__bf16*)(ws + 3 * SD) + SD;         // slot3 hi
    __bf16* vb   = (__bf16*)(ws + 4 * SD);              // slot4 lo
    __bf16* vtg  = (__bf16*)(ws + 4 * SD) + SD;         // slot4 hi
    __bf16* kgb  = (__bf16*)(ws + 5 * SD);              // slot5 lo
    __bf16* vgt  = (__bf16*)(ws + 5 * SD) + SD;         // slot5 hi
    __bf16* gelu_b = qb;                                // FFN overlays slots 3-4
    float* extra = ws + 6 * SD;
    __bf16* Wbf   = (__bf16*)extra;                     // 30*DD bf16 = 8,847,360 f32-equiv/2
    // Wbf layout (bf16 elems): QKV z0-5 (z*DD), KGVG z6-9, WO z10-11, WQG z12-13,
    // WF1 at 14*DD (+4*DD per layer), WF2 at 22*DD (+4*DD per layer); total 30*DD.
    float* after_w = extra + (30 * DD) / 2;             // 30*DD bf16 = 15*DD f32
    float* bqkv   = after_w;                            // 2*2304
    float* bkgvg  = bqkv + 2 * 2304;                    // 2*1536
    float* Opart  = bkgvg + 2 * 1536;                   // 786432
    float* mlpart = Opart + 786432;                     // 24576
    __bf16* hgbb  = (__bf16*)(mlpart + 24576);          // 64*768 bf16
    __bf16* qgbb  = hgbb + (size_t)NCLS * DIM;          // 64*768 bf16
    int*   isglb  = (int*)(qgbb + (size_t)NCLS * DIM);

    build_glb_kernel<<<1, 256, 0, stream>>>(clss, isglb);
    embed_ln_kernel<<<SEQ, 256, 0, stream>>>(x, segs, word_emb, pos_emb, type_emb,
                                             ln_e_s, ln_e_b, h, hb);
    concat_bias_kernel<<<18, 256, 0, stream>>>(bq, bk, bv, bkg, bvg, bqkv, bkgvg);

    // all weight transposes up-front
    {
        Ptr16 wp{};
        wp.p[0] = Wq;        wp.p[1] = Wk;        wp.p[2] = Wv;
        wp.p[3] = Wq + DD;   wp.p[4] = Wk + DD;   wp.p[5] = Wv + DD;
        wp.p[6] = Wkg;       wp.p[7] = Wvg;
        wp.p[8] = Wkg + DD;  wp.p[9] = Wvg + DD;
        wp.p[10] = Wo;       wp.p[11] = Wo + DD;
        wp.p[12] = Wqg;      wp.p[13] = Wqg + DD;
        transpose_w_kernel<<<dim3(24, 24, 14), 256, 0, stream>>>(wp, Wbf, DIM, DIM);
        Ptr16 wf1{};
        wf1.p[0] = Wf1; wf1.p[1] = Wf1 + (size_t)DIM * FFD;
        transpose_w_kernel<<<dim3(96, 24, 2), 256, 0, stream>>>(wf1, Wbf + 14 * DD, DIM, FFD);
        Ptr16 wf2{};
        wf2.p[0] = Wf2; wf2.p[1] = Wf2 + (size_t)FFD * DIM;
        transpose_w_kernel<<<dim3(24, 96, 2), 256, 0, stream>>>(wf2, Wbf + 22 * DD, FFD, DIM);
    }

    for (int l = 0; l < NLAYER; l++) {
        const float* bqg_l = bqg + (size_t)l * DIM;
        const float* bo_l  = bo  + (size_t)l * DIM;
        const float* bf1_l = bf1 + (size_t)l * FFD;
        const float* bf2_l = bf2 + (size_t)l * DIM;

        // fused QKV projection (q scaled by QSCALE*log2e), v also transposed
        mfma_gemm_qkv<<<dim3(SEQ / 128, 2304 / 128), 256, 0, stream>>>(
            hb, Wbf + (size_t)l * 3 * DD, bqkv + l * 2304,
            qb, kb, vb, vtg, 2304, DIM, QSC2, 0);
        band_attn_mfma<<<dim3(NCHK, NH, 2), 128, 0, stream>>>(qb, kb, vb, vtg, clss,
                                                              mask_src, isglb, b6b);
        // fused KG/VG projection (vg transposed only)
        mfma_gemm_qkv<<<dim3(SEQ / 128, 1536 / 128), 256, 0, stream>>>(
            hb, Wbf + 6 * DD + (size_t)l * 2 * DD, bkgvg + l * 1536,
            nullptr, kgb, nullptr, vgt, 1536, DIM, 1.0f, 1);
        gather_rows_bf16<<<NCLS, 256, 0, stream>>>(h, clss, hgbb);
        mfma_gemm_t<64, 128><<<dim3(1, 6), 256, 0, stream>>>(
            hgbb, Wbf + 12 * DD + (size_t)l * DD, bqg_l, nullptr, qgbb,
            NCLS, DIM, DIM, QSC2, 0);
        gq_flash<<<dim3(NH, 16), 256, 0, stream>>>(qgbb, kgb, vgt, mask_src, Opart, mlpart);
        gq_merge_scatter<<<dim3(NH, NCLS), 64, 0, stream>>>(Opart, mlpart, clss, b6b);
        // output projection + LN1
        mfma_gemm_t<128, 64><<<dim3(SEQ / 128, DIM / 64), 256, 0, stream>>>(
            b6b, Wbf + 10 * DD + (size_t)l * DD, bo_l, s4, nullptr,
            SEQ, DIM, DIM, 1.0f, 0);
        add_ln_kernel<<<SEQ, 256, 0, stream>>>(h, s4, ln1_s + (size_t)l * DIM,
                                               ln1_b + (size_t)l * DIM, hb);
        // FFN
        mfma_gemm_t<128, 128><<<dim3(SEQ / 128, FFD / 128), 256, 0, stream>>>(
            hb, Wbf + 14 * DD + (size_t)l * 4 * DD, bf1_l, nullptr, gelu_b,
            SEQ, FFD, DIM, 1.0f, 1);
        mfma_gemm_t<128, 64><<<dim3(SEQ / 128, DIM / 64), 256, 0, stream>>>(
            gelu_b, Wbf + 22 * DD + (size_t)l * 4 * DD, bf2_l, s4, nullptr,
            SEQ, DIM, FFD, 1.0f, 0);
        add_ln_kernel<<<SEQ, 256, 0, stream>>>(h, s4, ln2_s + (size_t)l * DIM,
                                               ln2_b + (size_t)l * DIM, hb);
    }

    hipMemcpyAsync(d_out, h, SD * sizeof(float), hipMemcpyDeviceToDevice, stream);
}

// Round 5
// 887.401 us; speedup vs baseline: 3.8499x; 1.0676x over previous
//
#include <hip/hip_runtime.h>
#include <hip/hip_bf16.h>
#include <cstdint>

#define SEQ  4096
#define DIM  768
#define NH   12
#define HDIM 64
#define NLAYER 2
#define CHK  256
#define WINR 256
#define NCLS 64
#define NCHK 16
#define FFD  3072
#define QSCALE 0.125f
#define LOG2E 1.44269504f
#define QSC2 (QSCALE * LOG2E)
#define SD ((size_t)SEQ * DIM)
#define PS_LD 72
#define TK 32

typedef __attribute__((__vector_size__(16))) float floatx4;
typedef __attribute__((ext_vector_type(8))) __bf16 bf16x8;

__device__ __forceinline__ void async16(const void* g, void* l) {
    __builtin_amdgcn_global_load_lds(
        (const __attribute__((address_space(1))) uint32_t*)g,
        (__attribute__((address_space(3))) uint32_t*)l, 16, 0, 0);
}

__device__ __forceinline__ float block_reduce_sum(float v, float* red) {
    int t = threadIdx.x;
    red[t] = v; __syncthreads();
    #pragma unroll
    for (int st = 128; st > 0; st >>= 1) {
        if (t < st) red[t] += red[t + st];
        __syncthreads();
    }
    float r = red[0]; __syncthreads();
    return r;
}

__device__ __forceinline__ float gelu_f(float x) {
    float x3 = x * x * x;
    return 0.5f * x * (1.0f + tanhf(0.7978845608028654f * (x + 0.044715f * x3)));
}

// ---------------- embedding + LN ----------------
__global__ __launch_bounds__(256) void embed_ln_kernel(
    const int* __restrict__ x, const int* __restrict__ segs,
    const float* __restrict__ word_emb, const float* __restrict__ pos_emb,
    const float* __restrict__ type_emb, const float* __restrict__ gs,
    const float* __restrict__ gb, float* __restrict__ h, __bf16* __restrict__ hb)
{
    __shared__ float red[256];
    int s = blockIdx.x, t = threadIdx.x;
    int w = x[s], sg = segs[s];
    float v0[3]; float lsum = 0.f;
    #pragma unroll
    for (int i = 0; i < 3; i++) {
        int d = t + i * 256;
        float val = word_emb[(size_t)w * DIM + d] + pos_emb[(size_t)s * DIM + d]
                  + type_emb[(size_t)sg * DIM + d];
        v0[i] = val; lsum += val;
    }
    float mean = block_reduce_sum(lsum, red) * (1.0f / DIM);
    float lv = 0.f;
    #pragma unroll
    for (int i = 0; i < 3; i++) { float dv = v0[i] - mean; lv += dv * dv; }
    float var = block_reduce_sum(lv, red) * (1.0f / DIM);
    float rstd = rsqrtf(var + 1e-5f);
    #pragma unroll
    for (int i = 0; i < 3; i++) {
        int d = t + i * 256;
        float o = (v0[i] - mean) * rstd * gs[d] + gb[d];
        h[(size_t)s * DIM + d] = o;
        hb[(size_t)s * DIM + d] = (__bf16)o;
    }
}

// ---------------- residual add + LN ----------------
__global__ __launch_bounds__(256) void add_ln_kernel(
    float* __restrict__ h, const float* __restrict__ r,
    const float* __restrict__ gs, const float* __restrict__ gb,
    __bf16* __restrict__ hb)
{
    __shared__ float red[256];
    int s = blockIdx.x, t = threadIdx.x;
    float v0[3]; float lsum = 0.f;
    #pragma unroll
    for (int i = 0; i < 3; i++) {
        int d = t + i * 256;
        float val = h[(size_t)s * DIM + d] + r[(size_t)s * DIM + d];
        v0[i] = val; lsum += val;
    }
    float mean = block_reduce_sum(lsum, red) * (1.0f / DIM);
    float lv = 0.f;
    #pragma unroll
    for (int i = 0; i < 3; i++) { float dv = v0[i] - mean; lv += dv * dv; }
    float var = block_reduce_sum(lv, red) * (1.0f / DIM);
    float rstd = rsqrtf(var + 1e-5f);
    #pragma unroll
    for (int i = 0; i < 3; i++) {
        int d = t + i * 256;
        float o = (v0[i] - mean) * rstd * gs[d] + gb[d];
        h[(size_t)s * DIM + d] = o;
        hb[(size_t)s * DIM + d] = (__bf16)o;
    }
}

// ---------------- weight transpose-convert: f32 [K][N] -> bf16 [N][K] ----------
struct Ptr16 { const float* p[16]; };
__global__ __launch_bounds__(256) void transpose_w_kernel(
    Ptr16 in, __bf16* __restrict__ out, int K, int N)
{
    __shared__ float tile[32][33];
    const float* src = in.p[blockIdx.z];
    __bf16* dst = out + (size_t)blockIdx.z * K * N;
    int bx = blockIdx.x * 32;
    int by = blockIdx.y * 32;
    int tx = threadIdx.x & 31, ty = threadIdx.x >> 5;
    #pragma unroll
    for (int i = 0; i < 32; i += 8)
        tile[ty + i][tx] = src[(size_t)(by + ty + i) * N + bx + tx];
    __syncthreads();
    #pragma unroll
    for (int i = 0; i < 32; i += 8)
        dst[(size_t)(bx + ty + i) * K + by + tx] = (__bf16)tile[tx][ty + i];
}

// ---------------- bias concat ----------------
__global__ __launch_bounds__(256) void concat_bias_kernel(
    const float* __restrict__ bq, const float* __restrict__ bk, const float* __restrict__ bv,
    const float* __restrict__ bkg, const float* __restrict__ bvg,
    float* __restrict__ bqkv, float* __restrict__ bkgvg)
{
    int idx = blockIdx.x * 256 + threadIdx.x;
    if (idx < 2 * 2304) {
        int l = idx / 2304, c = idx % 2304, j = c / 768, d = c % 768;
        const float* s = (j == 0) ? bq : (j == 1) ? bk : bv;
        bqkv[idx] = s[l * 768 + d];
    }
    if (idx < 2 * 1536) {
        int l = idx / 1536, c = idx % 1536, j = c / 768, d = c % 768;
        const float* s = j ? bvg : bkg;
        bkgvg[idx] = s[l * 768 + d];
    }
}

// ================= generic templated MFMA GEMM =================
template<int TMv, int TNv>
__global__ __launch_bounds__(256) void mfma_gemm_t(
    const __bf16* __restrict__ A, const __bf16* __restrict__ Bt,
    const float* __restrict__ bias, float* __restrict__ Cf,
    __bf16* __restrict__ Cb, int M, int N, int K, float scale, int act)
{
    constexpr int AM = TMv / 32, AN = TNv / 32;
    constexpr int CA = TMv / 64, CB = TNv / 64;
    __shared__ __align__(16) __bf16 As[TMv * TK];
    __shared__ __align__(16) __bf16 Bs[TNv * TK];
    int t = threadIdx.x;
    int wave = t >> 6, lane = t & 63;
    int bm = blockIdx.x * TMv, bn = blockIdx.y * TNv;
    int wm = (wave & 1) * (TMv / 2), wn = (wave >> 1) * (TNv / 2);

    floatx4 acc[AM][AN];
    #pragma unroll
    for (int i = 0; i < AM; i++)
        #pragma unroll
        for (int j = 0; j < AN; j++) { floatx4 z = {0.f,0.f,0.f,0.f}; acc[i][j] = z; }

    const int mrow = lane & 15, kq = (lane >> 4) * 8;

    for (int k0 = 0; k0 < K; k0 += TK) {
        __syncthreads();
        #pragma unroll
        for (int i = 0; i < CA; i++) {
            int c = i * 256 + wave * 64 + lane;
            async16(A + (size_t)(bm + (c >> 2)) * K + k0 + (c & 3) * 8,
                    &As[(size_t)(i * 256 + wave * 64) * 8]);
        }
        #pragma unroll
        for (int i = 0; i < CB; i++) {
            int c = i * 256 + wave * 64 + lane;
            async16(Bt + (size_t)(bn + (c >> 2)) * K + k0 + (c & 3) * 8,
                    &Bs[(size_t)(i * 256 + wave * 64) * 8]);
        }
        __builtin_amdgcn_s_waitcnt(0x0f70);
        __syncthreads();
        bf16x8 af[AM], bfr[AN];
        #pragma unroll
        for (int mt = 0; mt < AM; mt++)
            af[mt] = *(const bf16x8*)&As[(wm + mt * 16 + mrow) * TK + kq];
        #pragma unroll
        for (int nt = 0; nt < AN; nt++)
            bfr[nt] = *(const bf16x8*)&Bs[(wn + nt * 16 + mrow) * TK + kq];
        #pragma unroll
        for (int mt = 0; mt < AM; mt++)
            #pragma unroll
            for (int nt = 0; nt < AN; nt++)
                acc[mt][nt] = __builtin_amdgcn_mfma_f32_16x16x32_bf16(
                    af[mt], bfr[nt], acc[mt][nt], 0, 0, 0);
    }

    int col_l = lane & 15, row_l = (lane >> 4) * 4;
    #pragma unroll
    for (int nt = 0; nt < AN; nt++) {
        int col = bn + wn + nt * 16 + col_l;
        float bs = bias[col];
        #pragma unroll
        for (int mt = 0; mt < AM; mt++) {
            floatx4 v = acc[mt][nt];
            int row0 = bm + wm + mt * 16 + row_l;
            #pragma unroll
            for (int rr = 0; rr < 4; rr++) {
                float o = (v[rr] + bs) * scale;
                if (act) o = gelu_f(o);
                if (Cf) Cf[(size_t)(row0 + rr) * N + col] = o;
                if (Cb) Cb[(size_t)(row0 + rr) * N + col] = (__bf16)o;
            }
        }
    }
}

// ================= fused QKV / KGVG GEMM (128x128 tile) =================
__global__ __launch_bounds__(256) void mfma_gemm_qkv(
    const __bf16* __restrict__ A, const __bf16* __restrict__ Bt,
    const float* __restrict__ bias,
    __bf16* __restrict__ qdst, __bf16* __restrict__ kdst,
    __bf16* __restrict__ vdst, __bf16* __restrict__ vt,
    int N, int K, float qscale, int mode)
{
    __shared__ __align__(16) __bf16 As[128 * TK];
    __shared__ __align__(16) __bf16 Bs[128 * TK];
    int t = threadIdx.x;
    int wave = t >> 6, lane = t & 63;
    int bm = blockIdx.x * 128, bn = blockIdx.y * 128;
    int wm = (wave & 1) * 64, wn = (wave >> 1) * 64;

    floatx4 acc[4][4];
    #pragma unroll
    for (int i = 0; i < 4; i++)
        #pragma unroll
        for (int j = 0; j < 4; j++) { floatx4 z = {0.f,0.f,0.f,0.f}; acc[i][j] = z; }

    const int mrow = lane & 15, kq = (lane >> 4) * 8;

    for (int k0 = 0; k0 < K; k0 += TK) {
        __syncthreads();
        #pragma unroll
        for (int i = 0; i < 2; i++) {
            int c = i * 256 + wave * 64 + lane;
            async16(A + (size_t)(bm + (c >> 2)) * K + k0 + (c & 3) * 8,
                    &As[(size_t)(i * 256 + wave * 64) * 8]);
            async16(Bt + (size_t)(bn + (c >> 2)) * K + k0 + (c & 3) * 8,
                    &Bs[(size_t)(i * 256 + wave * 64) * 8]);
        }
        __builtin_amdgcn_s_waitcnt(0x0f70);
        __syncthreads();
        bf16x8 af[4], bfr[4];
        #pragma unroll
        for (int mt = 0; mt < 4; mt++)
            af[mt] = *(const bf16x8*)&As[(wm + mt * 16 + mrow) * TK + kq];
        #pragma unroll
        for (int nt = 0; nt < 4; nt++)
            bfr[nt] = *(const bf16x8*)&Bs[(wn + nt * 16 + mrow) * TK + kq];
        #pragma unroll
        for (int mt = 0; mt < 4; mt++)
            #pragma unroll
            for (int nt = 0; nt < 4; nt++)
                acc[mt][nt] = __builtin_amdgcn_mfma_f32_16x16x32_bf16(
                    af[mt], bfr[nt], acc[mt][nt], 0, 0, 0);
    }

    int col_l = lane & 15, row_l = (lane >> 4) * 4;
    int seg = bn / 768;
    int colw_base = bn - seg * 768 + wn;
    float scl = (mode == 0 && seg == 0) ? qscale : 1.0f;
    #pragma unroll
    for (int nt = 0; nt < 4; nt++) {
        int col = bn + wn + nt * 16 + col_l;
        int colw = colw_base + nt * 16 + col_l;
        float bs = bias[col];
        #pragma unroll
        for (int mt = 0; mt < 4; mt++) {
            floatx4 v = acc[mt][nt];
            int row0 = bm + wm + mt * 16 + row_l;
            __bf16 t4[4];
            #pragma unroll
            for (int rr = 0; rr < 4; rr++) t4[rr] = (__bf16)((v[rr] + bs) * scl);
            if (mode == 0) {
                __bf16* dst = (seg == 0) ? qdst : (seg == 1) ? kdst : vdst;
                #pragma unroll
                for (int rr = 0; rr < 4; rr++)
                    dst[(size_t)(row0 + rr) * 768 + colw] = t4[rr];
                if (seg == 2)
                    *(uint2*)&vt[(size_t)colw * SEQ + row0] = *(uint2*)t4;
            } else {
                if (seg == 0) {
                    #pragma unroll
                    for (int rr = 0; rr < 4; rr++)
                        kdst[(size_t)(row0 + rr) * 768 + colw] = t4[rr];
                } else {
                    *(uint2*)&vt[(size_t)colw * SEQ + row0] = *(uint2*)t4;
                }
            }
        }
    }
}

// ---------------- MFMA band + global-key attention (flash, split-K partials) ----
// grid (NCHK, NH, 4): z = qh*2 + ks. 256 threads = 4 waves x 32 queries.
// ks0: global tile + band tiles jt in [qh*2, qh*2+4]; ks1: jt in [qh*2+5, qh*2+9].
__global__ __launch_bounds__(256) void band_attn_mfma(
    const __bf16* __restrict__ qb, const __bf16* __restrict__ kb,
    const __bf16* __restrict__ vb, const __bf16* __restrict__ vtg,
    const int* __restrict__ clss, const int* __restrict__ mask_src,
    const int* __restrict__ is_glb,
    float* __restrict__ Opart, float* __restrict__ mlpart)
{
    __shared__ __align__(16) __bf16 Kt[4096];           // [p][key(64)][d(32)]
    __shared__ __align__(16) __bf16 Vt[4096];           // [p][d(64)][key(32)]
    __shared__ __align__(16) __bf16 Ps[4][32 * PS_LD];  // per-wave P tile
    __shared__ int kvalid[64];
    __shared__ int gpos[64];

    const int n = blockIdx.x, hh = blockIdx.y, zi = blockIdx.z;
    const int qh = zi >> 1, ks = zi & 1;
    const int t = threadIdx.x, wave = t >> 6, lane = t & 63;
    const int quad = lane >> 4, col_l = lane & 15, row_l = quad * 4;
    const int qw = qh * 128 + wave * 32;       // chunk-relative wave query base
    const int l3 = lane & 3, l2h = lane >> 2, l7 = lane & 7, l3h = lane >> 3;

    if (t < 64) gpos[t] = clss[t];

    bf16x8 aq[2][2];
    #pragma unroll
    for (int mt = 0; mt < 2; mt++) {
        const __bf16* qp = qb + (size_t)(n * CHK + qw + mt * 16 + col_l) * DIM + hh * HDIM;
        aq[mt][0] = *(const bf16x8*)(qp + quad * 8);
        aq[mt][1] = *(const bf16x8*)(qp + 32 + quad * 8);
    }

    floatx4 oacc[2][4];
    #pragma unroll
    for (int i = 0; i < 2; i++)
        #pragma unroll
        for (int j = 0; j < 4; j++) { floatx4 z = {0.f,0.f,0.f,0.f}; oacc[i][j] = z; }
    float mrow[8], lrow[8];
    #pragma unroll
    for (int r = 0; r < 8; r++) { mrow[r] = -1e30f; lrow[r] = 0.f; }

    __bf16* PsW = Ps[wave];
    const int ntiles = ks ? 5 : 6;

    for (int tt = 0; tt < ntiles; tt++) {
        __syncthreads();
        int jbase = -1;
        int isglob = (ks == 0 && tt == 0);
        if (isglob) {
            if (t < 64) kvalid[t] = (mask_src[gpos[t]] > 0) ? 1 : 0;
            #pragma unroll
            for (int g = 0; g < 2; g++) {
                int gid = wave * 2 + g;
                int p = gid >> 2, kbase = (gid & 3) * 16;
                int pos = gpos[kbase + l2h];
                async16(kb + (size_t)pos * DIM + hh * HDIM + p * 32 + l3 * 8,
                        &Kt[p * 2048 + kbase * 32]);
            }
            __bf16* Vrow = &Ps[0][0];
            #pragma unroll
            for (int g = 0; g < 2; g++) {
                int cg = wave * 2 + g;
                int pos = gpos[cg * 8 + l3h];
                async16(vb + (size_t)pos * DIM + hh * HDIM + l7 * 8,
                        &Vrow[cg * 64 * 8]);
            }
        } else {
            int jt = ks ? (qh * 2 + 5 + tt) : (qh * 2 + tt - 1);
            jbase = jt * 64;
            if (t < 64) {
                int pos = n * CHK + jbase + t - CHK;
                kvalid[t] = (pos >= 0 && pos < SEQ && mask_src[pos] > 0
                             && is_glb[pos] == 0) ? 1 : 0;
            }
            int s0 = n * CHK + jbase - CHK;
            #pragma unroll
            for (int g = 0; g < 2; g++) {
                int gid = wave * 2 + g;
                int p = gid >> 2, kbase = (gid & 3) * 16;
                int pos = s0 + kbase + l2h; pos = min(max(pos, 0), SEQ - 1);
                async16(kb + (size_t)pos * DIM + hh * HDIM + p * 32 + l3 * 8,
                        &Kt[p * 2048 + kbase * 32]);
            }
            #pragma unroll
            for (int g = 0; g < 2; g++) {
                int gid = wave * 2 + g;
                int p = gid >> 2, dbase = (gid & 3) * 16;
                int d = dbase + l2h;
                int s = s0 + p * 32 + l3 * 8; s = min(max(s, 0), SEQ - 8);
                async16(vtg + (size_t)(hh * HDIM + d) * SEQ + s,
                        &Vt[p * 2048 + dbase * 32]);
            }
        }
        __builtin_amdgcn_s_waitcnt(0x0f70);
        __syncthreads();
        if (isglob) {
            const __bf16* Vrow = &Ps[0][0];
            for (int idx = t; idx < 4096; idx += 256) {
                int key = idx >> 6, d = idx & 63;
                Vt[(key >> 5) * 2048 + d * 32 + (key & 31)] = Vrow[idx];
            }
            __syncthreads();
        } else {
            if (jbase + 63 < qw || jbase > qw + 543) continue;  // wave-uniform skip
        }

        bf16x8 bkf[4][2];
        #pragma unroll
        for (int nt = 0; nt < 4; nt++) {
            bkf[nt][0] = *(const bf16x8*)&Kt[(nt * 16 + col_l) * 32 + quad * 8];
            bkf[nt][1] = *(const bf16x8*)&Kt[2048 + (nt * 16 + col_l) * 32 + quad * 8];
        }
        int kv[4];
        #pragma unroll
        for (int nt = 0; nt < 4; nt++) kv[nt] = kvalid[nt * 16 + col_l];

        #pragma unroll
        for (int mt = 0; mt < 2; mt++) {
            floatx4 s[4];
            #pragma unroll
            for (int nt = 0; nt < 4; nt++) {
                floatx4 z = {0.f,0.f,0.f,0.f};
                z = __builtin_amdgcn_mfma_f32_16x16x32_bf16(aq[mt][0], bkf[nt][0], z, 0,0,0);
                z = __builtin_amdgcn_mfma_f32_16x16x32_bf16(aq[mt][1], bkf[nt][1], z, 0,0,0);
                s[nt] = z;
            }
            #pragma unroll
            for (int nt = 0; nt < 4; nt++)
                #pragma unroll
                for (int rr = 0; rr < 4; rr++) {
                    int ok = kv[nt];
                    if (!isglob) {
                        int i = qw + mt * 16 + row_l + rr;
                        int rel = jbase + nt * 16 + col_l - i;
                        ok = ok && (rel >= 0) && (rel <= 2 * WINR);
                    }
                    if (!ok) s[nt][rr] = -1e30f;
                }
            #pragma unroll
            for (int rr = 0; rr < 4; rr++) {
                float rm = fmaxf(fmaxf(s[0][rr], s[1][rr]), fmaxf(s[2][rr], s[3][rr]));
                rm = fmaxf(rm, __shfl_xor(rm, 1));
                rm = fmaxf(rm, __shfl_xor(rm, 2));
                rm = fmaxf(rm, __shfl_xor(rm, 4));
                rm = fmaxf(rm, __shfl_xor(rm, 8));
                int ri = mt * 4 + rr;
                float mo = mrow[ri];
                float mn = fmaxf(mo, rm);
                float alpha = exp2f(mo - mn);
                float rsum = 0.f;
                #pragma unroll
                for (int nt = 0; nt < 4; nt++) {
                    float p = exp2f(s[nt][rr] - mn);   // masked -> underflows to 0
                    rsum += p;
                    PsW[(mt * 16 + row_l + rr) * PS_LD + nt * 16 + col_l] = (__bf16)p;
                }
                rsum += __shfl_xor(rsum, 1);
                rsum += __shfl_xor(rsum, 2);
                rsum += __shfl_xor(rsum, 4);
                rsum += __shfl_xor(rsum, 8);
                lrow[ri] = lrow[ri] * alpha + rsum;
                mrow[ri] = mn;
                #pragma unroll
                for (int nt = 0; nt < 4; nt++) oacc[mt][nt][rr] *= alpha;
            }
        }
        bf16x8 bvf[4][2], ap[2][2];
        #pragma unroll
        for (int nt = 0; nt < 4; nt++) {
            bvf[nt][0] = *(const bf16x8*)&Vt[(nt * 16 + col_l) * 32 + quad * 8];
            bvf[nt][1] = *(const bf16x8*)&Vt[2048 + (nt * 16 + col_l) * 32 + quad * 8];
        }
        #pragma unroll
        for (int mt = 0; mt < 2; mt++) {
            ap[mt][0] = *(const bf16x8*)&PsW[(mt * 16 + col_l) * PS_LD + quad * 8];
            ap[mt][1] = *(const bf16x8*)&PsW[(mt * 16 + col_l) * PS_LD + 32 + quad * 8];
        }
        #pragma unroll
        for (int mt = 0; mt < 2; mt++)
            #pragma unroll
            for (int nt = 0; nt < 4; nt++) {
                oacc[mt][nt] = __builtin_amdgcn_mfma_f32_16x16x32_bf16(
                    ap[mt][0], bvf[nt][0], oacc[mt][nt], 0,0,0);
                oacc[mt][nt] = __builtin_amdgcn_mfma_f32_16x16x32_bf16(
                    ap[mt][1], bvf[nt][1], oacc[mt][nt], 0,0,0);
            }
    }

    #pragma unroll
    for (int mt = 0; mt < 2; mt++) {
        #pragma unroll
        for (int rr = 0; rr < 4; rr++) {
            int srow = n * CHK + qw + mt * 16 + row_l + rr;
            size_t rbase = ((size_t)ks * SEQ + srow) * NH + hh;
            #pragma unroll
            for (int nt = 0; nt < 4; nt++)
                Opart[rbase * 64 + nt * 16 + col_l] = oacc[mt][nt][rr];
            if (col_l == 0) {
                mlpart[rbase * 2]     = mrow[mt * 4 + rr];
                mlpart[rbase * 2 + 1] = lrow[mt * 4 + rr];
            }
        }
    }
}

// ---------------- band split-K merge: 2 partials -> bf16 out ----------------
__global__ __launch_bounds__(256) void band_merge(
    const float* __restrict__ Opart, const float* __restrict__ mlpart,
    __bf16* __restrict__ outb)
{
    int g = threadIdx.x >> 6, d = threadIdx.x & 63;
    int s = blockIdx.x * 4 + g, hh = blockIdx.y;
    size_t r0 = ((size_t)s) * NH + hh;
    size_t r1 = ((size_t)SEQ + s) * NH + hh;
    float m0 = mlpart[r0 * 2], l0 = mlpart[r0 * 2 + 1];
    float m1 = mlpart[r1 * 2], l1 = mlpart[r1 * 2 + 1];
    float M = fmaxf(m0, m1);
    float w0 = exp2f(m0 - M), w1 = exp2f(m1 - M);
    float L = l0 * w0 + l1 * w1;
    float o = (Opart[r0 * 64 + d] * w0 + Opart[r1 * 64 + d] * w1) / L;
    outb[(size_t)s * DIM + hh * HDIM + d] = (__bf16)o;
}

// ---------------- global-query flash, split-K partials (32 splits) -------------
__global__ __launch_bounds__(256) void gq_flash(
    const __bf16* __restrict__ qgbb, const __bf16* __restrict__ kgb,
    const __bf16* __restrict__ vgt, const int* __restrict__ mask_src,
    float* __restrict__ Opart, float* __restrict__ mlpart)
{
    __shared__ __align__(16) __bf16 Kg[4096];
    __shared__ __align__(16) __bf16 Vg[4096];
    __shared__ __align__(16) __bf16 Psg[4][16 * PS_LD];
    __shared__ int kvalid[64];
    const int hh = blockIdx.x, sp = blockIdx.y;
    const int t = threadIdx.x, wave = t >> 6, lane = t & 63;
    const int quad = lane >> 4, col_l = lane & 15, row_l = quad * 4;
    const int l3 = lane & 3, l2h = lane >> 2;

    bf16x8 aq[2];
    {
        const __bf16* qp = qgbb + (size_t)(wave * 16 + col_l) * DIM + hh * HDIM;
        aq[0] = *(const bf16x8*)(qp + quad * 8);
        aq[1] = *(const bf16x8*)(qp + 32 + quad * 8);
    }
    floatx4 oacc[4];
    #pragma unroll
    for (int i = 0; i < 4; i++) { floatx4 z = {0.f,0.f,0.f,0.f}; oacc[i] = z; }
    float m4[4], l4[4];
    #pragma unroll
    for (int r = 0; r < 4; r++) { m4[r] = -1e30f; l4[r] = 0.f; }
    __bf16* PsW = Psg[wave];

    for (int tt = 0; tt < 2; tt++) {
        int pos0 = sp * 128 + tt * 64;
        __syncthreads();
        if (t < 64) kvalid[t] = (mask_src[pos0 + t] > 0) ? 1 : 0;
        #pragma unroll
        for (int ii = 0; ii < 2; ii++) {
            int gid = wave * 2 + ii;
            int p = gid >> 2, kbase = (gid & 3) * 16;
            int key = kbase + l2h;
            const __bf16* g = kgb + (size_t)(pos0 + key) * DIM + hh * HDIM + p * 32 + l3 * 8;
            async16(g, &Kg[p * 2048 + kbase * 32]);
        }
        #pragma unroll
        for (int ii = 0; ii < 2; ii++) {
            int gid = wave * 2 + ii;
            int p = gid >> 2, dbase = (gid & 3) * 16;
            int d = dbase + l2h;
            const __bf16* g = vgt + (size_t)(hh * HDIM + d) * SEQ + pos0 + p * 32 + l3 * 8;
            async16(g, &Vg[p * 2048 + dbase * 32]);
        }
        __builtin_amdgcn_s_waitcnt(0x0f70);
        __syncthreads();

        floatx4 s[4];
        #pragma unroll
        for (int nt = 0; nt < 4; nt++) {
            bf16x8 b0 = *(const bf16x8*)&Kg[(nt * 16 + col_l) * 32 + quad * 8];
            bf16x8 b1 = *(const bf16x8*)&Kg[2048 + (nt * 16 + col_l) * 32 + quad * 8];
            floatx4 z = {0.f,0.f,0.f,0.f};
            z = __builtin_amdgcn_mfma_f32_16x16x32_bf16(aq[0], b0, z, 0,0,0);
            z = __builtin_amdgcn_mfma_f32_16x16x32_bf16(aq[1], b1, z, 0,0,0);
            s[nt] = z;
        }
        int kv[4];
        #pragma unroll
        for (int nt = 0; nt < 4; nt++) kv[nt] = kvalid[nt * 16 + col_l];
        #pragma unroll
        for (int nt = 0; nt < 4; nt++)
            #pragma unroll
            for (int rr = 0; rr < 4; rr++)
                if (!kv[nt]) s[nt][rr] = -1e30f;
        #pragma unroll
        for (int rr = 0; rr < 4; rr++) {
            float rm = fmaxf(fmaxf(s[0][rr], s[1][rr]), fmaxf(s[2][rr], s[3][rr]));
            rm = fmaxf(rm, __shfl_xor(rm, 1));
            rm = fmaxf(rm, __shfl_xor(rm, 2));
            rm = fmaxf(rm, __shfl_xor(rm, 4));
            rm = fmaxf(rm, __shfl_xor(rm, 8));
            float mo = m4[rr];
            float mn = fmaxf(mo, rm);
            float alpha = exp2f(mo - mn);
            float rsum = 0.f;
            #pragma unroll
            for (int nt = 0; nt < 4; nt++) {
                float p = exp2f(s[nt][rr] - mn);
                rsum += p;
                PsW[(row_l + rr) * PS_LD + nt * 16 + col_l] = (__bf16)p;
            }
            rsum += __shfl_xor(rsum, 1);
            rsum += __shfl_xor(rsum, 2);
            rsum += __shfl_xor(rsum, 4);
            rsum += __shfl_xor(rsum, 8);
            l4[rr] = l4[rr] * alpha + rsum;
            m4[rr] = mn;
            #pragma unroll
            for (int nt = 0; nt < 4; nt++) oacc[nt][rr] *= alpha;
        }
        bf16x8 ap0 = *(const bf16x8*)&PsW[col_l * PS_LD + quad * 8];
        bf16x8 ap1 = *(const bf16x8*)&PsW[col_l * PS_LD + 32 + quad * 8];
        #pragma unroll
        for (int nt = 0; nt < 4; nt++) {
            bf16x8 b0 = *(const bf16x8*)&Vg[(nt * 16 + col_l) * 32 + quad * 8];
            bf16x8 b1 = *(const bf16x8*)&Vg[2048 + (nt * 16 + col_l) * 32 + quad * 8];
            oacc[nt] = __builtin_amdgcn_mfma_f32_16x16x32_bf16(ap0, b0, oacc[nt], 0,0,0);
            oacc[nt] = __builtin_amdgcn_mfma_f32_16x16x32_bf16(ap1, b1, oacc[nt], 0,0,0);
        }
    }
    size_t base = (size_t)(hh * 32 + sp) * 64;
    #pragma unroll
    for (int nt = 0; nt < 4; nt++)
        #pragma unroll
        for (int rr = 0; rr < 4; rr++)
            Opart[(base + wave * 16 + row_l + rr) * 64 + nt * 16 + col_l] = oacc[nt][rr];
    if (col_l == 0) {
        #pragma unroll
        for (int rr = 0; rr < 4; rr++) {
            mlpart[(base + wave * 16 + row_l + rr) * 2]     = m4[rr];
            mlpart[(base + wave * 16 + row_l + rr) * 2 + 1] = l4[rr];
        }
    }
}

// ---------------- merge split-K partials + scatter into attention out ----------
__global__ __launch_bounds__(64) void gq_merge_scatter(
    const float* __restrict__ Opart, const float* __restrict__ mlpart,
    const int* __restrict__ clss, __bf16* __restrict__ b6b)
{
    int hh = blockIdx.x, q = blockIdx.y, d = threadIdx.x;
    float M = -1e30f;
    for (int s = 0; s < 32; s++)
        M = fmaxf(M, mlpart[(((size_t)hh * 32 + s) * 64 + q) * 2]);
    float L = 0.f, acc = 0.f;
    for (int s = 0; s < 32; s++) {
        size_t b = ((size_t)hh * 32 + s) * 64 + q;
        float w = exp2f(mlpart[b * 2] - M);
        L += mlpart[b * 2 + 1] * w;
        acc += w * Opart[b * 64 + d];
    }
    b6b[(size_t)clss[q] * DIM + hh * HDIM + d] = (__bf16)(acc / L);
}

// ---------------- gather rows -> bf16 ----------------
__global__ __launch_bounds__(256) void gather_rows_bf16(
    const float* __restrict__ src, const int* __restrict__ idx, __bf16* __restrict__ dst)
{
    int i = blockIdx.x, t = threadIdx.x;
    int p = idx[i];
    #pragma unroll
    for (int c = 0; c < 3; c++)
        dst[(size_t)i * DIM + t + c * 256] = (__bf16)src[(size_t)p * DIM + t + c * 256];
}

// ---------------- is_glb build ----------------
__global__ __launch_bounds__(256) void build_glb_kernel(
    const int* __restrict__ clss, int* __restrict__ is_glb)
{
    int t = threadIdx.x;
    for (int s0 = t; s0 < SEQ; s0 += 256) is_glb[s0] = 0;
    __syncthreads();
    if (t < NCLS) is_glb[clss[t]] = 1;
}

// ---------------- host launcher ----------------
extern "C" void kernel_launch(void* const* d_in, const int* in_sizes, int n_in,
                              void* d_out, int out_size, void* d_ws, size_t ws_size,
                              hipStream_t stream)
{
    const int* x        = (const int*)d_in[0];
    const int* mask_src = (const int*)d_in[1];
    const int* clss     = (const int*)d_in[2];
    const int* segs     = (const int*)d_in[3];
    const float* word_emb = (const float*)d_in[4];
    const float* pos_emb  = (const float*)d_in[5];
    const float* type_emb = (const float*)d_in[6];
    const float* ln_e_s   = (const float*)d_in[7];
    const float* ln_e_b   = (const float*)d_in[8];
    const float* Wq  = (const float*)d_in[9];
    const float* bq  = (const float*)d_in[10];
    const float* Wk  = (const float*)d_in[11];
    const float* bk  = (const float*)d_in[12];
    const float* Wv  = (const float*)d_in[13];
    const float* bv  = (const float*)d_in[14];
    const float* Wqg = (const float*)d_in[15];
    const float* bqg = (const float*)d_in[16];
    const float* Wkg = (const float*)d_in[17];
    const float* bkg = (const float*)d_in[18];
    const float* Wvg = (const float*)d_in[19];
    const float* bvg = (const float*)d_in[20];
    const float* Wo  = (const float*)d_in[21];
    const float* bo  = (const float*)d_in[22];
    const float* ln1_s = (const float*)d_in[23];
    const float* ln1_b = (const float*)d_in[24];
    const float* Wf1 = (const float*)d_in[25];
    const float* bf1 = (const float*)d_in[26];
    const float* Wf2 = (const float*)d_in[27];
    const float* bf2 = (const float*)d_in[28];
    const float* ln2_s = (const float*)d_in[29];
    const float* ln2_b = (const float*)d_in[30];

    const size_t DD = (size_t)DIM * DIM;
    float* ws = (float*)d_ws;
    float*  h    = ws;
    float*  s4   = ws + SD;
    __bf16* hb   = (__bf16*)(ws + 2 * SD);
    __bf16* b6b  = (__bf16*)(ws + 2 * SD) + SD;
    __bf16* qb   = (__bf16*)(ws + 3 * SD);
    __bf16* kb   = (__bf16*)(ws + 3 * SD) + SD;
    __bf16* vb   = (__bf16*)(ws + 4 * SD);
    __bf16* vtg  = (__bf16*)(ws + 4 * SD) + SD;
    __bf16* kgb  = (__bf16*)(ws + 5 * SD);
    __bf16* vgt  = (__bf16*)(ws + 5 * SD) + SD;
    __bf16* gelu_b = qb;
    float* extra = ws + 6 * SD;
    __bf16* Wbf   = (__bf16*)extra;                     // 30*DD bf16
    float* after_w = extra + 15 * DD;                   // = 8,847,360 f32
    float* bqkv   = after_w;                            // 4608
    float* bkgvg  = bqkv + 4608;                        // 3072
    float* OpartG = bkgvg + 3072;                       // 12*32*64*64 = 1,572,864
    float* mlpartG= OpartG + 1572864;                   // 12*32*64*2  = 49,152
    float* OpartB = mlpartG + 49152;                    // 2*4096*12*64 = 6,291,456
    float* mlpartB= OpartB + 6291456;                   // 2*4096*12*2  = 196,608
    __bf16* hgbb  = (__bf16*)(mlpartB + 196608);
    __bf16* qgbb  = hgbb + (size_t)NCLS * DIM;
    int*   isglb  = (int*)(qgbb + (size_t)NCLS * DIM);

    build_glb_kernel<<<1, 256, 0, stream>>>(clss, isglb);
    embed_ln_kernel<<<SEQ, 256, 0, stream>>>(x, segs, word_emb, pos_emb, type_emb,
                                             ln_e_s, ln_e_b, h, hb);
    concat_bias_kernel<<<18, 256, 0, stream>>>(bq, bk, bv, bkg, bvg, bqkv, bkgvg);

    {
        Ptr16 wp{};
        wp.p[0] = Wq;        wp.p[1] = Wk;        wp.p[2] = Wv;
        wp.p[3] = Wq + DD;   wp.p[4] = Wk + DD;   wp.p[5] = Wv + DD;
        wp.p[6] = Wkg;       wp.p[7] = Wvg;
        wp.p[8] = Wkg + DD;  wp.p[9] = Wvg + DD;
        wp.p[10] = Wo;       wp.p[11] = Wo + DD;
        wp.p[12] = Wqg;      wp.p[13] = Wqg + DD;
        transpose_w_kernel<<<dim3(24, 24, 14), 256, 0, stream>>>(wp, Wbf, DIM, DIM);
        Ptr16 wf1{};
        wf1.p[0] = Wf1; wf1.p[1] = Wf1 + (size_t)DIM * FFD;
        transpose_w_kernel<<<dim3(96, 24, 2), 256, 0, stream>>>(wf1, Wbf + 14 * DD, DIM, FFD);
        Ptr16 wf2{};
        wf2.p[0] = Wf2; wf2.p[1] = Wf2 + (size_t)FFD * DIM;
        transpose_w_kernel<<<dim3(24, 96, 2), 256, 0, stream>>>(wf2, Wbf + 22 * DD, FFD, DIM);
    }

    for (int l = 0; l < NLAYER; l++) {
        const float* bqg_l = bqg + (size_t)l * DIM;
        const float* bo_l  = bo  + (size_t)l * DIM;
        const float* bf1_l = bf1 + (size_t)l * FFD;
        const float* bf2_l = bf2 + (size_t)l * DIM;

        mfma_gemm_qkv<<<dim3(SEQ / 128, 2304 / 128), 256, 0, stream>>>(
            hb, Wbf + (size_t)l * 3 * DD, bqkv + l * 2304,
            qb, kb, vb, vtg, 2304, DIM, QSC2, 0);
        band_attn_mfma<<<dim3(NCHK, NH, 4), 256, 0, stream>>>(
            qb, kb, vb, vtg, clss, mask_src, isglb, OpartB, mlpartB);
        band_merge<<<dim3(SEQ / 4, NH), 256, 0, stream>>>(OpartB, mlpartB, b6b);
        mfma_gemm_qkv<<<dim3(SEQ / 128, 1536 / 128), 256, 0, stream>>>(
            hb, Wbf + 6 * DD + (size_t)l * 2 * DD, bkgvg + l * 1536,
            nullptr, kgb, nullptr, vgt, 1536, DIM, 1.0f, 1);
        gather_rows_bf16<<<NCLS, 256, 0, stream>>>(h, clss, hgbb);
        mfma_gemm_t<64, 128><<<dim3(1, 6), 256, 0, stream>>>(
            hgbb, Wbf + 12 * DD + (size_t)l * DD, bqg_l, nullptr, qgbb,
            NCLS, DIM, DIM, QSC2, 0);
        gq_flash<<<dim3(NH, 32), 256, 0, stream>>>(qgbb, kgb, vgt, mask_src,
                                                   OpartG, mlpartG);
        gq_merge_scatter<<<dim3(NH, NCLS), 64, 0, stream>>>(OpartG, mlpartG, clss, b6b);
        mfma_gemm_t<128, 64><<<dim3(SEQ / 128, DIM / 64), 256, 0, stream>>>(
            b6b, Wbf + 10 * DD + (size_t)l * DD, bo_l, s4, nullptr,
            SEQ, DIM, DIM, 1.0f, 0);
        add_ln_kernel<<<SEQ, 256, 0, stream>>>(h, s4, ln1_s + (size_t)l * DIM,
                                               ln1_b + (size_t)l * DIM, hb);
        mfma_gemm_t<128, 128><<<dim3(SEQ / 128, FFD / 128), 256, 0, stream>>>(
            hb, Wbf + 14 * DD + (size_t)l * 4 * DD, bf1_l, nullptr, gelu_b,
            SEQ, FFD, DIM, 1.0f, 1);
        mfma_gemm_t<128, 64><<<dim3(SEQ / 128, DIM / 64), 256, 0, stream>>>(
            gelu_b, Wbf + 22 * DD + (size_t)l * 4 * DD, bf2_l, s4, nullptr,
            SEQ, DIM, FFD, 1.0f, 0);
        add_ln_kernel<<<SEQ, 256, 0, stream>>>(h, s4, ln2_s + (size_t)l * DIM,
                                               ln2_b + (size_t)l * DIM, hb);
    }

    hipMemcpyAsync(d_out, h, SD * sizeof(float), hipMemcpyDeviceToDevice, stream);
}

// Round 6
// 864.167 us; speedup vs baseline: 3.9534x; 1.0269x over previous
//
#include <hip/hip_runtime.h>
#include <hip/hip_bf16.h>
#include <cstdint>

#define SEQ  4096
#define DIM  768
#define NH   12
#define HDIM 64
#define NLAYER 2
#define CHK  256
#define WINR 256
#define NCLS 64
#define NCHK 16
#define FFD  3072
#define QSCALE 0.125f
#define LOG2E 1.44269504f
#define QSC2 (QSCALE * LOG2E)
#define SD ((size_t)SEQ * DIM)
#define PS_LD 72
#define TK 32

typedef __attribute__((__vector_size__(16))) float floatx4;
typedef __attribute__((ext_vector_type(8))) __bf16 bf16x8;

__device__ __forceinline__ void async16(const void* g, void* l) {
    __builtin_amdgcn_global_load_lds(
        (const __attribute__((address_space(1))) uint32_t*)g,
        (__attribute__((address_space(3))) uint32_t*)l, 16, 0, 0);
}

__device__ __forceinline__ float block_reduce_sum(float v, float* red) {
    int t = threadIdx.x;
    red[t] = v; __syncthreads();
    #pragma unroll
    for (int st = 128; st > 0; st >>= 1) {
        if (t < st) red[t] += red[t + st];
        __syncthreads();
    }
    float r = red[0]; __syncthreads();
    return r;
}

__device__ __forceinline__ float gelu_f(float x) {
    float x3 = x * x * x;
    return 0.5f * x * (1.0f + tanhf(0.7978845608028654f * (x + 0.044715f * x3)));
}

// ---------------- setup: bias concat + isglb/glb_rank init ----------------
__global__ __launch_bounds__(256) void setup_kernel(
    const float* __restrict__ bq, const float* __restrict__ bk, const float* __restrict__ bv,
    const float* __restrict__ bkg, const float* __restrict__ bvg,
    float* __restrict__ bqkv, int* __restrict__ isglb, int* __restrict__ glb_rank)
{
    int idx = blockIdx.x * 256 + threadIdx.x;   // 0..7679
    int l = idx / 3840, c = idx % 3840, j = c / 768, d = c % 768;
    const float* s = (j == 0) ? bq : (j == 1) ? bk : (j == 2) ? bv : (j == 3) ? bkg : bvg;
    bqkv[idx] = s[l * 768 + d];
    if (idx < SEQ) { isglb[idx] = 0; glb_rank[idx] = -1; }
}
__global__ __launch_bounds__(64) void set_rank_kernel(
    const int* __restrict__ clss, int* __restrict__ isglb, int* __restrict__ glb_rank)
{
    int t = threadIdx.x;
    int p = clss[t];
    isglb[p] = 1;
    glb_rank[p] = t;   // duplicates: either rank gives identical output rows
}

// ---------------- embedding + LN ----------------
__global__ __launch_bounds__(256) void embed_ln_kernel(
    const int* __restrict__ x, const int* __restrict__ segs,
    const float* __restrict__ word_emb, const float* __restrict__ pos_emb,
    const float* __restrict__ type_emb, const float* __restrict__ gs,
    const float* __restrict__ gb, float* __restrict__ h, __bf16* __restrict__ hb)
{
    __shared__ float red[256];
    int s = blockIdx.x, t = threadIdx.x;
    int w = x[s], sg = segs[s];
    float v0[3]; float lsum = 0.f;
    #pragma unroll
    for (int i = 0; i < 3; i++) {
        int d = t + i * 256;
        float val = word_emb[(size_t)w * DIM + d] + pos_emb[(size_t)s * DIM + d]
                  + type_emb[(size_t)sg * DIM + d];
        v0[i] = val; lsum += val;
    }
    float mean = block_reduce_sum(lsum, red) * (1.0f / DIM);
    float lv = 0.f;
    #pragma unroll
    for (int i = 0; i < 3; i++) { float dv = v0[i] - mean; lv += dv * dv; }
    float var = block_reduce_sum(lv, red) * (1.0f / DIM);
    float rstd = rsqrtf(var + 1e-5f);
    #pragma unroll
    for (int i = 0; i < 3; i++) {
        int d = t + i * 256;
        float o = (v0[i] - mean) * rstd * gs[d] + gb[d];
        h[(size_t)s * DIM + d] = o;
        hb[(size_t)s * DIM + d] = (__bf16)o;
    }
}

// ---------------- residual add + LN ----------------
__global__ __launch_bounds__(256) void add_ln_kernel(
    float* __restrict__ h, const float* __restrict__ r,
    const float* __restrict__ gs, const float* __restrict__ gb,
    __bf16* __restrict__ hb)
{
    __shared__ float red[256];
    int s = blockIdx.x, t = threadIdx.x;
    float v0[3]; float lsum = 0.f;
    #pragma unroll
    for (int i = 0; i < 3; i++) {
        int d = t + i * 256;
        float val = h[(size_t)s * DIM + d] + r[(size_t)s * DIM + d];
        v0[i] = val; lsum += val;
    }
    float mean = block_reduce_sum(lsum, red) * (1.0f / DIM);
    float lv = 0.f;
    #pragma unroll
    for (int i = 0; i < 3; i++) { float dv = v0[i] - mean; lv += dv * dv; }
    float var = block_reduce_sum(lv, red) * (1.0f / DIM);
    float rstd = rsqrtf(var + 1e-5f);
    #pragma unroll
    for (int i = 0; i < 3; i++) {
        int d = t + i * 256;
        float o = (v0[i] - mean) * rstd * gs[d] + gb[d];
        h[(size_t)s * DIM + d] = o;
        hb[(size_t)s * DIM + d] = (__bf16)o;
    }
}

// ---------------- weight transpose-convert: f32 [K][N] -> bf16 [N][K] ----------
struct Ptr16 { const float* p[16]; };
__global__ __launch_bounds__(256) void transpose_w_kernel(
    Ptr16 in, __bf16* __restrict__ out, int K, int N)
{
    __shared__ float tile[32][33];
    const float* src = in.p[blockIdx.z];
    __bf16* dst = out + (size_t)blockIdx.z * K * N;
    int bx = blockIdx.x * 32;
    int by = blockIdx.y * 32;
    int tx = threadIdx.x & 31, ty = threadIdx.x >> 5;
    #pragma unroll
    for (int i = 0; i < 32; i += 8)
        tile[ty + i][tx] = src[(size_t)(by + ty + i) * N + bx + tx];
    __syncthreads();
    #pragma unroll
    for (int i = 0; i < 32; i += 8)
        dst[(size_t)(bx + ty + i) * K + by + tx] = (__bf16)tile[tx][ty + i];
}

// ================= generic templated MFMA GEMM =================
template<int TMv, int TNv>
__global__ __launch_bounds__(256) void mfma_gemm_t(
    const __bf16* __restrict__ A, const __bf16* __restrict__ Bt,
    const float* __restrict__ bias, float* __restrict__ Cf,
    __bf16* __restrict__ Cb, int M, int N, int K, float scale, int act)
{
    constexpr int AM = TMv / 32, AN = TNv / 32;
    constexpr int CA = TMv / 64, CB = TNv / 64;
    __shared__ __align__(16) __bf16 As[TMv * TK];
    __shared__ __align__(16) __bf16 Bs[TNv * TK];
    int t = threadIdx.x;
    int wave = t >> 6, lane = t & 63;
    int bm = blockIdx.x * TMv, bn = blockIdx.y * TNv;
    int wm = (wave & 1) * (TMv / 2), wn = (wave >> 1) * (TNv / 2);

    floatx4 acc[AM][AN];
    #pragma unroll
    for (int i = 0; i < AM; i++)
        #pragma unroll
        for (int j = 0; j < AN; j++) { floatx4 z = {0.f,0.f,0.f,0.f}; acc[i][j] = z; }

    const int mrow = lane & 15, kq = (lane >> 4) * 8;

    for (int k0 = 0; k0 < K; k0 += TK) {
        __syncthreads();
        #pragma unroll
        for (int i = 0; i < CA; i++) {
            int c = i * 256 + wave * 64 + lane;
            async16(A + (size_t)(bm + (c >> 2)) * K + k0 + (c & 3) * 8,
                    &As[(size_t)(i * 256 + wave * 64) * 8]);
        }
        #pragma unroll
        for (int i = 0; i < CB; i++) {
            int c = i * 256 + wave * 64 + lane;
            async16(Bt + (size_t)(bn + (c >> 2)) * K + k0 + (c & 3) * 8,
                    &Bs[(size_t)(i * 256 + wave * 64) * 8]);
        }
        __builtin_amdgcn_s_waitcnt(0x0f70);
        __syncthreads();
        bf16x8 af[AM], bfr[AN];
        #pragma unroll
        for (int mt = 0; mt < AM; mt++)
            af[mt] = *(const bf16x8*)&As[(wm + mt * 16 + mrow) * TK + kq];
        #pragma unroll
        for (int nt = 0; nt < AN; nt++)
            bfr[nt] = *(const bf16x8*)&Bs[(wn + nt * 16 + mrow) * TK + kq];
        #pragma unroll
        for (int mt = 0; mt < AM; mt++)
            #pragma unroll
            for (int nt = 0; nt < AN; nt++)
                acc[mt][nt] = __builtin_amdgcn_mfma_f32_16x16x32_bf16(
                    af[mt], bfr[nt], acc[mt][nt], 0, 0, 0);
    }

    int col_l = lane & 15, row_l = (lane >> 4) * 4;
    #pragma unroll
    for (int nt = 0; nt < AN; nt++) {
        int col = bn + wn + nt * 16 + col_l;
        float bs = bias[col];
        #pragma unroll
        for (int mt = 0; mt < AM; mt++) {
            floatx4 v = acc[mt][nt];
            int row0 = bm + wm + mt * 16 + row_l;
            #pragma unroll
            for (int rr = 0; rr < 4; rr++) {
                float o = (v[rr] + bs) * scale;
                if (act) o = gelu_f(o);
                if (Cf) Cf[(size_t)(row0 + rr) * N + col] = o;
                if (Cb) Cb[(size_t)(row0 + rr) * N + col] = (__bf16)o;
            }
        }
    }
}

// ================= fused 5-way projection GEMM (q|k|v|kg|vg, N=3840) ===========
__global__ __launch_bounds__(256) void mfma_gemm_proj(
    const __bf16* __restrict__ A, const __bf16* __restrict__ Bt,
    const float* __restrict__ bias,
    __bf16* __restrict__ qb, __bf16* __restrict__ kb,
    __bf16* __restrict__ vb, __bf16* __restrict__ vtg,
    __bf16* __restrict__ kgb, __bf16* __restrict__ vgt, int K)
{
    __shared__ __align__(16) __bf16 As[128 * TK];
    __shared__ __align__(16) __bf16 Bs[128 * TK];
    int t = threadIdx.x;
    int wave = t >> 6, lane = t & 63;
    int bm = blockIdx.x * 128, bn = blockIdx.y * 128;
    int wm = (wave & 1) * 64, wn = (wave >> 1) * 64;

    floatx4 acc[4][4];
    #pragma unroll
    for (int i = 0; i < 4; i++)
        #pragma unroll
        for (int j = 0; j < 4; j++) { floatx4 z = {0.f,0.f,0.f,0.f}; acc[i][j] = z; }

    const int mrow = lane & 15, kq = (lane >> 4) * 8;

    for (int k0 = 0; k0 < K; k0 += TK) {
        __syncthreads();
        #pragma unroll
        for (int i = 0; i < 2; i++) {
            int c = i * 256 + wave * 64 + lane;
            async16(A + (size_t)(bm + (c >> 2)) * K + k0 + (c & 3) * 8,
                    &As[(size_t)(i * 256 + wave * 64) * 8]);
            async16(Bt + (size_t)(bn + (c >> 2)) * K + k0 + (c & 3) * 8,
                    &Bs[(size_t)(i * 256 + wave * 64) * 8]);
        }
        __builtin_amdgcn_s_waitcnt(0x0f70);
        __syncthreads();
        bf16x8 af[4], bfr[4];
        #pragma unroll
        for (int mt = 0; mt < 4; mt++)
            af[mt] = *(const bf16x8*)&As[(wm + mt * 16 + mrow) * TK + kq];
        #pragma unroll
        for (int nt = 0; nt < 4; nt++)
            bfr[nt] = *(const bf16x8*)&Bs[(wn + nt * 16 + mrow) * TK + kq];
        #pragma unroll
        for (int mt = 0; mt < 4; mt++)
            #pragma unroll
            for (int nt = 0; nt < 4; nt++)
                acc[mt][nt] = __builtin_amdgcn_mfma_f32_16x16x32_bf16(
                    af[mt], bfr[nt], acc[mt][nt], 0, 0, 0);
    }

    int col_l = lane & 15, row_l = (lane >> 4) * 4;
    int seg = bn / 768;                      // 0=q 1=k 2=v 3=kg 4=vg
    int colw_base = bn - seg * 768 + wn;
    float scl = (seg == 0) ? QSC2 : 1.0f;
    #pragma unroll
    for (int nt = 0; nt < 4; nt++) {
        int col = bn + wn + nt * 16 + col_l;
        int colw = colw_base + nt * 16 + col_l;
        float bs = bias[col];
        #pragma unroll
        for (int mt = 0; mt < 4; mt++) {
            floatx4 v = acc[mt][nt];
            int row0 = bm + wm + mt * 16 + row_l;
            __bf16 t4[4];
            #pragma unroll
            for (int rr = 0; rr < 4; rr++) t4[rr] = (__bf16)((v[rr] + bs) * scl);
            if (seg <= 2 || seg == 3) {
                __bf16* dst = (seg == 0) ? qb : (seg == 1) ? kb : (seg == 2) ? vb : kgb;
                #pragma unroll
                for (int rr = 0; rr < 4; rr++)
                    dst[(size_t)(row0 + rr) * 768 + colw] = t4[rr];
            }
            if (seg == 2)
                *(uint2*)&vtg[(size_t)colw * SEQ + row0] = *(uint2*)t4;
            if (seg == 4)
                *(uint2*)&vgt[(size_t)colw * SEQ + row0] = *(uint2*)t4;
        }
    }
}

// ================= qg projection with fused row-gather =================
// grid (1, 6): 64x128 tile; A rows gathered via clss (per-lane async16 source).
__global__ __launch_bounds__(256) void qg_proj(
    const __bf16* __restrict__ hb, const __bf16* __restrict__ Bt,
    const int* __restrict__ clss, const float* __restrict__ bias,
    __bf16* __restrict__ out)
{
    __shared__ __align__(16) __bf16 As[64 * TK];
    __shared__ __align__(16) __bf16 Bs[128 * TK];
    int t = threadIdx.x;
    int wave = t >> 6, lane = t & 63;
    int bn = blockIdx.y * 128;
    int wm = (wave & 1) * 32, wn = (wave >> 1) * 64;

    int cA = wave * 64 + lane;              // 256 chunks: row=c>>2, kc=(c&3)*8
    int grow = clss[cA >> 2];

    floatx4 acc[2][4];
    #pragma unroll
    for (int i = 0; i < 2; i++)
        #pragma unroll
        for (int j = 0; j < 4; j++) { floatx4 z = {0.f,0.f,0.f,0.f}; acc[i][j] = z; }

    const int mrow = lane & 15, kq = (lane >> 4) * 8;

    for (int k0 = 0; k0 < DIM; k0 += TK) {
        __syncthreads();
        async16(hb + (size_t)grow * DIM + k0 + (cA & 3) * 8,
                &As[(size_t)(wave * 64) * 8]);
        #pragma unroll
        for (int i = 0; i < 2; i++) {
            int c = i * 256 + wave * 64 + lane;
            async16(Bt + (size_t)(bn + (c >> 2)) * DIM + k0 + (c & 3) * 8,
                    &Bs[(size_t)(i * 256 + wave * 64) * 8]);
        }
        __builtin_amdgcn_s_waitcnt(0x0f70);
        __syncthreads();
        bf16x8 af[2], bfr[4];
        #pragma unroll
        for (int mt = 0; mt < 2; mt++)
            af[mt] = *(const bf16x8*)&As[(wm + mt * 16 + mrow) * TK + kq];
        #pragma unroll
        for (int nt = 0; nt < 4; nt++)
            bfr[nt] = *(const bf16x8*)&Bs[(wn + nt * 16 + mrow) * TK + kq];
        #pragma unroll
        for (int mt = 0; mt < 2; mt++)
            #pragma unroll
            for (int nt = 0; nt < 4; nt++)
                acc[mt][nt] = __builtin_amdgcn_mfma_f32_16x16x32_bf16(
                    af[mt], bfr[nt], acc[mt][nt], 0, 0, 0);
    }
    int col_l = lane & 15, row_l = (lane >> 4) * 4;
    #pragma unroll
    for (int nt = 0; nt < 4; nt++) {
        int col = bn + wn + nt * 16 + col_l;
        float bs = bias[col];
        #pragma unroll
        for (int mt = 0; mt < 2; mt++) {
            floatx4 v = acc[mt][nt];
            int row0 = wm + mt * 16 + row_l;
            #pragma unroll
            for (int rr = 0; rr < 4; rr++)
                out[(size_t)(row0 + rr) * DIM + col] = (__bf16)((v[rr] + bs) * QSC2);
        }
    }
}

// ================= unified attention: band (z<4) + gq flash (z>=4) =============
__global__ __launch_bounds__(256) void attn_kernel(
    const __bf16* __restrict__ qb, const __bf16* __restrict__ kb,
    const __bf16* __restrict__ vb, const __bf16* __restrict__ vtg,
    const __bf16* __restrict__ qgbb, const __bf16* __restrict__ kgb,
    const __bf16* __restrict__ vgt,
    const int* __restrict__ clss, const int* __restrict__ mask_src,
    const int* __restrict__ is_glb,
    float* __restrict__ OpartB, float* __restrict__ mlpartB,
    float* __restrict__ OpartG, float* __restrict__ mlpartG)
{
    __shared__ __align__(16) __bf16 Kt[4096];
    __shared__ __align__(16) __bf16 Vt[4096];
    __shared__ __align__(16) __bf16 Ps[4][32 * PS_LD];
    __shared__ int kvalid[64];
    __shared__ int gpos[64];

    const int hh = blockIdx.y;
    const int t = threadIdx.x, wave = t >> 6, lane = t & 63;
    const int quad = lane >> 4, col_l = lane & 15, row_l = quad * 4;
    const int l3 = lane & 3, l2h = lane >> 2, l7 = lane & 7, l3h = lane >> 3;
    __bf16* PsW = Ps[wave];

    if (blockIdx.z >= 4) {
        // ---------- gq flash: split sp over 32, 4 waves x 16 queries ----------
        const int sp = blockIdx.x * 2 + (blockIdx.z - 4);
        bf16x8 aq[2];
        {
            const __bf16* qp = qgbb + (size_t)(wave * 16 + col_l) * DIM + hh * HDIM;
            aq[0] = *(const bf16x8*)(qp + quad * 8);
            aq[1] = *(const bf16x8*)(qp + 32 + quad * 8);
        }
        floatx4 oacc[4];
        #pragma unroll
        for (int i = 0; i < 4; i++) { floatx4 z = {0.f,0.f,0.f,0.f}; oacc[i] = z; }
        float m4[4], l4[4];
        #pragma unroll
        for (int r = 0; r < 4; r++) { m4[r] = -1e30f; l4[r] = 0.f; }

        for (int tt = 0; tt < 2; tt++) {
            int pos0 = sp * 128 + tt * 64;
            __syncthreads();
            if (t < 64) kvalid[t] = (mask_src[pos0 + t] > 0) ? 1 : 0;
            #pragma unroll
            for (int ii = 0; ii < 2; ii++) {
                int gid = wave * 2 + ii;
                int p = gid >> 2, kbase = (gid & 3) * 16;
                async16(kgb + (size_t)(pos0 + kbase + l2h) * DIM + hh * HDIM + p * 32 + l3 * 8,
                        &Kt[p * 2048 + kbase * 32]);
            }
            #pragma unroll
            for (int ii = 0; ii < 2; ii++) {
                int gid = wave * 2 + ii;
                int p = gid >> 2, dbase = (gid & 3) * 16;
                async16(vgt + (size_t)(hh * HDIM + dbase + l2h) * SEQ + pos0 + p * 32 + l3 * 8,
                        &Vt[p * 2048 + dbase * 32]);
            }
            __builtin_amdgcn_s_waitcnt(0x0f70);
            __syncthreads();

            floatx4 s[4];
            #pragma unroll
            for (int nt = 0; nt < 4; nt++) {
                bf16x8 b0 = *(const bf16x8*)&Kt[(nt * 16 + col_l) * 32 + quad * 8];
                bf16x8 b1 = *(const bf16x8*)&Kt[2048 + (nt * 16 + col_l) * 32 + quad * 8];
                floatx4 z = {0.f,0.f,0.f,0.f};
                z = __builtin_amdgcn_mfma_f32_16x16x32_bf16(aq[0], b0, z, 0,0,0);
                z = __builtin_amdgcn_mfma_f32_16x16x32_bf16(aq[1], b1, z, 0,0,0);
                s[nt] = z;
            }
            #pragma unroll
            for (int nt = 0; nt < 4; nt++) {
                int kvv = kvalid[nt * 16 + col_l];
                #pragma unroll
                for (int rr = 0; rr < 4; rr++)
                    if (!kvv) s[nt][rr] = -1e30f;
            }
            #pragma unroll
            for (int rr = 0; rr < 4; rr++) {
                float rm = fmaxf(fmaxf(s[0][rr], s[1][rr]), fmaxf(s[2][rr], s[3][rr]));
                rm = fmaxf(rm, __shfl_xor(rm, 1));
                rm = fmaxf(rm, __shfl_xor(rm, 2));
                rm = fmaxf(rm, __shfl_xor(rm, 4));
                rm = fmaxf(rm, __shfl_xor(rm, 8));
                float mo = m4[rr];
                float mn = fmaxf(mo, rm);
                float alpha = exp2f(mo - mn);
                float rsum = 0.f;
                #pragma unroll
                for (int nt = 0; nt < 4; nt++) {
                    float p = exp2f(s[nt][rr] - mn);
                    rsum += p;
                    PsW[(row_l + rr) * PS_LD + nt * 16 + col_l] = (__bf16)p;
                }
                rsum += __shfl_xor(rsum, 1);
                rsum += __shfl_xor(rsum, 2);
                rsum += __shfl_xor(rsum, 4);
                rsum += __shfl_xor(rsum, 8);
                l4[rr] = l4[rr] * alpha + rsum;
                m4[rr] = mn;
                #pragma unroll
                for (int nt = 0; nt < 4; nt++) oacc[nt][rr] *= alpha;
            }
            bf16x8 ap0 = *(const bf16x8*)&PsW[col_l * PS_LD + quad * 8];
            bf16x8 ap1 = *(const bf16x8*)&PsW[col_l * PS_LD + 32 + quad * 8];
            #pragma unroll
            for (int nt = 0; nt < 4; nt++) {
                bf16x8 b0 = *(const bf16x8*)&Vt[(nt * 16 + col_l) * 32 + quad * 8];
                bf16x8 b1 = *(const bf16x8*)&Vt[2048 + (nt * 16 + col_l) * 32 + quad * 8];
                oacc[nt] = __builtin_amdgcn_mfma_f32_16x16x32_bf16(ap0, b0, oacc[nt], 0,0,0);
                oacc[nt] = __builtin_amdgcn_mfma_f32_16x16x32_bf16(ap1, b1, oacc[nt], 0,0,0);
            }
        }
        size_t base = (size_t)(hh * 32 + sp) * 64;
        #pragma unroll
        for (int nt = 0; nt < 4; nt++)
            #pragma unroll
            for (int rr = 0; rr < 4; rr++)
                OpartG[(base + wave * 16 + row_l + rr) * 64 + nt * 16 + col_l] = oacc[nt][rr];
        if (col_l == 0) {
            #pragma unroll
            for (int rr = 0; rr < 4; rr++) {
                mlpartG[(base + wave * 16 + row_l + rr) * 2]     = m4[rr];
                mlpartG[(base + wave * 16 + row_l + rr) * 2 + 1] = l4[rr];
            }
        }
        return;
    }

    // ---------- band + global-key flash (split-K over 2) ----------
    const int n = blockIdx.x, zi = blockIdx.z;
    const int qh = zi >> 1, ks = zi & 1;
    const int qw = qh * 128 + wave * 32;

    if (t < 64) gpos[t] = clss[t];

    bf16x8 aq[2][2];
    #pragma unroll
    for (int mt = 0; mt < 2; mt++) {
        const __bf16* qp = qb + (size_t)(n * CHK + qw + mt * 16 + col_l) * DIM + hh * HDIM;
        aq[mt][0] = *(const bf16x8*)(qp + quad * 8);
        aq[mt][1] = *(const bf16x8*)(qp + 32 + quad * 8);
    }

    floatx4 oacc[2][4];
    #pragma unroll
    for (int i = 0; i < 2; i++)
        #pragma unroll
        for (int j = 0; j < 4; j++) { floatx4 z = {0.f,0.f,0.f,0.f}; oacc[i][j] = z; }
    float mrw[8], lrw[8];
    #pragma unroll
    for (int r = 0; r < 8; r++) { mrw[r] = -1e30f; lrw[r] = 0.f; }

    const int ntiles = ks ? 5 : 6;

    for (int tt = 0; tt < ntiles; tt++) {
        __syncthreads();
        int jbase = -1;
        int isglob = (ks == 0 && tt == 0);
        if (isglob) {
            if (t < 64) kvalid[t] = (mask_src[gpos[t]] > 0) ? 1 : 0;
            #pragma unroll
            for (int g = 0; g < 2; g++) {
                int gid = wave * 2 + g;
                int p = gid >> 2, kbase = (gid & 3) * 16;
                int pos = gpos[kbase + l2h];
                async16(kb + (size_t)pos * DIM + hh * HDIM + p * 32 + l3 * 8,
                        &Kt[p * 2048 + kbase * 32]);
            }
            __bf16* Vrow = &Ps[0][0];
            #pragma unroll
            for (int g = 0; g < 2; g++) {
                int cg = wave * 2 + g;
                int pos = gpos[cg * 8 + l3h];
                async16(vb + (size_t)pos * DIM + hh * HDIM + l7 * 8,
                        &Vrow[cg * 64 * 8]);
            }
        } else {
            int jt = ks ? (qh * 2 + 5 + tt) : (qh * 2 + tt - 1);
            jbase = jt * 64;
            if (t < 64) {
                int pos = n * CHK + jbase + t - CHK;
                kvalid[t] = (pos >= 0 && pos < SEQ && mask_src[pos] > 0
                             && is_glb[pos] == 0) ? 1 : 0;
            }
            int s0 = n * CHK + jbase - CHK;
            #pragma unroll
            for (int g = 0; g < 2; g++) {
                int gid = wave * 2 + g;
                int p = gid >> 2, kbase = (gid & 3) * 16;
                int pos = s0 + kbase + l2h; pos = min(max(pos, 0), SEQ - 1);
                async16(kb + (size_t)pos * DIM + hh * HDIM + p * 32 + l3 * 8,
                        &Kt[p * 2048 + kbase * 32]);
            }
            #pragma unroll
            for (int g = 0; g < 2; g++) {
                int gid = wave * 2 + g;
                int p = gid >> 2, dbase = (gid & 3) * 16;
                int d = dbase + l2h;
                int s = s0 + p * 32 + l3 * 8; s = min(max(s, 0), SEQ - 8);
                async16(vtg + (size_t)(hh * HDIM + d) * SEQ + s,
                        &Vt[p * 2048 + dbase * 32]);
            }
        }
        __builtin_amdgcn_s_waitcnt(0x0f70);
        __syncthreads();
        if (isglob) {
            const __bf16* Vrow = &Ps[0][0];
            for (int idx = t; idx < 4096; idx += 256) {
                int key = idx >> 6, d = idx & 63;
                Vt[(key >> 5) * 2048 + d * 32 + (key & 31)] = Vrow[idx];
            }
            __syncthreads();
        } else {
            if (jbase + 63 < qw || jbase > qw + 543) continue;
        }

        bf16x8 bkf[4][2];
        #pragma unroll
        for (int nt = 0; nt < 4; nt++) {
            bkf[nt][0] = *(const bf16x8*)&Kt[(nt * 16 + col_l) * 32 + quad * 8];
            bkf[nt][1] = *(const bf16x8*)&Kt[2048 + (nt * 16 + col_l) * 32 + quad * 8];
        }
        int kv[4];
        #pragma unroll
        for (int nt = 0; nt < 4; nt++) kv[nt] = kvalid[nt * 16 + col_l];

        #pragma unroll
        for (int mt = 0; mt < 2; mt++) {
            floatx4 s[4];
            #pragma unroll
            for (int nt = 0; nt < 4; nt++) {
                floatx4 z = {0.f,0.f,0.f,0.f};
                z = __builtin_amdgcn_mfma_f32_16x16x32_bf16(aq[mt][0], bkf[nt][0], z, 0,0,0);
                z = __builtin_amdgcn_mfma_f32_16x16x32_bf16(aq[mt][1], bkf[nt][1], z, 0,0,0);
                s[nt] = z;
            }
            #pragma unroll
            for (int nt = 0; nt < 4; nt++)
                #pragma unroll
                for (int rr = 0; rr < 4; rr++) {
                    int ok = kv[nt];
                    if (!isglob) {
                        int i = qw + mt * 16 + row_l + rr;
                        int rel = jbase + nt * 16 + col_l - i;
                        ok = ok && (rel >= 0) && (rel <= 2 * WINR);
                    }
                    if (!ok) s[nt][rr] = -1e30f;
                }
            #pragma unroll
            for (int rr = 0; rr < 4; rr++) {
                float rm = fmaxf(fmaxf(s[0][rr], s[1][rr]), fmaxf(s[2][rr], s[3][rr]));
                rm = fmaxf(rm, __shfl_xor(rm, 1));
                rm = fmaxf(rm, __shfl_xor(rm, 2));
                rm = fmaxf(rm, __shfl_xor(rm, 4));
                rm = fmaxf(rm, __shfl_xor(rm, 8));
                int ri = mt * 4 + rr;
                float mo = mrw[ri];
                float mn = fmaxf(mo, rm);
                float alpha = exp2f(mo - mn);
                float rsum = 0.f;
                #pragma unroll
                for (int nt = 0; nt < 4; nt++) {
                    float p = exp2f(s[nt][rr] - mn);
                    rsum += p;
                    PsW[(mt * 16 + row_l + rr) * PS_LD + nt * 16 + col_l] = (__bf16)p;
                }
                rsum += __shfl_xor(rsum, 1);
                rsum += __shfl_xor(rsum, 2);
                rsum += __shfl_xor(rsum, 4);
                rsum += __shfl_xor(rsum, 8);
                lrw[ri] = lrw[ri] * alpha + rsum;
                mrw[ri] = mn;
                #pragma unroll
                for (int nt = 0; nt < 4; nt++) oacc[mt][nt][rr] *= alpha;
            }
        }
        bf16x8 bvf[4][2], ap[2][2];
        #pragma unroll
        for (int nt = 0; nt < 4; nt++) {
            bvf[nt][0] = *(const bf16x8*)&Vt[(nt * 16 + col_l) * 32 + quad * 8];
            bvf[nt][1] = *(const bf16x8*)&Vt[2048 + (nt * 16 + col_l) * 32 + quad * 8];
        }
        #pragma unroll
        for (int mt = 0; mt < 2; mt++) {
            ap[mt][0] = *(const bf16x8*)&PsW[(mt * 16 + col_l) * PS_LD + quad * 8];
            ap[mt][1] = *(const bf16x8*)&PsW[(mt * 16 + col_l) * PS_LD + 32 + quad * 8];
        }
        #pragma unroll
        for (int mt = 0; mt < 2; mt++)
            #pragma unroll
            for (int nt = 0; nt < 4; nt++) {
                oacc[mt][nt] = __builtin_amdgcn_mfma_f32_16x16x32_bf16(
                    ap[mt][0], bvf[nt][0], oacc[mt][nt], 0,0,0);
                oacc[mt][nt] = __builtin_amdgcn_mfma_f32_16x16x32_bf16(
                    ap[mt][1], bvf[nt][1], oacc[mt][nt], 0,0,0);
            }
    }

    #pragma unroll
    for (int mt = 0; mt < 2; mt++) {
        #pragma unroll
        for (int rr = 0; rr < 4; rr++) {
            int srow = n * CHK + qw + mt * 16 + row_l + rr;
            size_t rbase = ((size_t)ks * SEQ + srow) * NH + hh;
            #pragma unroll
            for (int nt = 0; nt < 4; nt++)
                OpartB[rbase * 64 + nt * 16 + col_l] = oacc[mt][nt][rr];
            if (col_l == 0) {
                mlpartB[rbase * 2]     = mrw[mt * 4 + rr];
                mlpartB[rbase * 2 + 1] = lrw[mt * 4 + rr];
            }
        }
    }
}

// ---------------- finalize: band 2-way merge / gq 32-way merge + scatter -------
__global__ __launch_bounds__(256) void attn_finalize(
    const float* __restrict__ OpartB, const float* __restrict__ mlpartB,
    const float* __restrict__ OpartG, const float* __restrict__ mlpartG,
    const int* __restrict__ glb_rank, __bf16* __restrict__ outb)
{
    int g = threadIdx.x >> 6, d = threadIdx.x & 63;
    int s = blockIdx.x * 4 + g, hh = blockIdx.y;
    int r = glb_rank[s];
    float o;
    if (r >= 0) {
        float M = -1e30f;
        for (int sp = 0; sp < 32; sp++)
            M = fmaxf(M, mlpartG[(((size_t)hh * 32 + sp) * 64 + r) * 2]);
        float L = 0.f, acc = 0.f;
        for (int sp = 0; sp < 32; sp++) {
            size_t b = ((size_t)hh * 32 + sp) * 64 + r;
            float w = exp2f(mlpartG[b * 2] - M);
            L += mlpartG[b * 2 + 1] * w;
            acc += w * OpartG[b * 64 + d];
        }
        o = acc / L;
    } else {
        size_t r0 = ((size_t)s) * NH + hh;
        size_t r1 = ((size_t)SEQ + s) * NH + hh;
        float m0 = mlpartB[r0 * 2], l0 = mlpartB[r0 * 2 + 1];
        float m1 = mlpartB[r1 * 2], l1 = mlpartB[r1 * 2 + 1];
        float M = fmaxf(m0, m1);
        float w0 = exp2f(m0 - M), w1 = exp2f(m1 - M);
        o = (OpartB[r0 * 64 + d] * w0 + OpartB[r1 * 64 + d] * w1) / (l0 * w0 + l1 * w1);
    }
    outb[(size_t)s * DIM + hh * HDIM + d] = (__bf16)o;
}

// ---------------- host launcher ----------------
extern "C" void kernel_launch(void* const* d_in, const int* in_sizes, int n_in,
                              void* d_out, int out_size, void* d_ws, size_t ws_size,
                              hipStream_t stream)
{
    const int* x        = (const int*)d_in[0];
    const int* mask_src = (const int*)d_in[1];
    const int* clss     = (const int*)d_in[2];
    const int* segs     = (const int*)d_in[3];
    const float* word_emb = (const float*)d_in[4];
    const float* pos_emb  = (const float*)d_in[5];
    const float* type_emb = (const float*)d_in[6];
    const float* ln_e_s   = (const float*)d_in[7];
    const float* ln_e_b   = (const float*)d_in[8];
    const float* Wq  = (const float*)d_in[9];
    const float* bq  = (const float*)d_in[10];
    const float* Wk  = (const float*)d_in[11];
    const float* bk  = (const float*)d_in[12];
    const float* Wv  = (const float*)d_in[13];
    const float* bv  = (const float*)d_in[14];
    const float* Wqg = (const float*)d_in[15];
    const float* bqg = (const float*)d_in[16];
    const float* Wkg = (const float*)d_in[17];
    const float* bkg = (const float*)d_in[18];
    const float* Wvg = (const float*)d_in[19];
    const float* bvg = (const float*)d_in[20];
    const float* Wo  = (const float*)d_in[21];
    const float* bo  = (const float*)d_in[22];
    const float* ln1_s = (const float*)d_in[23];
    const float* ln1_b = (const float*)d_in[24];
    const float* Wf1 = (const float*)d_in[25];
    const float* bf1 = (const float*)d_in[26];
    const float* Wf2 = (const float*)d_in[27];
    const float* bf2 = (const float*)d_in[28];
    const float* ln2_s = (const float*)d_in[29];
    const float* ln2_b = (const float*)d_in[30];

    const size_t DD = (size_t)DIM * DIM;
    float* ws = (float*)d_ws;
    float*  h    = ws;
    float*  s4   = ws + SD;
    __bf16* hb   = (__bf16*)(ws + 2 * SD);
    __bf16* b6b  = (__bf16*)(ws + 2 * SD) + SD;
    __bf16* qb   = (__bf16*)(ws + 3 * SD);
    __bf16* kb   = (__bf16*)(ws + 3 * SD) + SD;
    __bf16* vb   = (__bf16*)(ws + 4 * SD);
    __bf16* vtg  = (__bf16*)(ws + 4 * SD) + SD;
    __bf16* kgb  = (__bf16*)(ws + 5 * SD);
    __bf16* vgt  = (__bf16*)(ws + 5 * SD) + SD;
    __bf16* gelu_b = qb;
    float* extra = ws + 6 * SD;
    __bf16* Wbf   = (__bf16*)extra;                     // 30*DD bf16
    // Wbf layout: per-layer [Wq,Wk,Wv,Wkg,Wvg] at l*5*DD (z order below),
    // WO at 10*DD(+DD/layer), WQG at 12*DD(+DD/layer), WF1 at 14*DD, WF2 at 22*DD.
    float* after_w = extra + 15 * DD;
    float* bqkv   = after_w;                            // 2*3840
    float* OpartG = bqkv + 7680;                        // 12*32*64*64 = 1,572,864
    float* mlpartG= OpartG + 1572864;                   // 49,152
    float* OpartB = mlpartG + 49152;                    // 2*4096*12*64 = 6,291,456
    float* mlpartB= OpartB + 6291456;                   // 196,608
    __bf16* qgbb  = (__bf16*)(mlpartB + 196608);        // 64*768 bf16
    int*   isglb  = (int*)(qgbb + (size_t)NCLS * DIM);  // SEQ
    int*   grank  = isglb + SEQ;                        // SEQ

    setup_kernel<<<30, 256, 0, stream>>>(bq, bk, bv, bkg, bvg, bqkv, isglb, grank);
    set_rank_kernel<<<1, 64, 0, stream>>>(clss, isglb, grank);
    embed_ln_kernel<<<SEQ, 256, 0, stream>>>(x, segs, word_emb, pos_emb, type_emb,
                                             ln_e_s, ln_e_b, h, hb);
    {
        Ptr16 wp{};
        wp.p[0] = Wq;        wp.p[1] = Wk;        wp.p[2] = Wv;
        wp.p[3] = Wkg;       wp.p[4] = Wvg;
        wp.p[5] = Wq + DD;   wp.p[6] = Wk + DD;   wp.p[7] = Wv + DD;
        wp.p[8] = Wkg + DD;  wp.p[9] = Wvg + DD;
        wp.p[10] = Wo;       wp.p[11] = Wo + DD;
        wp.p[12] = Wqg;      wp.p[13] = Wqg + DD;
        transpose_w_kernel<<<dim3(24, 24, 14), 256, 0, stream>>>(wp, Wbf, DIM, DIM);
        Ptr16 wf1{};
        wf1.p[0] = Wf1; wf1.p[1] = Wf1 + (size_t)DIM * FFD;
        transpose_w_kernel<<<dim3(96, 24, 2), 256, 0, stream>>>(wf1, Wbf + 14 * DD, DIM, FFD);
        Ptr16 wf2{};
        wf2.p[0] = Wf2; wf2.p[1] = Wf2 + (size_t)FFD * DIM;
        transpose_w_kernel<<<dim3(24, 96, 2), 256, 0, stream>>>(wf2, Wbf + 22 * DD, FFD, DIM);
    }

    for (int l = 0; l < NLAYER; l++) {
        const float* bqg_l = bqg + (size_t)l * DIM;
        const float* bo_l  = bo  + (size_t)l * DIM;
        const float* bf1_l = bf1 + (size_t)l * FFD;
        const float* bf2_l = bf2 + (size_t)l * DIM;

        // qg projection (gather fused) -- independent of proj, needed by attn z>=4
        qg_proj<<<dim3(1, 6), 256, 0, stream>>>(
            hb, Wbf + 12 * DD + (size_t)l * DD, clss, bqg_l, qgbb);
        // fused 5-way projection
        mfma_gemm_proj<<<dim3(SEQ / 128, 3840 / 128), 256, 0, stream>>>(
            hb, Wbf + (size_t)l * 5 * DD, bqkv + l * 3840,
            qb, kb, vb, vtg, kgb, vgt, DIM);
        // unified band + gq attention
        attn_kernel<<<dim3(NCHK, NH, 6), 256, 0, stream>>>(
            qb, kb, vb, vtg, qgbb, kgb, vgt, clss, mask_src, isglb,
            OpartB, mlpartB, OpartG, mlpartG);
        attn_finalize<<<dim3(SEQ / 4, NH), 256, 0, stream>>>(
            OpartB, mlpartB, OpartG, mlpartG, grank, b6b);
        // output projection + LN1
        mfma_gemm_t<128, 64><<<dim3(SEQ / 128, DIM / 64), 256, 0, stream>>>(
            b6b, Wbf + 10 * DD + (size_t)l * DD, bo_l, s4, nullptr,
            SEQ, DIM, DIM, 1.0f, 0);
        add_ln_kernel<<<SEQ, 256, 0, stream>>>(h, s4, ln1_s + (size_t)l * DIM,
                                               ln1_b + (size_t)l * DIM, hb);
        // FFN
        mfma_gemm_t<128, 128><<<dim3(SEQ / 128, FFD / 128), 256, 0, stream>>>(
            hb, Wbf + 14 * DD + (size_t)l * 4 * DD, bf1_l, nullptr, gelu_b,
            SEQ, FFD, DIM, 1.0f, 1);
        mfma_gemm_t<128, 64><<<dim3(SEQ / 128, DIM / 64), 256, 0, stream>>>(
            gelu_b, Wbf + 22 * DD + (size_t)l * 4 * DD, bf2_l, s4, nullptr,
            SEQ, DIM, FFD, 1.0f, 0);
        add_ln_kernel<<<SEQ, 256, 0, stream>>>(h, s4, ln2_s + (size_t)l * DIM,
                                               ln2_b + (size_t)l * DIM, hb);
    }

    hipMemcpyAsync(d_out, h, SD * sizeof(float), hipMemcpyDeviceToDevice, stream);
}